// Round 3
// baseline (438.301 us; speedup 1.0000x reference)
//
#include <hip/hip_runtime.h>

// SingleScaleSA: B=4, N=16384, S=2048, K=32, mlp 64 -> 64 -> 128, radius 0.2.
// Round 25:
//  - L2/L3 software-pipelined: 4 phases x 16-k; next phase's global loads
//    (activations + weights -> regs) issued before the compute barrier, so
//    load latency hides under FMA. LDS ~15K/~19K -> 5+ blocks/CU
//    (__launch_bounds__(256,5)).
//  - stats1 kernel deleted: BN1 stats fused into the ball kernel (wave owns
//    its group's 32 idx+dxyz in LDS; coalesced P1-row reads, lane=channel).
//  - w2 pre-transposed (wT2) like wT3 for coalesced float4 weight staging.
constexpr int kNB      = 4;
constexpr int kNPts    = 16384;
constexpr int kNS      = 2048;
constexpr int kNK      = 32;
constexpr int kC3      = 128;
constexpr int kNRows   = kNB * kNS * kNK;   // 262144
constexpr int kNGrp    = kNB * kNS;         // 8192
constexpr int kNPtsTot = kNB * kNPts;       // 65536
constexpr double kR2   = 0.2 * 0.2;

// ---------------------------------------------------------------- prep
__global__ __launch_bounds__(256) void ssaPrepKernel(
    const float* xyz, const float* newXyz, const float* w2, const float* w3,
    float* outHead, float4* soa, float* stats, float* wT2, float* wT3)
{
    int t = static_cast<int>(blockIdx.x) * 256 + static_cast<int>(threadIdx.x);
    if (t < kNPtsTot) {
        soa[t] = make_float4(xyz[t * 3 + 0], xyz[t * 3 + 1], xyz[t * 3 + 2], 0.0f);
    }
    if (t < kNB * kNS * 3) {
        outHead[t] = newXyz[t];
    }
    if (t < 512) {
        stats[t] = 0.0f;
    }
    if (t < 64 * 128) {
        int k = t >> 7;
        int c = t & 127;
        wT3[t] = w3[c * 64 + k];
    }
    if (t < 64 * 64) {
        int k = t >> 6;
        int c = t & 63;
        wT2[t] = w2[c * 64 + k];
    }
}

// ---------------------------------------------------------------- ball query + BN1 stats
__global__ __launch_bounds__(256) void ssaBallKernel(
    const float* newXyz, const float4* soa, const float* w1, const float* bias1,
    const float* p1f, int* ballIdx, float4* ballDxyz, float* stats)
{
    __shared__ int   sIdx[4][32];
    __shared__ float sDx[4][32];
    __shared__ float sDy[4][32];
    __shared__ float sDz[4][32];
    __shared__ float sStat[128];
    int tid  = static_cast<int>(threadIdx.x);
    int wv   = tid >> 6;
    int lane = tid & 63;
    int w    = static_cast<int>(blockIdx.x) * 4 + wv;
    int b    = w >> 11;
    if (tid < 128) sStat[tid] = 0.0f;
    __syncthreads();

    float qx = newXyz[w * 3 + 0];
    float qy = newXyz[w * 3 + 1];
    float qz = newXyz[w * 3 + 2];
    double qxd = static_cast<double>(qx);
    double qyd = static_cast<double>(qy);
    double qzd = static_cast<double>(qz);
    double qq  = qxd * qxd + qyd * qyd + qzd * qzd;
    const float4* sp = soa + b * kNPts;
    int*    oi = ballIdx  + static_cast<size_t>(w) * kNK;
    float4* od = ballDxyz + static_cast<size_t>(w) * kNK;

    int cnt = 0;
    int firstN = -1;
    float fdx = 0.0f, fdy = 0.0f, fdz = 0.0f;
    for (int base = 0; base < kNPts && cnt < kNK; base += 64) {
        float4 p = sp[base + lane];
        double pxd = static_cast<double>(p.x);
        double pyd = static_cast<double>(p.y);
        double pzd = static_cast<double>(p.z);
        double d2  = qq + (pxd * pxd + pyd * pyd + pzd * pzd)
                   - 2.0 * (qxd * pxd + qyd * pyd + qzd * pzd);
        bool hit   = (d2 <= kR2);
        unsigned long long m = __ballot(hit);
        int pos = cnt + __popcll(m & ((1ull << lane) - 1ull));
        if (hit && pos < kNK) {
            float dx = p.x - qx;
            float dy = p.y - qy;
            float dz = p.z - qz;
            oi[pos] = base + lane;
            od[pos] = make_float4(dx, dy, dz, 0.0f);
            sIdx[wv][pos] = base + lane;
            sDx[wv][pos] = dx;
            sDy[wv][pos] = dy;
            sDz[wv][pos] = dz;
            if (pos == 0) { firstN = base + lane; fdx = dx; fdy = dy; fdz = dz; }
        }
        cnt += __popcll(m);
    }
    if (cnt < kNK) {
        unsigned long long hv = __ballot(firstN >= 0);
        int fi;
        float dx, dy, dz;
        if (hv != 0ull) {
            int src = __builtin_ctzll(hv);
            fi = __shfl(firstN, src);
            dx = __shfl(fdx, src);
            dy = __shfl(fdy, src);
            dz = __shfl(fdz, src);
        } else {
            float4 p = sp[kNPts - 1];
            fi = kNPts - 1;
            dx = p.x - qx;
            dy = p.y - qy;
            dz = p.z - qz;
        }
        for (int p2 = cnt + lane; p2 < kNK; p2 += 64) {
            oi[p2] = fi;
            od[p2] = make_float4(dx, dy, dz, 0.0f);
            sIdx[wv][p2] = fi;
            sDx[wv][p2] = dx;
            sDy[wv][p2] = dy;
            sDz[wv][p2] = dz;
        }
    }

    // BN1 stats: lane = channel; z1 = P1[gi,c] + dxyz.W1xyz[:,c] + b1[c].
    float wa  = w1[lane * 67 + 0];
    float wbv = w1[lane * 67 + 1];
    float wc  = w1[lane * 67 + 2];
    float bb  = bias1[lane];
    const float* pb = p1f + static_cast<size_t>(b) * kNPts * 64;
    float s = 0.0f, q = 0.0f;
    #pragma unroll 4
    for (int k2 = 0; k2 < kNK; k2++) {
        int g = sIdx[wv][k2];
        float val = pb[static_cast<size_t>(g) * 64 + lane]
                  + sDx[wv][k2] * wa + sDy[wv][k2] * wbv + sDz[wv][k2] * wc + bb;
        s += val;
        q += val * val;
    }
    atomicAdd(&sStat[lane], s);
    atomicAdd(&sStat[64 + lane], q);
    __syncthreads();
    if (tid < 128) {
        atomicAdd(&stats[tid], sStat[tid]);
    }
}

// ---------------------------------------------------------------- P1 GEMM
// P1[b,n,:] = points[b,n,:] @ W1[:,3:67]^T  — 65536 rows, K=64, 64 cols.
__global__ __launch_bounds__(256) void ssaP1Kernel(
    const float4* points, const float* w1, float4* p1)
{
    __shared__ float xT[32 * 128];
    __shared__ float sW[64 * 64];
    int tid = static_cast<int>(threadIdx.x);
    int R0  = static_cast<int>(blockIdx.x) * 128;
    int ty  = tid >> 4;
    int tx  = tid & 15;
    int r   = tid & 127;
    int h   = tid >> 7;

    for (int i = tid; i < 64 * 64; i += 256) {
        int k = i >> 6;
        int c = i & 63;
        sW[i] = w1[c * 67 + 3 + k];
    }
    __syncthreads();

    float acc[8][4];
    #pragma unroll
    for (int i = 0; i < 8; i++)
        #pragma unroll
        for (int j = 0; j < 4; j++) acc[i][j] = 0.0f;

    const float4* prow = points + static_cast<size_t>(R0 + r) * 16;

    #pragma unroll 1
    for (int ch = 0; ch < 2; ch++) {
        if (ch > 0) __syncthreads();
        for (int j = h * 4; j < h * 4 + 4; j++) {
            float4 v = prow[ch * 8 + j];
            int k = j * 4;
            xT[(k + 0) * 128 + r] = v.x;
            xT[(k + 1) * 128 + r] = v.y;
            xT[(k + 2) * 128 + r] = v.z;
            xT[(k + 3) * 128 + r] = v.w;
        }
        __syncthreads();

        int kw = ch * 32;
        for (int k = 0; k < 32; k++) {
            const float* xk = &xT[k * 128 + ty * 8];
            const float* wk = &sW[(kw + k) * 64 + tx * 4];
            float w0 = wk[0], w1v = wk[1], w2v = wk[2], w3v = wk[3];
            #pragma unroll
            for (int i = 0; i < 8; i++) {
                float xv = xk[i];
                acc[i][0] += xv * w0;
                acc[i][1] += xv * w1v;
                acc[i][2] += xv * w2v;
                acc[i][3] += xv * w3v;
            }
        }
    }

    #pragma unroll
    for (int i = 0; i < 8; i++) {
        p1[static_cast<size_t>(R0 + ty * 8 + i) * 16 + tx] =
            make_float4(acc[i][0], acc[i][1], acc[i][2], acc[i][3]);
    }
}

// ---------------------------------------------------------------- layer 2
// 4-phase pipelined: relu(bn1(P1[gi] + dxyz@W1xyz + b1)) @ W2; fused BN2 stats.
__global__ __launch_bounds__(256, 5) void ssaLayer2Kernel(
    const float4* p1, const float* w1, const float* bias1,
    const float4* wT2f4, const float* bias2,
    const float* gamma1, const float* beta1, const float* statsIn,
    const int* ballIdx, const float4* ballDxyz,
    float4* z2, float* statsOut)
{
    __shared__ __align__(16) float xT[16 * 128];   // 8 KB
    __shared__ __align__(16) float sW[16 * 64];    // 4 KB
    __shared__ float sWx[256];
    __shared__ float sB[64];
    __shared__ float sG[64];
    __shared__ float sH[64];
    __shared__ float sStat[128];
    int tid = static_cast<int>(threadIdx.x);
    int R0  = static_cast<int>(blockIdx.x) * 128;
    int ty  = tid >> 4;
    int tx  = tid & 15;
    int r   = tid & 127;
    int h   = tid >> 7;

    int gi = ballIdx[R0 + r];
    float4 dd = ballDxyz[R0 + r];
    int b = R0 >> 16;
    const float4* prow = p1 + (static_cast<size_t>(b) * kNPts + static_cast<size_t>(gi)) * 16;

    // phase-0 prefetch
    float4 xa = prow[h * 2 + 0];
    float4 xb = prow[h * 2 + 1];
    float4 wa = wT2f4[tid];

    if (tid < 64) {
        sB[tid] = bias2[tid];
        double mean = static_cast<double>(statsIn[tid]) / static_cast<double>(kNRows);
        double var  = static_cast<double>(statsIn[64 + tid]) / static_cast<double>(kNRows) - mean * mean;
        double rstd = 1.0 / sqrt(var + 1e-5);
        float g = static_cast<float>(rstd) * gamma1[tid];
        sG[tid] = g;
        sH[tid] = beta1[tid] - static_cast<float>(mean) * g;
        sWx[tid]       = w1[tid * 67 + 0];
        sWx[64 + tid]  = w1[tid * 67 + 1];
        sWx[128 + tid] = w1[tid * 67 + 2];
        sWx[192 + tid] = bias1[tid];
    }
    if (tid < 128) sStat[tid] = 0.0f;
    __syncthreads();

    float dx = dd.x, dy = dd.y, dz = dd.z;
    float acc[8][4];
    #pragma unroll
    for (int i = 0; i < 8; i++)
        #pragma unroll
        for (int j = 0; j < 4; j++) acc[i][j] = sB[tx * 4 + j];

    #pragma unroll 1
    for (int p = 0; p < 4; p++) {
        if (p > 0) __syncthreads();
        #pragma unroll
        for (int m = 0; m < 2; m++) {
            float4 v = (m == 0) ? xa : xb;
            int j  = p * 4 + h * 2 + m;
            int kg = j * 4;
            int kl = (h * 2 + m) * 4;
            float z0 = v.x + dx * sWx[kg + 0] + dy * sWx[64 + kg + 0] + dz * sWx[128 + kg + 0] + sWx[192 + kg + 0];
            float z1v = v.y + dx * sWx[kg + 1] + dy * sWx[64 + kg + 1] + dz * sWx[128 + kg + 1] + sWx[192 + kg + 1];
            float z2v = v.z + dx * sWx[kg + 2] + dy * sWx[64 + kg + 2] + dz * sWx[128 + kg + 2] + sWx[192 + kg + 2];
            float z3v = v.w + dx * sWx[kg + 3] + dy * sWx[64 + kg + 3] + dz * sWx[128 + kg + 3] + sWx[192 + kg + 3];
            xT[(kl + 0) * 128 + r] = fmaxf(z0  * sG[kg + 0] + sH[kg + 0], 0.0f);
            xT[(kl + 1) * 128 + r] = fmaxf(z1v * sG[kg + 1] + sH[kg + 1], 0.0f);
            xT[(kl + 2) * 128 + r] = fmaxf(z2v * sG[kg + 2] + sH[kg + 2], 0.0f);
            xT[(kl + 3) * 128 + r] = fmaxf(z3v * sG[kg + 3] + sH[kg + 3], 0.0f);
        }
        reinterpret_cast<float4*>(sW)[tid] = wa;
        if (p < 3) {
            xa = prow[(p + 1) * 4 + h * 2 + 0];
            xb = prow[(p + 1) * 4 + h * 2 + 1];
            wa = wT2f4[(p + 1) * 256 + tid];
        }
        __syncthreads();

        for (int k = 0; k < 16; k++) {
            const float* xk = &xT[k * 128 + ty * 8];
            const float* wk = &sW[k * 64 + tx * 4];
            float w0 = wk[0], w1v = wk[1], w2v = wk[2], w3v = wk[3];
            #pragma unroll
            for (int i = 0; i < 8; i++) {
                float xv = xk[i];
                acc[i][0] += xv * w0;
                acc[i][1] += xv * w1v;
                acc[i][2] += xv * w2v;
                acc[i][3] += xv * w3v;
            }
        }
    }

    float s[4] = {0.f, 0.f, 0.f, 0.f};
    float q[4] = {0.f, 0.f, 0.f, 0.f};
    #pragma unroll
    for (int i = 0; i < 8; i++) {
        int row = R0 + ty * 8 + i;
        z2[static_cast<size_t>(row) * 16 + tx] =
            make_float4(acc[i][0], acc[i][1], acc[i][2], acc[i][3]);
        #pragma unroll
        for (int j = 0; j < 4; j++) {
            s[j] += acc[i][j];
            q[j] += acc[i][j] * acc[i][j];
        }
    }
    int lane = tid & 63;
    #pragma unroll
    for (int j = 0; j < 4; j++) {
        s[j] += __shfl_xor(s[j], 16); q[j] += __shfl_xor(q[j], 16);
        s[j] += __shfl_xor(s[j], 32); q[j] += __shfl_xor(q[j], 32);
    }
    if (lane < 16) {
        #pragma unroll
        for (int j = 0; j < 4; j++) {
            atomicAdd(&sStat[tx * 4 + j],      s[j]);
            atomicAdd(&sStat[64 + tx * 4 + j], q[j]);
        }
    }
    __syncthreads();
    if (tid < 128) {
        atomicAdd(&statsOut[tid], sStat[tid]);
    }
}

// ---------------------------------------------------------------- layer 3
// 4-phase pipelined; pre-BN wave max-pool; fused BN3 stats.
__global__ __launch_bounds__(256, 5) void ssaLayer3Kernel(
    const float4* z2, const float4* wT3f4, const float* bias3,
    const float* gamma2, const float* beta2, const float* statsIn,
    float* poolMax, float* statsOut)
{
    __shared__ __align__(16) float xT[16 * 128];   // 8 KB
    __shared__ __align__(16) float sW[16 * 128];   // 8 KB
    __shared__ float sB[128];
    __shared__ float sG[64];
    __shared__ float sH[64];
    __shared__ float sStat[256];
    int tid = static_cast<int>(threadIdx.x);
    int R0  = static_cast<int>(blockIdx.x) * 128;
    int ty  = tid >> 4;
    int tx  = tid & 15;
    int r   = tid & 127;
    int h   = tid >> 7;

    const float4* zr = z2 + static_cast<size_t>(R0 + r) * 16;

    // phase-0 prefetch
    float4 xa = zr[h * 2 + 0];
    float4 xb = zr[h * 2 + 1];
    float4 wa = wT3f4[tid];
    float4 wb = wT3f4[256 + tid];

    if (tid < 64) {
        double mean = static_cast<double>(statsIn[tid]) / static_cast<double>(kNRows);
        double var  = static_cast<double>(statsIn[64 + tid]) / static_cast<double>(kNRows) - mean * mean;
        double rstd = 1.0 / sqrt(var + 1e-5);
        float g = static_cast<float>(rstd) * gamma2[tid];
        sG[tid] = g;
        sH[tid] = beta2[tid] - static_cast<float>(mean) * g;
    }
    if (tid < 128) sB[tid] = bias3[tid];
    sStat[tid] = 0.0f;
    __syncthreads();

    float acc[8][8];
    #pragma unroll
    for (int i = 0; i < 8; i++) {
        #pragma unroll
        for (int j = 0; j < 4; j++) {
            acc[i][j]     = sB[tx * 4 + j];
            acc[i][4 + j] = sB[64 + tx * 4 + j];
        }
    }

    #pragma unroll 1
    for (int p = 0; p < 4; p++) {
        if (p > 0) __syncthreads();
        #pragma unroll
        for (int m = 0; m < 2; m++) {
            float4 v = (m == 0) ? xa : xb;
            int j  = p * 4 + h * 2 + m;
            int kg = j * 4;
            int kl = (h * 2 + m) * 4;
            xT[(kl + 0) * 128 + r] = fmaxf(v.x * sG[kg + 0] + sH[kg + 0], 0.0f);
            xT[(kl + 1) * 128 + r] = fmaxf(v.y * sG[kg + 1] + sH[kg + 1], 0.0f);
            xT[(kl + 2) * 128 + r] = fmaxf(v.z * sG[kg + 2] + sH[kg + 2], 0.0f);
            xT[(kl + 3) * 128 + r] = fmaxf(v.w * sG[kg + 3] + sH[kg + 3], 0.0f);
        }
        reinterpret_cast<float4*>(sW)[tid]       = wa;
        reinterpret_cast<float4*>(sW)[256 + tid] = wb;
        if (p < 3) {
            xa = zr[(p + 1) * 4 + h * 2 + 0];
            xb = zr[(p + 1) * 4 + h * 2 + 1];
            wa = wT3f4[(p + 1) * 512 + tid];
            wb = wT3f4[(p + 1) * 512 + 256 + tid];
        }
        __syncthreads();

        for (int k = 0; k < 16; k++) {
            const float* xk = &xT[k * 128 + ty * 8];
            const float* wk = &sW[k * 128];
            float wv[8];
            #pragma unroll
            for (int j = 0; j < 4; j++) wv[j] = wk[tx * 4 + j];
            #pragma unroll
            for (int j = 0; j < 4; j++) wv[4 + j] = wk[64 + tx * 4 + j];
            #pragma unroll
            for (int i = 0; i < 8; i++) {
                float xv = xk[i];
                #pragma unroll
                for (int j = 0; j < 8; j++) {
                    acc[i][j] += xv * wv[j];
                }
            }
        }
    }

    // pooling (max over the wave's 32 rows) + stats
    int lane = tid & 63;
    int grp  = static_cast<int>(blockIdx.x) * 4 + (ty >> 2);
    float mx[8];
    float s[8];
    float q[8];
    #pragma unroll
    for (int j = 0; j < 8; j++) {
        mx[j] = acc[0][j];
        s[j]  = 0.0f;
        q[j]  = 0.0f;
    }
    #pragma unroll
    for (int i = 0; i < 8; i++)
        #pragma unroll
        for (int j = 0; j < 8; j++) {
            float v = acc[i][j];
            mx[j] = fmaxf(mx[j], v);
            s[j] += v;
            q[j] += v * v;
        }
    #pragma unroll
    for (int j = 0; j < 8; j++) {
        mx[j] = fmaxf(mx[j], __shfl_xor(mx[j], 16));
        mx[j] = fmaxf(mx[j], __shfl_xor(mx[j], 32));
        s[j] += __shfl_xor(s[j], 16); q[j] += __shfl_xor(q[j], 16);
        s[j] += __shfl_xor(s[j], 32); q[j] += __shfl_xor(q[j], 32);
    }
    if (lane < 16) {
        #pragma unroll
        for (int j = 0; j < 8; j++) {
            int c = (j < 4) ? (tx * 4 + j) : (64 + tx * 4 + (j - 4));
            poolMax[static_cast<size_t>(grp) * kC3 + c] = mx[j];
            atomicAdd(&sStat[c],       s[j]);
            atomicAdd(&sStat[128 + c], q[j]);
        }
    }
    __syncthreads();
    atomicAdd(&statsOut[tid], sStat[tid]);
}

// ---------------------------------------------------------------- finalize
__global__ __launch_bounds__(256) void ssaFinalKernel(
    const float* poolMax, const float* sum3, const float* sq3,
    const float* gamma3, const float* beta3, float* outTail)
{
    __shared__ float sG[128];
    __shared__ float sH[128];
    int tid = static_cast<int>(threadIdx.x);
    if (tid < 128) {
        double mean = static_cast<double>(sum3[tid]) / static_cast<double>(kNRows);
        double var  = static_cast<double>(sq3[tid]) / static_cast<double>(kNRows) - mean * mean;
        double rstd = 1.0 / sqrt(var + 1e-5);
        float g = static_cast<float>(rstd) * gamma3[tid];
        sG[tid] = g;
        sH[tid] = beta3[tid] - static_cast<float>(mean) * g;
    }
    __syncthreads();
    int e  = static_cast<int>(blockIdx.x) * 256 + tid;
    int b  = e >> 18;
    int ch = (e >> 11) & 127;
    int s  = e & 2047;
    size_t gi = static_cast<size_t>(b * kNS + s) * kC3 + ch;
    outTail[e] = fmaxf(poolMax[gi] * sG[ch] + sH[ch], 0.0f);
}

// ---------------------------------------------------------------- launch
static inline void* ssaWsAt(void* base, size_t byteOff)
{
    return static_cast<void*>(static_cast<char*>(base) + byteOff);
}

extern "C" __attribute__((visibility("default"), used))
void kernel_launch(void* const* d_in, const int* in_sizes, int n_in,
                   void* d_out, int out_size, void* d_ws, size_t ws_size,
                   hipStream_t stream)
{
    static_cast<void>(in_sizes);
    static_cast<void>(n_in);
    static_cast<void>(out_size);
    static_cast<void>(ws_size);

    const float*  xyz    = static_cast<const float*>(d_in[0]);
    const float4* points = static_cast<const float4*>(d_in[1]);
    const float*  newXyz = static_cast<const float*>(d_in[2]);
    const float*  w1Ptr  = static_cast<const float*>(d_in[3]);
    const float*  b1Ptr  = static_cast<const float*>(d_in[4]);
    const float*  g1Ptr  = static_cast<const float*>(d_in[5]);
    const float*  e1Ptr  = static_cast<const float*>(d_in[6]);
    const float*  w2Ptr  = static_cast<const float*>(d_in[7]);
    const float*  b2Ptr  = static_cast<const float*>(d_in[8]);
    const float*  g2Ptr  = static_cast<const float*>(d_in[9]);
    const float*  e2Ptr  = static_cast<const float*>(d_in[10]);
    const float*  w3Ptr  = static_cast<const float*>(d_in[11]);
    const float*  b3Ptr  = static_cast<const float*>(d_in[12]);
    const float*  g3Ptr  = static_cast<const float*>(d_in[13]);
    const float*  e3Ptr  = static_cast<const float*>(d_in[14]);

    float4* soa   = static_cast<float4*>(ssaWsAt(d_ws, 0));           //  1,048,576 B
    int*    bIdx  = static_cast<int*>(ssaWsAt(d_ws, 1048576));        //  1,048,576 B
    float4* bDxy  = static_cast<float4*>(ssaWsAt(d_ws, 2097152));     //  4,194,304 B
    float4* p1    = static_cast<float4*>(ssaWsAt(d_ws, 6291456));     // 16,777,216 B
    float4* z2    = static_cast<float4*>(ssaWsAt(d_ws, 23068672));    // 67,108,864 B
    float*  pMax  = static_cast<float*>(ssaWsAt(d_ws, 90177536));     //  4,194,304 B
    float*  stats = static_cast<float*>(ssaWsAt(d_ws, 94371840));     //      2,048 B
    float*  wT3   = static_cast<float*>(ssaWsAt(d_ws, 94373888));     //     32,768 B
    float*  wT2   = static_cast<float*>(ssaWsAt(d_ws, 94406656));     //     16,384 B
    float*  outF  = static_cast<float*>(d_out);

    ssaPrepKernel<<<256, 256, 0, stream>>>(xyz, newXyz, w2Ptr, w3Ptr,
                                           outF, soa, stats, wT2, wT3);
    ssaP1Kernel<<<kNPtsTot / 128, 256, 0, stream>>>(points, w1Ptr, p1);
    ssaBallKernel<<<kNGrp / 4, 256, 0, stream>>>(newXyz, soa, w1Ptr, b1Ptr,
                                                 reinterpret_cast<const float*>(p1),
                                                 bIdx, bDxy, stats);
    ssaLayer2Kernel<<<kNRows / 128, 256, 0, stream>>>(p1, w1Ptr, b1Ptr,
                                                      reinterpret_cast<const float4*>(wT2),
                                                      b2Ptr, g1Ptr, e1Ptr, stats, bIdx, bDxy,
                                                      z2, stats + 128);
    ssaLayer3Kernel<<<kNRows / 128, 256, 0, stream>>>(z2,
                                                      reinterpret_cast<const float4*>(wT3),
                                                      b3Ptr, g2Ptr, e2Ptr,
                                                      stats + 128, pMax, stats + 256);
    ssaFinalKernel<<<kNB * kC3 * kNS / 256, 256, 0, stream>>>(pMax, stats + 256, stats + 384,
                                                              g3Ptr, e3Ptr,
                                                              outF + kNB * kNS * 3);
}

// Round 4
// 361.475 us; speedup vs baseline: 1.2125x; 1.2125x over previous
//
#include <hip/hip_runtime.h>

// SingleScaleSA: B=4, N=16384, S=2048, K=32, mlp 64 -> 64 -> 128, radius 0.2.
// Round 26: revert to the proven r24 structure (349 us), then ONE surgical
// change to L2/L3 only:
//  - full input row captured to registers once (128 B/thread burst, same
//    granularity as r24 but issued once) -> phase-1 staging is reg->LDS only.
//  - weights staged per 32-k chunk from pre-transposed wT2/wT3 (float4,
//    coalesced); phase-1 chunk prefetched into regs during phase-0 compute.
//  - hand-unrolled phases (no runtime-indexed register arrays).
constexpr int kNB      = 4;
constexpr int kNPts    = 16384;
constexpr int kNS      = 2048;
constexpr int kNK      = 32;
constexpr int kC3      = 128;
constexpr int kNRows   = kNB * kNS * kNK;   // 262144
constexpr int kNGrp    = kNB * kNS;         // 8192
constexpr int kNPtsTot = kNB * kNPts;       // 65536
constexpr double kR2   = 0.2 * 0.2;

// ---------------------------------------------------------------- prep
__global__ __launch_bounds__(256) void ssaPrepKernel(
    const float* xyz, const float* newXyz, const float* w2, const float* w3,
    float* outHead, float4* soa, float* stats, float* wT2, float* wT3)
{
    int t = static_cast<int>(blockIdx.x) * 256 + static_cast<int>(threadIdx.x);
    if (t < kNPtsTot) {
        soa[t] = make_float4(xyz[t * 3 + 0], xyz[t * 3 + 1], xyz[t * 3 + 2], 0.0f);
    }
    if (t < kNB * kNS * 3) {
        outHead[t] = newXyz[t];
    }
    if (t < 512) {
        stats[t] = 0.0f;
    }
    if (t < 64 * 128) {
        int k = t >> 7;
        int c = t & 127;
        wT3[t] = w3[c * 64 + k];
    }
    if (t < 64 * 64) {
        int k = t >> 6;
        int c = t & 63;
        wT2[t] = w2[c * 64 + k];
    }
}

// ---------------------------------------------------------------- ball query
__global__ __launch_bounds__(256) void ssaBallKernel(
    const float* newXyz, const float4* soa,
    int* ballIdx, float4* ballDxyz)
{
    int tid  = static_cast<int>(threadIdx.x);
    int w    = (static_cast<int>(blockIdx.x) * 256 + tid) >> 6;
    int lane = tid & 63;
    int b    = w >> 11;
    float qx = newXyz[w * 3 + 0];
    float qy = newXyz[w * 3 + 1];
    float qz = newXyz[w * 3 + 2];
    double qxd = static_cast<double>(qx);
    double qyd = static_cast<double>(qy);
    double qzd = static_cast<double>(qz);
    double qq  = qxd * qxd + qyd * qyd + qzd * qzd;
    const float4* sp = soa + b * kNPts;
    int*    oi = ballIdx  + static_cast<size_t>(w) * kNK;
    float4* od = ballDxyz + static_cast<size_t>(w) * kNK;

    int cnt = 0;
    int firstN = -1;
    float fdx = 0.0f, fdy = 0.0f, fdz = 0.0f;
    for (int base = 0; base < kNPts && cnt < kNK; base += 64) {
        float4 p = sp[base + lane];
        double pxd = static_cast<double>(p.x);
        double pyd = static_cast<double>(p.y);
        double pzd = static_cast<double>(p.z);
        double d2  = qq + (pxd * pxd + pyd * pyd + pzd * pzd)
                   - 2.0 * (qxd * pxd + qyd * pyd + qzd * pzd);
        bool hit   = (d2 <= kR2);
        unsigned long long m = __ballot(hit);
        int pos = cnt + __popcll(m & ((1ull << lane) - 1ull));
        if (hit && pos < kNK) {
            float dx = p.x - qx;
            float dy = p.y - qy;
            float dz = p.z - qz;
            oi[pos] = base + lane;
            od[pos] = make_float4(dx, dy, dz, 0.0f);
            if (pos == 0) { firstN = base + lane; fdx = dx; fdy = dy; fdz = dz; }
        }
        cnt += __popcll(m);
    }
    if (cnt < kNK) {
        unsigned long long hv = __ballot(firstN >= 0);
        int fi;
        float dx, dy, dz;
        if (hv != 0ull) {
            int src = __builtin_ctzll(hv);
            fi = __shfl(firstN, src);
            dx = __shfl(fdx, src);
            dy = __shfl(fdy, src);
            dz = __shfl(fdz, src);
        } else {
            float4 p = sp[kNPts - 1];
            fi = kNPts - 1;
            dx = p.x - qx;
            dy = p.y - qy;
            dz = p.z - qz;
        }
        for (int p2 = cnt + lane; p2 < kNK; p2 += 64) {
            oi[p2] = fi;
            od[p2] = make_float4(dx, dy, dz, 0.0f);
        }
    }
}

// ---------------------------------------------------------------- P1 GEMM
// P1[b,n,:] = points[b,n,:] @ W1[:,3:67]^T  — 65536 rows, K=64, 64 cols.
__global__ __launch_bounds__(256) void ssaP1Kernel(
    const float4* points, const float* w1, float4* p1)
{
    __shared__ float xT[32 * 128];
    __shared__ float sW[64 * 64];
    int tid = static_cast<int>(threadIdx.x);
    int R0  = static_cast<int>(blockIdx.x) * 128;
    int ty  = tid >> 4;
    int tx  = tid & 15;
    int r   = tid & 127;
    int h   = tid >> 7;

    for (int i = tid; i < 64 * 64; i += 256) {
        int k = i >> 6;
        int c = i & 63;
        sW[i] = w1[c * 67 + 3 + k];
    }
    __syncthreads();

    float acc[8][4];
    #pragma unroll
    for (int i = 0; i < 8; i++)
        #pragma unroll
        for (int j = 0; j < 4; j++) acc[i][j] = 0.0f;

    const float4* prow = points + static_cast<size_t>(R0 + r) * 16;

    #pragma unroll 1
    for (int ch = 0; ch < 2; ch++) {
        if (ch > 0) __syncthreads();
        for (int j = h * 4; j < h * 4 + 4; j++) {
            float4 v = prow[ch * 8 + j];
            int k = j * 4;
            xT[(k + 0) * 128 + r] = v.x;
            xT[(k + 1) * 128 + r] = v.y;
            xT[(k + 2) * 128 + r] = v.z;
            xT[(k + 3) * 128 + r] = v.w;
        }
        __syncthreads();

        int kw = ch * 32;
        for (int k = 0; k < 32; k++) {
            const float* xk = &xT[k * 128 + ty * 8];
            const float* wk = &sW[(kw + k) * 64 + tx * 4];
            float w0 = wk[0], w1v = wk[1], w2v = wk[2], w3v = wk[3];
            #pragma unroll
            for (int i = 0; i < 8; i++) {
                float xv = xk[i];
                acc[i][0] += xv * w0;
                acc[i][1] += xv * w1v;
                acc[i][2] += xv * w2v;
                acc[i][3] += xv * w3v;
            }
        }
    }

    #pragma unroll
    for (int i = 0; i < 8; i++) {
        p1[static_cast<size_t>(R0 + ty * 8 + i) * 16 + tx] =
            make_float4(acc[i][0], acc[i][1], acc[i][2], acc[i][3]);
    }
}

// ---------------------------------------------------------------- BN1 stats
__global__ __launch_bounds__(256) void ssaStats1Kernel(
    const float4* p1, const float* w1, const float* bias1,
    const int* ballIdx, const float4* ballDxyz, float* stats)
{
    __shared__ float sXyz[3 * 128];
    __shared__ int   sGi[128];
    __shared__ float sWx[256];
    __shared__ float sStat[128];
    int tid = static_cast<int>(threadIdx.x);
    int R0  = static_cast<int>(blockIdx.x) * 128;
    int ty  = tid >> 4;
    int tx  = tid & 15;

    if (tid < 128) {
        sGi[tid] = ballIdx[R0 + tid];
        float4 d = ballDxyz[R0 + tid];
        sXyz[tid]       = d.x;
        sXyz[128 + tid] = d.y;
        sXyz[256 + tid] = d.z;
        sStat[tid] = 0.0f;
    }
    if (tid < 64) {
        sWx[tid]       = w1[tid * 67 + 0];
        sWx[64 + tid]  = w1[tid * 67 + 1];
        sWx[128 + tid] = w1[tid * 67 + 2];
        sWx[192 + tid] = bias1[tid];
    }
    __syncthreads();

    int b = R0 >> 16;
    const float4* pb = p1 + static_cast<size_t>(b) * kNPts * 16;
    int c0 = tx * 4;
    float wa[4], wb[4], wc[4], bb[4];
    #pragma unroll
    for (int j = 0; j < 4; j++) {
        wa[j] = sWx[c0 + j];
        wb[j] = sWx[64 + c0 + j];
        wc[j] = sWx[128 + c0 + j];
        bb[j] = sWx[192 + c0 + j];
    }

    float s[4] = {0.f, 0.f, 0.f, 0.f};
    float q[4] = {0.f, 0.f, 0.f, 0.f};
    #pragma unroll
    for (int i = 0; i < 8; i++) {
        int r2 = ty * 8 + i;
        float4 v = pb[static_cast<size_t>(sGi[r2]) * 16 + tx];
        float dx = sXyz[r2], dy = sXyz[128 + r2], dz = sXyz[256 + r2];
        float vv[4] = {v.x, v.y, v.z, v.w};
        #pragma unroll
        for (int j = 0; j < 4; j++) {
            float val = vv[j] + dx * wa[j] + dy * wb[j] + dz * wc[j] + bb[j];
            s[j] += val;
            q[j] += val * val;
        }
    }
    int lane = tid & 63;
    #pragma unroll
    for (int j = 0; j < 4; j++) {
        s[j] += __shfl_xor(s[j], 16); q[j] += __shfl_xor(q[j], 16);
        s[j] += __shfl_xor(s[j], 32); q[j] += __shfl_xor(q[j], 32);
    }
    if (lane < 16) {
        #pragma unroll
        for (int j = 0; j < 4; j++) {
            atomicAdd(&sStat[tx * 4 + j],      s[j]);
            atomicAdd(&sStat[64 + tx * 4 + j], q[j]);
        }
    }
    __syncthreads();
    if (tid < 128) {
        atomicAdd(&stats[tid], sStat[tid]);
    }
}

// ---------------------------------------------------------------- layer 2
// Input reconstructed on the fly: relu(bn1(P1[gi] + dxyz@W1xyz + b1)).
// Full row in regs (rxA/rxB); weights per 32-k chunk from wT2, chunk-1
// prefetched during chunk-0 compute.
__global__ __launch_bounds__(256) void ssaLayer2Kernel(
    const float4* p1, const float* w1, const float* bias1,
    const float4* wT2f4, const float* bias2,
    const float* gamma1, const float* beta1, const float* statsIn,
    const int* ballIdx, const float4* ballDxyz,
    float4* z2, float* statsOut)
{
    __shared__ __align__(16) float xT[32 * 128];   // 16 KB
    __shared__ __align__(16) float sW[32 * 64];    //  8 KB (one chunk)
    __shared__ float sWx[256];
    __shared__ float sB[64];
    __shared__ float sG[64];
    __shared__ float sH[64];
    __shared__ float sStat[128];
    int tid = static_cast<int>(threadIdx.x);
    int R0  = static_cast<int>(blockIdx.x) * 128;
    int ty  = tid >> 4;
    int tx  = tid & 15;
    int r   = tid & 127;
    int h   = tid >> 7;

    int gi = ballIdx[R0 + r];
    float4 dd = ballDxyz[R0 + r];
    int b = R0 >> 16;
    const float4* prow = p1 + (static_cast<size_t>(b) * kNPts + static_cast<size_t>(gi)) * 16;

    // full row -> regs (one 64 B burst per half), chunk-0 weights via LDS loop
    float4 rxA0 = prow[h * 4 + 0];
    float4 rxA1 = prow[h * 4 + 1];
    float4 rxA2 = prow[h * 4 + 2];
    float4 rxA3 = prow[h * 4 + 3];
    float4 rxB0 = prow[8 + h * 4 + 0];
    float4 rxB1 = prow[8 + h * 4 + 1];
    float4 rxB2 = prow[8 + h * 4 + 2];
    float4 rxB3 = prow[8 + h * 4 + 3];

    float4* sWf4 = reinterpret_cast<float4*>(sW);
    sWf4[tid]       = wT2f4[tid];
    sWf4[256 + tid] = wT2f4[256 + tid];

    if (tid < 64) {
        sB[tid] = bias2[tid];
        double mean = static_cast<double>(statsIn[tid]) / static_cast<double>(kNRows);
        double var  = static_cast<double>(statsIn[64 + tid]) / static_cast<double>(kNRows) - mean * mean;
        double rstd = 1.0 / sqrt(var + 1e-5);
        float g = static_cast<float>(rstd) * gamma1[tid];
        sG[tid] = g;
        sH[tid] = beta1[tid] - static_cast<float>(mean) * g;
        sWx[tid]       = w1[tid * 67 + 0];
        sWx[64 + tid]  = w1[tid * 67 + 1];
        sWx[128 + tid] = w1[tid * 67 + 2];
        sWx[192 + tid] = bias1[tid];
    }
    if (tid < 128) sStat[tid] = 0.0f;

    float dx = dd.x, dy = dd.y, dz = dd.z;

    // stage chunk 0 activations (needs sG/sH -> barrier first)
    __syncthreads();
    #pragma unroll
    for (int mm = 0; mm < 4; mm++) {
        float4 v = (mm == 0) ? rxA0 : (mm == 1) ? rxA1 : (mm == 2) ? rxA2 : rxA3;
        int jj = h * 4 + mm;
        int kg = jj * 4;
        int kl = jj * 4;
        float z0  = v.x + dx * sWx[kg + 0] + dy * sWx[64 + kg + 0] + dz * sWx[128 + kg + 0] + sWx[192 + kg + 0];
        float z1v = v.y + dx * sWx[kg + 1] + dy * sWx[64 + kg + 1] + dz * sWx[128 + kg + 1] + sWx[192 + kg + 1];
        float z2v = v.z + dx * sWx[kg + 2] + dy * sWx[64 + kg + 2] + dz * sWx[128 + kg + 2] + sWx[192 + kg + 2];
        float z3v = v.w + dx * sWx[kg + 3] + dy * sWx[64 + kg + 3] + dz * sWx[128 + kg + 3] + sWx[192 + kg + 3];
        xT[(kl + 0) * 128 + r] = fmaxf(z0  * sG[kg + 0] + sH[kg + 0], 0.0f);
        xT[(kl + 1) * 128 + r] = fmaxf(z1v * sG[kg + 1] + sH[kg + 1], 0.0f);
        xT[(kl + 2) * 128 + r] = fmaxf(z2v * sG[kg + 2] + sH[kg + 2], 0.0f);
        xT[(kl + 3) * 128 + r] = fmaxf(z3v * sG[kg + 3] + sH[kg + 3], 0.0f);
    }
    // prefetch chunk-1 weights
    float4 w1p0 = wT2f4[512 + tid];
    float4 w1p1 = wT2f4[768 + tid];
    __syncthreads();

    float acc[8][4];
    #pragma unroll
    for (int i = 0; i < 8; i++)
        #pragma unroll
        for (int j = 0; j < 4; j++) acc[i][j] = sB[tx * 4 + j];

    // compute chunk 0
    for (int k = 0; k < 32; k++) {
        const float* xk = &xT[k * 128 + ty * 8];
        const float* wk = &sW[k * 64 + tx * 4];
        float w0 = wk[0], w1v = wk[1], w2v = wk[2], w3v = wk[3];
        #pragma unroll
        for (int i = 0; i < 8; i++) {
            float xv = xk[i];
            acc[i][0] += xv * w0;
            acc[i][1] += xv * w1v;
            acc[i][2] += xv * w2v;
            acc[i][3] += xv * w3v;
        }
    }
    __syncthreads();

    // stage chunk 1 (activations from regs, weights from prefetch regs)
    #pragma unroll
    for (int mm = 0; mm < 4; mm++) {
        float4 v = (mm == 0) ? rxB0 : (mm == 1) ? rxB1 : (mm == 2) ? rxB2 : rxB3;
        int jj = h * 4 + mm;
        int kg = 32 + jj * 4;
        int kl = jj * 4;
        float z0  = v.x + dx * sWx[kg + 0] + dy * sWx[64 + kg + 0] + dz * sWx[128 + kg + 0] + sWx[192 + kg + 0];
        float z1v = v.y + dx * sWx[kg + 1] + dy * sWx[64 + kg + 1] + dz * sWx[128 + kg + 1] + sWx[192 + kg + 1];
        float z2v = v.z + dx * sWx[kg + 2] + dy * sWx[64 + kg + 2] + dz * sWx[128 + kg + 2] + sWx[192 + kg + 2];
        float z3v = v.w + dx * sWx[kg + 3] + dy * sWx[64 + kg + 3] + dz * sWx[128 + kg + 3] + sWx[192 + kg + 3];
        xT[(kl + 0) * 128 + r] = fmaxf(z0  * sG[kg + 0] + sH[kg + 0], 0.0f);
        xT[(kl + 1) * 128 + r] = fmaxf(z1v * sG[kg + 1] + sH[kg + 1], 0.0f);
        xT[(kl + 2) * 128 + r] = fmaxf(z2v * sG[kg + 2] + sH[kg + 2], 0.0f);
        xT[(kl + 3) * 128 + r] = fmaxf(z3v * sG[kg + 3] + sH[kg + 3], 0.0f);
    }
    sWf4[tid]       = w1p0;
    sWf4[256 + tid] = w1p1;
    __syncthreads();

    // compute chunk 1
    for (int k = 0; k < 32; k++) {
        const float* xk = &xT[k * 128 + ty * 8];
        const float* wk = &sW[k * 64 + tx * 4];
        float w0 = wk[0], w1v = wk[1], w2v = wk[2], w3v = wk[3];
        #pragma unroll
        for (int i = 0; i < 8; i++) {
            float xv = xk[i];
            acc[i][0] += xv * w0;
            acc[i][1] += xv * w1v;
            acc[i][2] += xv * w2v;
            acc[i][3] += xv * w3v;
        }
    }

    float s[4] = {0.f, 0.f, 0.f, 0.f};
    float q[4] = {0.f, 0.f, 0.f, 0.f};
    #pragma unroll
    for (int i = 0; i < 8; i++) {
        int row = R0 + ty * 8 + i;
        z2[static_cast<size_t>(row) * 16 + tx] =
            make_float4(acc[i][0], acc[i][1], acc[i][2], acc[i][3]);
        #pragma unroll
        for (int j = 0; j < 4; j++) {
            s[j] += acc[i][j];
            q[j] += acc[i][j] * acc[i][j];
        }
    }
    int lane = tid & 63;
    #pragma unroll
    for (int j = 0; j < 4; j++) {
        s[j] += __shfl_xor(s[j], 16); q[j] += __shfl_xor(q[j], 16);
        s[j] += __shfl_xor(s[j], 32); q[j] += __shfl_xor(q[j], 32);
    }
    if (lane < 16) {
        #pragma unroll
        for (int j = 0; j < 4; j++) {
            atomicAdd(&sStat[tx * 4 + j],      s[j]);
            atomicAdd(&sStat[64 + tx * 4 + j], q[j]);
        }
    }
    __syncthreads();
    if (tid < 128) {
        atomicAdd(&statsOut[tid], sStat[tid]);
    }
}

// ---------------------------------------------------------------- layer 3
// Full z2 row in regs; weights per 32-k chunk from wT3 (chunk-1 prefetched
// during chunk-0 compute); split column tile (2-way LDS, conflict-free);
// pre-BN wave max-pool; fused BN3 stats.
__global__ __launch_bounds__(256) void ssaLayer3Kernel(
    const float4* z2, const float4* wT3f4, const float* bias3,
    const float* gamma2, const float* beta2, const float* statsIn,
    float* poolMax, float* statsOut)
{
    __shared__ __align__(16) float xT[32 * 128];   // 16 KB
    __shared__ __align__(16) float sW[32 * 128];   // 16 KB (one chunk)
    __shared__ float sB[128];
    __shared__ float sG[64];
    __shared__ float sH[64];
    __shared__ float sStat[256];
    int tid = static_cast<int>(threadIdx.x);
    int R0  = static_cast<int>(blockIdx.x) * 128;
    int ty  = tid >> 4;
    int tx  = tid & 15;
    int r   = tid & 127;
    int h   = tid >> 7;

    const float4* zr = z2 + static_cast<size_t>(R0 + r) * 16;

    float4 rxA0 = zr[h * 4 + 0];
    float4 rxA1 = zr[h * 4 + 1];
    float4 rxA2 = zr[h * 4 + 2];
    float4 rxA3 = zr[h * 4 + 3];
    float4 rxB0 = zr[8 + h * 4 + 0];
    float4 rxB1 = zr[8 + h * 4 + 1];
    float4 rxB2 = zr[8 + h * 4 + 2];
    float4 rxB3 = zr[8 + h * 4 + 3];

    float4* sWf4 = reinterpret_cast<float4*>(sW);
    #pragma unroll
    for (int q2 = 0; q2 < 4; q2++) {
        sWf4[q2 * 256 + tid] = wT3f4[q2 * 256 + tid];
    }

    if (tid < 64) {
        double mean = static_cast<double>(statsIn[tid]) / static_cast<double>(kNRows);
        double var  = static_cast<double>(statsIn[64 + tid]) / static_cast<double>(kNRows) - mean * mean;
        double rstd = 1.0 / sqrt(var + 1e-5);
        float g = static_cast<float>(rstd) * gamma2[tid];
        sG[tid] = g;
        sH[tid] = beta2[tid] - static_cast<float>(mean) * g;
    }
    if (tid < 128) sB[tid] = bias3[tid];
    sStat[tid] = 0.0f;
    __syncthreads();

    // stage chunk 0 activations
    #pragma unroll
    for (int mm = 0; mm < 4; mm++) {
        float4 v = (mm == 0) ? rxA0 : (mm == 1) ? rxA1 : (mm == 2) ? rxA2 : rxA3;
        int jj = h * 4 + mm;
        int kg = jj * 4;
        int kl = jj * 4;
        xT[(kl + 0) * 128 + r] = fmaxf(v.x * sG[kg + 0] + sH[kg + 0], 0.0f);
        xT[(kl + 1) * 128 + r] = fmaxf(v.y * sG[kg + 1] + sH[kg + 1], 0.0f);
        xT[(kl + 2) * 128 + r] = fmaxf(v.z * sG[kg + 2] + sH[kg + 2], 0.0f);
        xT[(kl + 3) * 128 + r] = fmaxf(v.w * sG[kg + 3] + sH[kg + 3], 0.0f);
    }
    // prefetch chunk-1 weights
    float4 w1p0 = wT3f4[1024 + tid];
    float4 w1p1 = wT3f4[1280 + tid];
    float4 w1p2 = wT3f4[1536 + tid];
    float4 w1p3 = wT3f4[1792 + tid];
    __syncthreads();

    float acc[8][8];
    #pragma unroll
    for (int i = 0; i < 8; i++) {
        #pragma unroll
        for (int j = 0; j < 4; j++) {
            acc[i][j]     = sB[tx * 4 + j];
            acc[i][4 + j] = sB[64 + tx * 4 + j];
        }
    }

    // compute chunk 0
    for (int k = 0; k < 32; k++) {
        const float* xk = &xT[k * 128 + ty * 8];
        const float* wk = &sW[k * 128];
        float wv[8];
        #pragma unroll
        for (int j = 0; j < 4; j++) wv[j] = wk[tx * 4 + j];
        #pragma unroll
        for (int j = 0; j < 4; j++) wv[4 + j] = wk[64 + tx * 4 + j];
        #pragma unroll
        for (int i = 0; i < 8; i++) {
            float xv = xk[i];
            #pragma unroll
            for (int j = 0; j < 8; j++) {
                acc[i][j] += xv * wv[j];
            }
        }
    }
    __syncthreads();

    // stage chunk 1 (activations + weights from regs, no global wait)
    #pragma unroll
    for (int mm = 0; mm < 4; mm++) {
        float4 v = (mm == 0) ? rxB0 : (mm == 1) ? rxB1 : (mm == 2) ? rxB2 : rxB3;
        int jj = h * 4 + mm;
        int kg = 32 + jj * 4;
        int kl = jj * 4;
        xT[(kl + 0) * 128 + r] = fmaxf(v.x * sG[kg + 0] + sH[kg + 0], 0.0f);
        xT[(kl + 1) * 128 + r] = fmaxf(v.y * sG[kg + 1] + sH[kg + 1], 0.0f);
        xT[(kl + 2) * 128 + r] = fmaxf(v.z * sG[kg + 2] + sH[kg + 2], 0.0f);
        xT[(kl + 3) * 128 + r] = fmaxf(v.w * sG[kg + 3] + sH[kg + 3], 0.0f);
    }
    sWf4[tid]        = w1p0;
    sWf4[256 + tid]  = w1p1;
    sWf4[512 + tid]  = w1p2;
    sWf4[768 + tid]  = w1p3;
    __syncthreads();

    // compute chunk 1
    for (int k = 0; k < 32; k++) {
        const float* xk = &xT[k * 128 + ty * 8];
        const float* wk = &sW[k * 128];
        float wv[8];
        #pragma unroll
        for (int j = 0; j < 4; j++) wv[j] = wk[tx * 4 + j];
        #pragma unroll
        for (int j = 0; j < 4; j++) wv[4 + j] = wk[64 + tx * 4 + j];
        #pragma unroll
        for (int i = 0; i < 8; i++) {
            float xv = xk[i];
            #pragma unroll
            for (int j = 0; j < 8; j++) {
                acc[i][j] += xv * wv[j];
            }
        }
    }

    // pooling (max over the wave's 32 rows) + stats
    int lane = tid & 63;
    int grp  = static_cast<int>(blockIdx.x) * 4 + (ty >> 2);
    float mx[8];
    float s[8];
    float q[8];
    #pragma unroll
    for (int j = 0; j < 8; j++) {
        mx[j] = acc[0][j];
        s[j]  = 0.0f;
        q[j]  = 0.0f;
    }
    #pragma unroll
    for (int i = 0; i < 8; i++)
        #pragma unroll
        for (int j = 0; j < 8; j++) {
            float v = acc[i][j];
            mx[j] = fmaxf(mx[j], v);
            s[j] += v;
            q[j] += v * v;
        }
    #pragma unroll
    for (int j = 0; j < 8; j++) {
        mx[j] = fmaxf(mx[j], __shfl_xor(mx[j], 16));
        mx[j] = fmaxf(mx[j], __shfl_xor(mx[j], 32));
        s[j] += __shfl_xor(s[j], 16); q[j] += __shfl_xor(q[j], 16);
        s[j] += __shfl_xor(s[j], 32); q[j] += __shfl_xor(q[j], 32);
    }
    if (lane < 16) {
        #pragma unroll
        for (int j = 0; j < 8; j++) {
            int c = (j < 4) ? (tx * 4 + j) : (64 + tx * 4 + (j - 4));
            poolMax[static_cast<size_t>(grp) * kC3 + c] = mx[j];
            atomicAdd(&sStat[c],       s[j]);
            atomicAdd(&sStat[128 + c], q[j]);
        }
    }
    __syncthreads();
    atomicAdd(&statsOut[tid], sStat[tid]);
}

// ---------------------------------------------------------------- finalize
__global__ __launch_bounds__(256) void ssaFinalKernel(
    const float* poolMax, const float* sum3, const float* sq3,
    const float* gamma3, const float* beta3, float* outTail)
{
    __shared__ float sG[128];
    __shared__ float sH[128];
    int tid = static_cast<int>(threadIdx.x);
    if (tid < 128) {
        double mean = static_cast<double>(sum3[tid]) / static_cast<double>(kNRows);
        double var  = static_cast<double>(sq3[tid]) / static_cast<double>(kNRows) - mean * mean;
        double rstd = 1.0 / sqrt(var + 1e-5);
        float g = static_cast<float>(rstd) * gamma3[tid];
        sG[tid] = g;
        sH[tid] = beta3[tid] - static_cast<float>(mean) * g;
    }
    __syncthreads();
    int e  = static_cast<int>(blockIdx.x) * 256 + tid;
    int b  = e >> 18;
    int ch = (e >> 11) & 127;
    int s  = e & 2047;
    size_t gi = static_cast<size_t>(b * kNS + s) * kC3 + ch;
    outTail[e] = fmaxf(poolMax[gi] * sG[ch] + sH[ch], 0.0f);
}

// ---------------------------------------------------------------- launch
static inline void* ssaWsAt(void* base, size_t byteOff)
{
    return static_cast<void*>(static_cast<char*>(base) + byteOff);
}

extern "C" __attribute__((visibility("default"), used))
void kernel_launch(void* const* d_in, const int* in_sizes, int n_in,
                   void* d_out, int out_size, void* d_ws, size_t ws_size,
                   hipStream_t stream)
{
    static_cast<void>(in_sizes);
    static_cast<void>(n_in);
    static_cast<void>(out_size);
    static_cast<void>(ws_size);

    const float*  xyz    = static_cast<const float*>(d_in[0]);
    const float4* points = static_cast<const float4*>(d_in[1]);
    const float*  newXyz = static_cast<const float*>(d_in[2]);
    const float*  w1Ptr  = static_cast<const float*>(d_in[3]);
    const float*  b1Ptr  = static_cast<const float*>(d_in[4]);
    const float*  g1Ptr  = static_cast<const float*>(d_in[5]);
    const float*  e1Ptr  = static_cast<const float*>(d_in[6]);
    const float*  w2Ptr  = static_cast<const float*>(d_in[7]);
    const float*  b2Ptr  = static_cast<const float*>(d_in[8]);
    const float*  g2Ptr  = static_cast<const float*>(d_in[9]);
    const float*  e2Ptr  = static_cast<const float*>(d_in[10]);
    const float*  w3Ptr  = static_cast<const float*>(d_in[11]);
    const float*  b3Ptr  = static_cast<const float*>(d_in[12]);
    const float*  g3Ptr  = static_cast<const float*>(d_in[13]);
    const float*  e3Ptr  = static_cast<const float*>(d_in[14]);

    float4* soa   = static_cast<float4*>(ssaWsAt(d_ws, 0));           //  1,048,576 B
    int*    bIdx  = static_cast<int*>(ssaWsAt(d_ws, 1048576));        //  1,048,576 B
    float4* bDxy  = static_cast<float4*>(ssaWsAt(d_ws, 2097152));     //  4,194,304 B
    float4* p1    = static_cast<float4*>(ssaWsAt(d_ws, 6291456));     // 16,777,216 B
    float4* z2    = static_cast<float4*>(ssaWsAt(d_ws, 23068672));    // 67,108,864 B
    float*  pMax  = static_cast<float*>(ssaWsAt(d_ws, 90177536));     //  4,194,304 B
    float*  stats = static_cast<float*>(ssaWsAt(d_ws, 94371840));     //      2,048 B
    float*  wT3   = static_cast<float*>(ssaWsAt(d_ws, 94373888));     //     32,768 B
    float*  wT2   = static_cast<float*>(ssaWsAt(d_ws, 94406656));     //     16,384 B
    float*  outF  = static_cast<float*>(d_out);

    ssaPrepKernel<<<256, 256, 0, stream>>>(xyz, newXyz, w2Ptr, w3Ptr,
                                           outF, soa, stats, wT2, wT3);
    ssaBallKernel<<<kNGrp / 4, 256, 0, stream>>>(newXyz, soa, bIdx, bDxy);
    ssaP1Kernel<<<kNPtsTot / 128, 256, 0, stream>>>(points, w1Ptr, p1);
    ssaStats1Kernel<<<kNRows / 128, 256, 0, stream>>>(p1, w1Ptr, b1Ptr, bIdx, bDxy, stats);
    ssaLayer2Kernel<<<kNRows / 128, 256, 0, stream>>>(p1, w1Ptr, b1Ptr,
                                                      reinterpret_cast<const float4*>(wT2),
                                                      b2Ptr, g1Ptr, e1Ptr, stats, bIdx, bDxy,
                                                      z2, stats + 128);
    ssaLayer3Kernel<<<kNRows / 128, 256, 0, stream>>>(z2,
                                                      reinterpret_cast<const float4*>(wT3),
                                                      b3Ptr, g2Ptr, e2Ptr,
                                                      stats + 128, pMax, stats + 256);
    ssaFinalKernel<<<kNB * kC3 * kNS / 256, 256, 0, stream>>>(pMax, stats + 256, stats + 384,
                                                              g3Ptr, e3Ptr,
                                                              outF + kNB * kNS * 3);
}

// Round 5
// 359.205 us; speedup vs baseline: 1.2202x; 1.0063x over previous
//
#include <hip/hip_runtime.h>

// SingleScaleSA: B=4, N=16384, S=2048, K=32, mlp 64 -> 64 -> 128, radius 0.2.
// Round 27: r24 (349 us) structure, plus ONE-chunk-ahead register prefetch in
// L2/L3 with bounded live sets (r26's full-row capture hit VGPR=256 / 10% occ):
//  - chunk-0 acts -> 4 f4 regs -> LDS; SAME regs reloaded with chunk-1 acts
//    (L3: +4 f4 weight regs) before chunk-0 compute; chunk-1 staging is pure
//    reg->LDS (no global drain at the mid barriers).
//  - weights from pre-transposed wT2/wT3, coalesced float4.
//  - ball/P1/stats1/final and all epilogues identical to r24.
constexpr int kNB      = 4;
constexpr int kNPts    = 16384;
constexpr int kNS      = 2048;
constexpr int kNK      = 32;
constexpr int kC3      = 128;
constexpr int kNRows   = kNB * kNS * kNK;   // 262144
constexpr int kNGrp    = kNB * kNS;         // 8192
constexpr int kNPtsTot = kNB * kNPts;       // 65536
constexpr double kR2   = 0.2 * 0.2;

// ---------------------------------------------------------------- prep
__global__ __launch_bounds__(256) void ssaPrepKernel(
    const float* xyz, const float* newXyz, const float* w2, const float* w3,
    float* outHead, float4* soa, float* stats, float* wT2, float* wT3)
{
    int t = static_cast<int>(blockIdx.x) * 256 + static_cast<int>(threadIdx.x);
    if (t < kNPtsTot) {
        soa[t] = make_float4(xyz[t * 3 + 0], xyz[t * 3 + 1], xyz[t * 3 + 2], 0.0f);
    }
    if (t < kNB * kNS * 3) {
        outHead[t] = newXyz[t];
    }
    if (t < 512) {
        stats[t] = 0.0f;
    }
    if (t < 64 * 128) {
        int k = t >> 7;
        int c = t & 127;
        wT3[t] = w3[c * 64 + k];
    }
    if (t < 64 * 64) {
        int k = t >> 6;
        int c = t & 63;
        wT2[t] = w2[c * 64 + k];
    }
}

// ---------------------------------------------------------------- ball query
__global__ __launch_bounds__(256) void ssaBallKernel(
    const float* newXyz, const float4* soa,
    int* ballIdx, float4* ballDxyz)
{
    int tid  = static_cast<int>(threadIdx.x);
    int w    = (static_cast<int>(blockIdx.x) * 256 + tid) >> 6;
    int lane = tid & 63;
    int b    = w >> 11;
    float qx = newXyz[w * 3 + 0];
    float qy = newXyz[w * 3 + 1];
    float qz = newXyz[w * 3 + 2];
    double qxd = static_cast<double>(qx);
    double qyd = static_cast<double>(qy);
    double qzd = static_cast<double>(qz);
    double qq  = qxd * qxd + qyd * qyd + qzd * qzd;
    const float4* sp = soa + b * kNPts;
    int*    oi = ballIdx  + static_cast<size_t>(w) * kNK;
    float4* od = ballDxyz + static_cast<size_t>(w) * kNK;

    int cnt = 0;
    int firstN = -1;
    float fdx = 0.0f, fdy = 0.0f, fdz = 0.0f;
    for (int base = 0; base < kNPts && cnt < kNK; base += 64) {
        float4 p = sp[base + lane];
        double pxd = static_cast<double>(p.x);
        double pyd = static_cast<double>(p.y);
        double pzd = static_cast<double>(p.z);
        double d2  = qq + (pxd * pxd + pyd * pyd + pzd * pzd)
                   - 2.0 * (qxd * pxd + qyd * pyd + qzd * pzd);
        bool hit   = (d2 <= kR2);
        unsigned long long m = __ballot(hit);
        int pos = cnt + __popcll(m & ((1ull << lane) - 1ull));
        if (hit && pos < kNK) {
            float dx = p.x - qx;
            float dy = p.y - qy;
            float dz = p.z - qz;
            oi[pos] = base + lane;
            od[pos] = make_float4(dx, dy, dz, 0.0f);
            if (pos == 0) { firstN = base + lane; fdx = dx; fdy = dy; fdz = dz; }
        }
        cnt += __popcll(m);
    }
    if (cnt < kNK) {
        unsigned long long hv = __ballot(firstN >= 0);
        int fi;
        float dx, dy, dz;
        if (hv != 0ull) {
            int src = __builtin_ctzll(hv);
            fi = __shfl(firstN, src);
            dx = __shfl(fdx, src);
            dy = __shfl(fdy, src);
            dz = __shfl(fdz, src);
        } else {
            float4 p = sp[kNPts - 1];
            fi = kNPts - 1;
            dx = p.x - qx;
            dy = p.y - qy;
            dz = p.z - qz;
        }
        for (int p2 = cnt + lane; p2 < kNK; p2 += 64) {
            oi[p2] = fi;
            od[p2] = make_float4(dx, dy, dz, 0.0f);
        }
    }
}

// ---------------------------------------------------------------- P1 GEMM
// P1[b,n,:] = points[b,n,:] @ W1[:,3:67]^T  — 65536 rows, K=64, 64 cols.
__global__ __launch_bounds__(256) void ssaP1Kernel(
    const float4* points, const float* w1, float4* p1)
{
    __shared__ float xT[32 * 128];
    __shared__ float sW[64 * 64];
    int tid = static_cast<int>(threadIdx.x);
    int R0  = static_cast<int>(blockIdx.x) * 128;
    int ty  = tid >> 4;
    int tx  = tid & 15;
    int r   = tid & 127;
    int h   = tid >> 7;

    for (int i = tid; i < 64 * 64; i += 256) {
        int k = i >> 6;
        int c = i & 63;
        sW[i] = w1[c * 67 + 3 + k];
    }
    __syncthreads();

    float acc[8][4];
    #pragma unroll
    for (int i = 0; i < 8; i++)
        #pragma unroll
        for (int j = 0; j < 4; j++) acc[i][j] = 0.0f;

    const float4* prow = points + static_cast<size_t>(R0 + r) * 16;

    #pragma unroll 1
    for (int ch = 0; ch < 2; ch++) {
        if (ch > 0) __syncthreads();
        for (int j = h * 4; j < h * 4 + 4; j++) {
            float4 v = prow[ch * 8 + j];
            int k = j * 4;
            xT[(k + 0) * 128 + r] = v.x;
            xT[(k + 1) * 128 + r] = v.y;
            xT[(k + 2) * 128 + r] = v.z;
            xT[(k + 3) * 128 + r] = v.w;
        }
        __syncthreads();

        int kw = ch * 32;
        for (int k = 0; k < 32; k++) {
            const float* xk = &xT[k * 128 + ty * 8];
            const float* wk = &sW[(kw + k) * 64 + tx * 4];
            float w0 = wk[0], w1v = wk[1], w2v = wk[2], w3v = wk[3];
            #pragma unroll
            for (int i = 0; i < 8; i++) {
                float xv = xk[i];
                acc[i][0] += xv * w0;
                acc[i][1] += xv * w1v;
                acc[i][2] += xv * w2v;
                acc[i][3] += xv * w3v;
            }
        }
    }

    #pragma unroll
    for (int i = 0; i < 8; i++) {
        p1[static_cast<size_t>(R0 + ty * 8 + i) * 16 + tx] =
            make_float4(acc[i][0], acc[i][1], acc[i][2], acc[i][3]);
    }
}

// ---------------------------------------------------------------- BN1 stats
__global__ __launch_bounds__(256) void ssaStats1Kernel(
    const float4* p1, const float* w1, const float* bias1,
    const int* ballIdx, const float4* ballDxyz, float* stats)
{
    __shared__ float sXyz[3 * 128];
    __shared__ int   sGi[128];
    __shared__ float sWx[256];
    __shared__ float sStat[128];
    int tid = static_cast<int>(threadIdx.x);
    int R0  = static_cast<int>(blockIdx.x) * 128;
    int ty  = tid >> 4;
    int tx  = tid & 15;

    if (tid < 128) {
        sGi[tid] = ballIdx[R0 + tid];
        float4 d = ballDxyz[R0 + tid];
        sXyz[tid]       = d.x;
        sXyz[128 + tid] = d.y;
        sXyz[256 + tid] = d.z;
        sStat[tid] = 0.0f;
    }
    if (tid < 64) {
        sWx[tid]       = w1[tid * 67 + 0];
        sWx[64 + tid]  = w1[tid * 67 + 1];
        sWx[128 + tid] = w1[tid * 67 + 2];
        sWx[192 + tid] = bias1[tid];
    }
    __syncthreads();

    int b = R0 >> 16;
    const float4* pb = p1 + static_cast<size_t>(b) * kNPts * 16;
    int c0 = tx * 4;
    float wa[4], wb[4], wc[4], bb[4];
    #pragma unroll
    for (int j = 0; j < 4; j++) {
        wa[j] = sWx[c0 + j];
        wb[j] = sWx[64 + c0 + j];
        wc[j] = sWx[128 + c0 + j];
        bb[j] = sWx[192 + c0 + j];
    }

    float s[4] = {0.f, 0.f, 0.f, 0.f};
    float q[4] = {0.f, 0.f, 0.f, 0.f};
    #pragma unroll
    for (int i = 0; i < 8; i++) {
        int r2 = ty * 8 + i;
        float4 v = pb[static_cast<size_t>(sGi[r2]) * 16 + tx];
        float dx = sXyz[r2], dy = sXyz[128 + r2], dz = sXyz[256 + r2];
        float vv[4] = {v.x, v.y, v.z, v.w};
        #pragma unroll
        for (int j = 0; j < 4; j++) {
            float val = vv[j] + dx * wa[j] + dy * wb[j] + dz * wc[j] + bb[j];
            s[j] += val;
            q[j] += val * val;
        }
    }
    int lane = tid & 63;
    #pragma unroll
    for (int j = 0; j < 4; j++) {
        s[j] += __shfl_xor(s[j], 16); q[j] += __shfl_xor(q[j], 16);
        s[j] += __shfl_xor(s[j], 32); q[j] += __shfl_xor(q[j], 32);
    }
    if (lane < 16) {
        #pragma unroll
        for (int j = 0; j < 4; j++) {
            atomicAdd(&sStat[tx * 4 + j],      s[j]);
            atomicAdd(&sStat[64 + tx * 4 + j], q[j]);
        }
    }
    __syncthreads();
    if (tid < 128) {
        atomicAdd(&stats[tid], sStat[tid]);
    }
}

// ---------------------------------------------------------------- layer 2
// relu(bn1(P1[gi] + dxyz@W1xyz + b1)) @ W2; full W2 in LDS; acts one chunk
// ahead in 4 f4 regs (reused).
__global__ __launch_bounds__(256) void ssaLayer2Kernel(
    const float4* p1, const float* w1, const float* bias1,
    const float4* wT2f4, const float* bias2,
    const float* gamma1, const float* beta1, const float* statsIn,
    const int* ballIdx, const float4* ballDxyz,
    float4* z2, float* statsOut)
{
    __shared__ __align__(16) float xT[32 * 128];   // 16 KB
    __shared__ __align__(16) float sW[64 * 64];    // 16 KB (full W2^T)
    __shared__ float sWx[256];
    __shared__ float sB[64];
    __shared__ float sG[64];
    __shared__ float sH[64];
    __shared__ float sStat[128];
    int tid = static_cast<int>(threadIdx.x);
    int R0  = static_cast<int>(blockIdx.x) * 128;
    int ty  = tid >> 4;
    int tx  = tid & 15;
    int r   = tid & 127;
    int h   = tid >> 7;

    int gi = ballIdx[R0 + r];
    float4 dd = ballDxyz[R0 + r];
    int b = R0 >> 16;
    const float4* prow = p1 + (static_cast<size_t>(b) * kNPts + static_cast<size_t>(gi)) * 16;

    // chunk-0 acts -> regs; full weights -> LDS (coalesced f4)
    float4 a0 = prow[h * 4 + 0];
    float4 a1 = prow[h * 4 + 1];
    float4 a2 = prow[h * 4 + 2];
    float4 a3 = prow[h * 4 + 3];
    float4* sWf4 = reinterpret_cast<float4*>(sW);
    #pragma unroll
    for (int q2 = 0; q2 < 4; q2++) {
        sWf4[q2 * 256 + tid] = wT2f4[q2 * 256 + tid];
    }

    if (tid < 64) {
        sB[tid] = bias2[tid];
        double mean = static_cast<double>(statsIn[tid]) / static_cast<double>(kNRows);
        double var  = static_cast<double>(statsIn[64 + tid]) / static_cast<double>(kNRows) - mean * mean;
        double rstd = 1.0 / sqrt(var + 1e-5);
        float g = static_cast<float>(rstd) * gamma1[tid];
        sG[tid] = g;
        sH[tid] = beta1[tid] - static_cast<float>(mean) * g;
        sWx[tid]       = w1[tid * 67 + 0];
        sWx[64 + tid]  = w1[tid * 67 + 1];
        sWx[128 + tid] = w1[tid * 67 + 2];
        sWx[192 + tid] = bias1[tid];
    }
    if (tid < 128) sStat[tid] = 0.0f;
    __syncthreads();

    float dx = dd.x, dy = dd.y, dz = dd.z;
    auto stage = [&](float4 v, int jj, int kgOff) {
        int kg = kgOff + jj * 4;
        int kl = jj * 4;
        float z0  = v.x + dx * sWx[kg + 0] + dy * sWx[64 + kg + 0] + dz * sWx[128 + kg + 0] + sWx[192 + kg + 0];
        float z1v = v.y + dx * sWx[kg + 1] + dy * sWx[64 + kg + 1] + dz * sWx[128 + kg + 1] + sWx[192 + kg + 1];
        float z2v = v.z + dx * sWx[kg + 2] + dy * sWx[64 + kg + 2] + dz * sWx[128 + kg + 2] + sWx[192 + kg + 2];
        float z3v = v.w + dx * sWx[kg + 3] + dy * sWx[64 + kg + 3] + dz * sWx[128 + kg + 3] + sWx[192 + kg + 3];
        xT[(kl + 0) * 128 + r] = fmaxf(z0  * sG[kg + 0] + sH[kg + 0], 0.0f);
        xT[(kl + 1) * 128 + r] = fmaxf(z1v * sG[kg + 1] + sH[kg + 1], 0.0f);
        xT[(kl + 2) * 128 + r] = fmaxf(z2v * sG[kg + 2] + sH[kg + 2], 0.0f);
        xT[(kl + 3) * 128 + r] = fmaxf(z3v * sG[kg + 3] + sH[kg + 3], 0.0f);
    };

    // stage chunk 0, then reuse a0..a3 for chunk-1 prefetch
    stage(a0, h * 4 + 0, 0);
    stage(a1, h * 4 + 1, 0);
    stage(a2, h * 4 + 2, 0);
    stage(a3, h * 4 + 3, 0);
    a0 = prow[8 + h * 4 + 0];
    a1 = prow[8 + h * 4 + 1];
    a2 = prow[8 + h * 4 + 2];
    a3 = prow[8 + h * 4 + 3];
    __syncthreads();

    float acc[8][4];
    #pragma unroll
    for (int i = 0; i < 8; i++)
        #pragma unroll
        for (int j = 0; j < 4; j++) acc[i][j] = sB[tx * 4 + j];

    // compute chunk 0
    for (int k = 0; k < 32; k++) {
        const float* xk = &xT[k * 128 + ty * 8];
        const float* wk = &sW[k * 64 + tx * 4];
        float w0 = wk[0], w1v = wk[1], w2v = wk[2], w3v = wk[3];
        #pragma unroll
        for (int i = 0; i < 8; i++) {
            float xv = xk[i];
            acc[i][0] += xv * w0;
            acc[i][1] += xv * w1v;
            acc[i][2] += xv * w2v;
            acc[i][3] += xv * w3v;
        }
    }
    __syncthreads();

    // stage chunk 1 (regs -> LDS only)
    stage(a0, h * 4 + 0, 32);
    stage(a1, h * 4 + 1, 32);
    stage(a2, h * 4 + 2, 32);
    stage(a3, h * 4 + 3, 32);
    __syncthreads();

    // compute chunk 1
    for (int k = 0; k < 32; k++) {
        const float* xk = &xT[k * 128 + ty * 8];
        const float* wk = &sW[(32 + k) * 64 + tx * 4];
        float w0 = wk[0], w1v = wk[1], w2v = wk[2], w3v = wk[3];
        #pragma unroll
        for (int i = 0; i < 8; i++) {
            float xv = xk[i];
            acc[i][0] += xv * w0;
            acc[i][1] += xv * w1v;
            acc[i][2] += xv * w2v;
            acc[i][3] += xv * w3v;
        }
    }

    float s[4] = {0.f, 0.f, 0.f, 0.f};
    float q[4] = {0.f, 0.f, 0.f, 0.f};
    #pragma unroll
    for (int i = 0; i < 8; i++) {
        int row = R0 + ty * 8 + i;
        z2[static_cast<size_t>(row) * 16 + tx] =
            make_float4(acc[i][0], acc[i][1], acc[i][2], acc[i][3]);
        #pragma unroll
        for (int j = 0; j < 4; j++) {
            s[j] += acc[i][j];
            q[j] += acc[i][j] * acc[i][j];
        }
    }
    int lane = tid & 63;
    #pragma unroll
    for (int j = 0; j < 4; j++) {
        s[j] += __shfl_xor(s[j], 16); q[j] += __shfl_xor(q[j], 16);
        s[j] += __shfl_xor(s[j], 32); q[j] += __shfl_xor(q[j], 32);
    }
    if (lane < 16) {
        #pragma unroll
        for (int j = 0; j < 4; j++) {
            atomicAdd(&sStat[tx * 4 + j],      s[j]);
            atomicAdd(&sStat[64 + tx * 4 + j], q[j]);
        }
    }
    __syncthreads();
    if (tid < 128) {
        atomicAdd(&statsOut[tid], sStat[tid]);
    }
}

// ---------------------------------------------------------------- layer 3
// bn2+relu on staged z2 chunks; weights per 32-k chunk (chunk-1 acts+weights
// prefetched into regs during chunk-0 compute); split column tile; pre-BN
// wave max-pool; fused BN3 stats.
__global__ __launch_bounds__(256) void ssaLayer3Kernel(
    const float4* z2, const float4* wT3f4, const float* bias3,
    const float* gamma2, const float* beta2, const float* statsIn,
    float* poolMax, float* statsOut)
{
    __shared__ __align__(16) float xT[32 * 128];   // 16 KB
    __shared__ __align__(16) float sW[32 * 128];   // 16 KB (one chunk)
    __shared__ float sB[128];
    __shared__ float sG[64];
    __shared__ float sH[64];
    __shared__ float sStat[256];
    int tid = static_cast<int>(threadIdx.x);
    int R0  = static_cast<int>(blockIdx.x) * 128;
    int ty  = tid >> 4;
    int tx  = tid & 15;
    int r   = tid & 127;
    int h   = tid >> 7;

    const float4* zr = z2 + static_cast<size_t>(R0 + r) * 16;

    // chunk-0 acts -> regs; chunk-0 weights -> LDS
    float4 a0 = zr[h * 4 + 0];
    float4 a1 = zr[h * 4 + 1];
    float4 a2 = zr[h * 4 + 2];
    float4 a3 = zr[h * 4 + 3];
    float4* sWf4 = reinterpret_cast<float4*>(sW);
    #pragma unroll
    for (int q2 = 0; q2 < 4; q2++) {
        sWf4[q2 * 256 + tid] = wT3f4[q2 * 256 + tid];
    }

    if (tid < 64) {
        double mean = static_cast<double>(statsIn[tid]) / static_cast<double>(kNRows);
        double var  = static_cast<double>(statsIn[64 + tid]) / static_cast<double>(kNRows) - mean * mean;
        double rstd = 1.0 / sqrt(var + 1e-5);
        float g = static_cast<float>(rstd) * gamma2[tid];
        sG[tid] = g;
        sH[tid] = beta2[tid] - static_cast<float>(mean) * g;
    }
    if (tid < 128) sB[tid] = bias3[tid];
    sStat[tid] = 0.0f;
    __syncthreads();

    auto stage = [&](float4 v, int jj, int kgOff) {
        int kg = kgOff + jj * 4;
        int kl = jj * 4;
        xT[(kl + 0) * 128 + r] = fmaxf(v.x * sG[kg + 0] + sH[kg + 0], 0.0f);
        xT[(kl + 1) * 128 + r] = fmaxf(v.y * sG[kg + 1] + sH[kg + 1], 0.0f);
        xT[(kl + 2) * 128 + r] = fmaxf(v.z * sG[kg + 2] + sH[kg + 2], 0.0f);
        xT[(kl + 3) * 128 + r] = fmaxf(v.w * sG[kg + 3] + sH[kg + 3], 0.0f);
    };

    // stage chunk 0; prefetch chunk-1 acts (reuse regs) + weights
    stage(a0, h * 4 + 0, 0);
    stage(a1, h * 4 + 1, 0);
    stage(a2, h * 4 + 2, 0);
    stage(a3, h * 4 + 3, 0);
    a0 = zr[8 + h * 4 + 0];
    a1 = zr[8 + h * 4 + 1];
    a2 = zr[8 + h * 4 + 2];
    a3 = zr[8 + h * 4 + 3];
    float4 w0 = wT3f4[1024 + tid];
    float4 w1p = wT3f4[1280 + tid];
    float4 w2p = wT3f4[1536 + tid];
    float4 w3p = wT3f4[1792 + tid];
    __syncthreads();

    float acc[8][8];
    #pragma unroll
    for (int i = 0; i < 8; i++) {
        #pragma unroll
        for (int j = 0; j < 4; j++) {
            acc[i][j]     = sB[tx * 4 + j];
            acc[i][4 + j] = sB[64 + tx * 4 + j];
        }
    }

    // compute chunk 0
    for (int k = 0; k < 32; k++) {
        const float* xk = &xT[k * 128 + ty * 8];
        const float* wk = &sW[k * 128];
        float wv[8];
        #pragma unroll
        for (int j = 0; j < 4; j++) wv[j] = wk[tx * 4 + j];
        #pragma unroll
        for (int j = 0; j < 4; j++) wv[4 + j] = wk[64 + tx * 4 + j];
        #pragma unroll
        for (int i = 0; i < 8; i++) {
            float xv = xk[i];
            #pragma unroll
            for (int j = 0; j < 8; j++) {
                acc[i][j] += xv * wv[j];
            }
        }
    }
    __syncthreads();

    // stage chunk 1 (all from regs)
    stage(a0, h * 4 + 0, 32);
    stage(a1, h * 4 + 1, 32);
    stage(a2, h * 4 + 2, 32);
    stage(a3, h * 4 + 3, 32);
    sWf4[tid]       = w0;
    sWf4[256 + tid] = w1p;
    sWf4[512 + tid] = w2p;
    sWf4[768 + tid] = w3p;
    __syncthreads();

    // compute chunk 1
    for (int k = 0; k < 32; k++) {
        const float* xk = &xT[k * 128 + ty * 8];
        const float* wk = &sW[k * 128];
        float wv[8];
        #pragma unroll
        for (int j = 0; j < 4; j++) wv[j] = wk[tx * 4 + j];
        #pragma unroll
        for (int j = 0; j < 4; j++) wv[4 + j] = wk[64 + tx * 4 + j];
        #pragma unroll
        for (int i = 0; i < 8; i++) {
            float xv = xk[i];
            #pragma unroll
            for (int j = 0; j < 8; j++) {
                acc[i][j] += xv * wv[j];
            }
        }
    }

    // pooling (max over the wave's 32 rows) + stats
    int lane = tid & 63;
    int grp  = static_cast<int>(blockIdx.x) * 4 + (ty >> 2);
    float mx[8];
    float s[8];
    float q[8];
    #pragma unroll
    for (int j = 0; j < 8; j++) {
        mx[j] = acc[0][j];
        s[j]  = 0.0f;
        q[j]  = 0.0f;
    }
    #pragma unroll
    for (int i = 0; i < 8; i++)
        #pragma unroll
        for (int j = 0; j < 8; j++) {
            float v = acc[i][j];
            mx[j] = fmaxf(mx[j], v);
            s[j] += v;
            q[j] += v * v;
        }
    #pragma unroll
    for (int j = 0; j < 8; j++) {
        mx[j] = fmaxf(mx[j], __shfl_xor(mx[j], 16));
        mx[j] = fmaxf(mx[j], __shfl_xor(mx[j], 32));
        s[j] += __shfl_xor(s[j], 16); q[j] += __shfl_xor(q[j], 16);
        s[j] += __shfl_xor(s[j], 32); q[j] += __shfl_xor(q[j], 32);
    }
    if (lane < 16) {
        #pragma unroll
        for (int j = 0; j < 8; j++) {
            int c = (j < 4) ? (tx * 4 + j) : (64 + tx * 4 + (j - 4));
            poolMax[static_cast<size_t>(grp) * kC3 + c] = mx[j];
            atomicAdd(&sStat[c],       s[j]);
            atomicAdd(&sStat[128 + c], q[j]);
        }
    }
    __syncthreads();
    atomicAdd(&statsOut[tid], sStat[tid]);
}

// ---------------------------------------------------------------- finalize
__global__ __launch_bounds__(256) void ssaFinalKernel(
    const float* poolMax, const float* sum3, const float* sq3,
    const float* gamma3, const float* beta3, float* outTail)
{
    __shared__ float sG[128];
    __shared__ float sH[128];
    int tid = static_cast<int>(threadIdx.x);
    if (tid < 128) {
        double mean = static_cast<double>(sum3[tid]) / static_cast<double>(kNRows);
        double var  = static_cast<double>(sq3[tid]) / static_cast<double>(kNRows) - mean * mean;
        double rstd = 1.0 / sqrt(var + 1e-5);
        float g = static_cast<float>(rstd) * gamma3[tid];
        sG[tid] = g;
        sH[tid] = beta3[tid] - static_cast<float>(mean) * g;
    }
    __syncthreads();
    int e  = static_cast<int>(blockIdx.x) * 256 + tid;
    int b  = e >> 18;
    int ch = (e >> 11) & 127;
    int s  = e & 2047;
    size_t gi = static_cast<size_t>(b * kNS + s) * kC3 + ch;
    outTail[e] = fmaxf(poolMax[gi] * sG[ch] + sH[ch], 0.0f);
}

// ---------------------------------------------------------------- launch
static inline void* ssaWsAt(void* base, size_t byteOff)
{
    return static_cast<void*>(static_cast<char*>(base) + byteOff);
}

extern "C" __attribute__((visibility("default"), used))
void kernel_launch(void* const* d_in, const int* in_sizes, int n_in,
                   void* d_out, int out_size, void* d_ws, size_t ws_size,
                   hipStream_t stream)
{
    static_cast<void>(in_sizes);
    static_cast<void>(n_in);
    static_cast<void>(out_size);
    static_cast<void>(ws_size);

    const float*  xyz    = static_cast<const float*>(d_in[0]);
    const float4* points = static_cast<const float4*>(d_in[1]);
    const float*  newXyz = static_cast<const float*>(d_in[2]);
    const float*  w1Ptr  = static_cast<const float*>(d_in[3]);
    const float*  b1Ptr  = static_cast<const float*>(d_in[4]);
    const float*  g1Ptr  = static_cast<const float*>(d_in[5]);
    const float*  e1Ptr  = static_cast<const float*>(d_in[6]);
    const float*  w2Ptr  = static_cast<const float*>(d_in[7]);
    const float*  b2Ptr  = static_cast<const float*>(d_in[8]);
    const float*  g2Ptr  = static_cast<const float*>(d_in[9]);
    const float*  e2Ptr  = static_cast<const float*>(d_in[10]);
    const float*  w3Ptr  = static_cast<const float*>(d_in[11]);
    const float*  b3Ptr  = static_cast<const float*>(d_in[12]);
    const float*  g3Ptr  = static_cast<const float*>(d_in[13]);
    const float*  e3Ptr  = static_cast<const float*>(d_in[14]);

    float4* soa   = static_cast<float4*>(ssaWsAt(d_ws, 0));           //  1,048,576 B
    int*    bIdx  = static_cast<int*>(ssaWsAt(d_ws, 1048576));        //  1,048,576 B
    float4* bDxy  = static_cast<float4*>(ssaWsAt(d_ws, 2097152));     //  4,194,304 B
    float4* p1    = static_cast<float4*>(ssaWsAt(d_ws, 6291456));     // 16,777,216 B
    float4* z2    = static_cast<float4*>(ssaWsAt(d_ws, 23068672));    // 67,108,864 B
    float*  pMax  = static_cast<float*>(ssaWsAt(d_ws, 90177536));     //  4,194,304 B
    float*  stats = static_cast<float*>(ssaWsAt(d_ws, 94371840));     //      2,048 B
    float*  wT3   = static_cast<float*>(ssaWsAt(d_ws, 94373888));     //     32,768 B
    float*  wT2   = static_cast<float*>(ssaWsAt(d_ws, 94406656));     //     16,384 B
    float*  outF  = static_cast<float*>(d_out);

    ssaPrepKernel<<<256, 256, 0, stream>>>(xyz, newXyz, w2Ptr, w3Ptr,
                                           outF, soa, stats, wT2, wT3);
    ssaBallKernel<<<kNGrp / 4, 256, 0, stream>>>(newXyz, soa, bIdx, bDxy);
    ssaP1Kernel<<<kNPtsTot / 128, 256, 0, stream>>>(points, w1Ptr, p1);
    ssaStats1Kernel<<<kNRows / 128, 256, 0, stream>>>(p1, w1Ptr, b1Ptr, bIdx, bDxy, stats);
    ssaLayer2Kernel<<<kNRows / 128, 256, 0, stream>>>(p1, w1Ptr, b1Ptr,
                                                      reinterpret_cast<const float4*>(wT2),
                                                      b2Ptr, g1Ptr, e1Ptr, stats, bIdx, bDxy,
                                                      z2, stats + 128);
    ssaLayer3Kernel<<<kNRows / 128, 256, 0, stream>>>(z2,
                                                      reinterpret_cast<const float4*>(wT3),
                                                      b3Ptr, g2Ptr, e2Ptr,
                                                      stats + 128, pMax, stats + 256);
    ssaFinalKernel<<<kNB * kC3 * kNS / 256, 256, 0, stream>>>(pMax, stats + 256, stats + 384,
                                                              g3Ptr, e3Ptr,
                                                              outF + kNB * kNS * 3);
}

// Round 6
// 332.604 us; speedup vs baseline: 1.3178x; 1.0800x over previous
//
#include <hip/hip_runtime.h>

// SingleScaleSA: B=4, N=16384, S=2048, K=32, mlp 64 -> 64 -> 128, radius 0.2.
// Round 28: base = r24 (349 us, verified). ONE change: stats1 kernel deleted,
// BN1 stats fused into the ball kernel (wave owns its group's 32 idx+dxyz in
// LDS; coalesced 256B p1-row reads, lane=channel). L2/L3/P1/final byte-
// identical to r24. Lesson from r26/r27: reg-prefetch staging patterns make
// hipcc balloon VGPR to 250+ (occupancy 10%) -- do not pipeline these kernels
// at source level.
constexpr int kNB      = 4;
constexpr int kNPts    = 16384;
constexpr int kNS      = 2048;
constexpr int kNK      = 32;
constexpr int kC3      = 128;
constexpr int kNRows   = kNB * kNS * kNK;   // 262144
constexpr int kNGrp    = kNB * kNS;         // 8192
constexpr int kNPtsTot = kNB * kNPts;       // 65536
constexpr double kR2   = 0.2 * 0.2;

// ---------------------------------------------------------------- prep
__global__ __launch_bounds__(256) void ssaPrepKernel(
    const float* xyz, const float* newXyz, const float* w2, const float* w3,
    float* outHead, float4* soa, float* stats, float* wT2, float* wT3)
{
    int t = static_cast<int>(blockIdx.x) * 256 + static_cast<int>(threadIdx.x);
    if (t < kNPtsTot) {
        soa[t] = make_float4(xyz[t * 3 + 0], xyz[t * 3 + 1], xyz[t * 3 + 2], 0.0f);
    }
    if (t < kNB * kNS * 3) {
        outHead[t] = newXyz[t];
    }
    if (t < 512) {
        stats[t] = 0.0f;
    }
    if (t < 64 * 128) {
        int k = t >> 7;
        int c = t & 127;
        wT3[t] = w3[c * 64 + k];
    }
    if (t < 64 * 64) {
        int k = t >> 6;
        int c = t & 63;
        wT2[t] = w2[c * 64 + k];
    }
}

// ---------------------------------------------------------------- P1 GEMM
// P1[b,n,:] = points[b,n,:] @ W1[:,3:67]^T  — 65536 rows, K=64, 64 cols.
__global__ __launch_bounds__(256) void ssaP1Kernel(
    const float4* points, const float* w1, float4* p1)
{
    __shared__ float xT[32 * 128];
    __shared__ float sW[64 * 64];
    int tid = static_cast<int>(threadIdx.x);
    int R0  = static_cast<int>(blockIdx.x) * 128;
    int ty  = tid >> 4;
    int tx  = tid & 15;
    int r   = tid & 127;
    int h   = tid >> 7;

    for (int i = tid; i < 64 * 64; i += 256) {
        int k = i >> 6;
        int c = i & 63;
        sW[i] = w1[c * 67 + 3 + k];
    }
    __syncthreads();

    float acc[8][4];
    #pragma unroll
    for (int i = 0; i < 8; i++)
        #pragma unroll
        for (int j = 0; j < 4; j++) acc[i][j] = 0.0f;

    const float4* prow = points + static_cast<size_t>(R0 + r) * 16;

    #pragma unroll 1
    for (int ch = 0; ch < 2; ch++) {
        if (ch > 0) __syncthreads();
        for (int j = h * 4; j < h * 4 + 4; j++) {
            float4 v = prow[ch * 8 + j];
            int k = j * 4;
            xT[(k + 0) * 128 + r] = v.x;
            xT[(k + 1) * 128 + r] = v.y;
            xT[(k + 2) * 128 + r] = v.z;
            xT[(k + 3) * 128 + r] = v.w;
        }
        __syncthreads();

        int kw = ch * 32;
        for (int k = 0; k < 32; k++) {
            const float* xk = &xT[k * 128 + ty * 8];
            const float* wk = &sW[(kw + k) * 64 + tx * 4];
            float w0 = wk[0], w1v = wk[1], w2v = wk[2], w3v = wk[3];
            #pragma unroll
            for (int i = 0; i < 8; i++) {
                float xv = xk[i];
                acc[i][0] += xv * w0;
                acc[i][1] += xv * w1v;
                acc[i][2] += xv * w2v;
                acc[i][3] += xv * w3v;
            }
        }
    }

    #pragma unroll
    for (int i = 0; i < 8; i++) {
        p1[static_cast<size_t>(R0 + ty * 8 + i) * 16 + tx] =
            make_float4(acc[i][0], acc[i][1], acc[i][2], acc[i][3]);
    }
}

// ---------------------------------------------------------------- ball query + BN1 stats
__global__ __launch_bounds__(256) void ssaBallKernel(
    const float* newXyz, const float4* soa, const float* w1, const float* bias1,
    const float* p1f, int* ballIdx, float4* ballDxyz, float* stats)
{
    __shared__ int   sIdx[4][32];
    __shared__ float sDx[4][32];
    __shared__ float sDy[4][32];
    __shared__ float sDz[4][32];
    __shared__ float sStat[128];
    int tid  = static_cast<int>(threadIdx.x);
    int wv   = tid >> 6;
    int lane = tid & 63;
    int w    = static_cast<int>(blockIdx.x) * 4 + wv;
    int b    = w >> 11;
    if (tid < 128) sStat[tid] = 0.0f;
    __syncthreads();

    float qx = newXyz[w * 3 + 0];
    float qy = newXyz[w * 3 + 1];
    float qz = newXyz[w * 3 + 2];
    double qxd = static_cast<double>(qx);
    double qyd = static_cast<double>(qy);
    double qzd = static_cast<double>(qz);
    double qq  = qxd * qxd + qyd * qyd + qzd * qzd;
    const float4* sp = soa + b * kNPts;
    int*    oi = ballIdx  + static_cast<size_t>(w) * kNK;
    float4* od = ballDxyz + static_cast<size_t>(w) * kNK;

    int cnt = 0;
    int firstN = -1;
    float fdx = 0.0f, fdy = 0.0f, fdz = 0.0f;
    for (int base = 0; base < kNPts && cnt < kNK; base += 64) {
        float4 p = sp[base + lane];
        double pxd = static_cast<double>(p.x);
        double pyd = static_cast<double>(p.y);
        double pzd = static_cast<double>(p.z);
        double d2  = qq + (pxd * pxd + pyd * pyd + pzd * pzd)
                   - 2.0 * (qxd * pxd + qyd * pyd + qzd * pzd);
        bool hit   = (d2 <= kR2);
        unsigned long long m = __ballot(hit);
        int pos = cnt + __popcll(m & ((1ull << lane) - 1ull));
        if (hit && pos < kNK) {
            float dx = p.x - qx;
            float dy = p.y - qy;
            float dz = p.z - qz;
            oi[pos] = base + lane;
            od[pos] = make_float4(dx, dy, dz, 0.0f);
            sIdx[wv][pos] = base + lane;
            sDx[wv][pos] = dx;
            sDy[wv][pos] = dy;
            sDz[wv][pos] = dz;
            if (pos == 0) { firstN = base + lane; fdx = dx; fdy = dy; fdz = dz; }
        }
        cnt += __popcll(m);
    }
    if (cnt < kNK) {
        unsigned long long hv = __ballot(firstN >= 0);
        int fi;
        float dx, dy, dz;
        if (hv != 0ull) {
            int src = __builtin_ctzll(hv);
            fi = __shfl(firstN, src);
            dx = __shfl(fdx, src);
            dy = __shfl(fdy, src);
            dz = __shfl(fdz, src);
        } else {
            float4 p = sp[kNPts - 1];
            fi = kNPts - 1;
            dx = p.x - qx;
            dy = p.y - qy;
            dz = p.z - qz;
        }
        for (int p2 = cnt + lane; p2 < kNK; p2 += 64) {
            oi[p2] = fi;
            od[p2] = make_float4(dx, dy, dz, 0.0f);
            sIdx[wv][p2] = fi;
            sDx[wv][p2] = dx;
            sDy[wv][p2] = dy;
            sDz[wv][p2] = dz;
        }
    }

    // BN1 stats: lane = channel; z1 = P1[gi,c] + dxyz.W1xyz[:,c] + b1[c].
    float wa  = w1[lane * 67 + 0];
    float wbv = w1[lane * 67 + 1];
    float wc  = w1[lane * 67 + 2];
    float bb  = bias1[lane];
    const float* pb = p1f + static_cast<size_t>(b) * kNPts * 64;
    float s = 0.0f, q = 0.0f;
    #pragma unroll 4
    for (int k2 = 0; k2 < kNK; k2++) {
        int g = sIdx[wv][k2];
        float val = pb[static_cast<size_t>(g) * 64 + lane]
                  + sDx[wv][k2] * wa + sDy[wv][k2] * wbv + sDz[wv][k2] * wc + bb;
        s += val;
        q += val * val;
    }
    atomicAdd(&sStat[lane], s);
    atomicAdd(&sStat[64 + lane], q);
    __syncthreads();
    if (tid < 128) {
        atomicAdd(&stats[tid], sStat[tid]);
    }
}

// ---------------------------------------------------------------- layer 2
// Input reconstructed on the fly: relu(bn1(P1[gi] + dxyz@W1xyz + b1)).
__global__ __launch_bounds__(256) void ssaLayer2Kernel(
    const float4* p1, const float* w1, const float* bias1,
    const float* w2, const float* bias2,
    const float* gamma1, const float* beta1, const float* statsIn,
    const int* ballIdx, const float4* ballDxyz,
    float4* z2, float* statsOut)
{
    __shared__ float xT[32 * 128];    // 16 KB
    __shared__ float sW[64 * 64];     // 16 KB
    __shared__ float sXyz[3 * 128];
    __shared__ float sWx[256];
    __shared__ float sB[64];
    __shared__ float sG[64];
    __shared__ float sH[64];
    __shared__ float sStat[128];
    int tid = static_cast<int>(threadIdx.x);
    int R0  = static_cast<int>(blockIdx.x) * 128;
    int ty  = tid >> 4;
    int tx  = tid & 15;
    int r   = tid & 127;
    int h   = tid >> 7;

    for (int i = tid; i < 64 * 64; i += 256) {
        int k = i >> 6;
        int c = i & 63;
        sW[i] = w2[c * 64 + k];
    }
    if (tid < 64) {
        sB[tid] = bias2[tid];
        double mean = static_cast<double>(statsIn[tid]) / static_cast<double>(kNRows);
        double var  = static_cast<double>(statsIn[64 + tid]) / static_cast<double>(kNRows) - mean * mean;
        double rstd = 1.0 / sqrt(var + 1e-5);
        float g = static_cast<float>(rstd) * gamma1[tid];
        sG[tid] = g;
        sH[tid] = beta1[tid] - static_cast<float>(mean) * g;
        sWx[tid]       = w1[tid * 67 + 0];
        sWx[64 + tid]  = w1[tid * 67 + 1];
        sWx[128 + tid] = w1[tid * 67 + 2];
        sWx[192 + tid] = bias1[tid];
    }
    if (tid < 128) sStat[tid] = 0.0f;
    if (h == 0) {
        float4 d = ballDxyz[R0 + r];
        sXyz[r]       = d.x;
        sXyz[128 + r] = d.y;
        sXyz[256 + r] = d.z;
    }
    __syncthreads();

    float acc[8][4];
    #pragma unroll
    for (int i = 0; i < 8; i++)
        #pragma unroll
        for (int j = 0; j < 4; j++) acc[i][j] = sB[tx * 4 + j];

    int gi = ballIdx[R0 + r];
    int b  = R0 >> 16;
    const float4* prow = p1 + (static_cast<size_t>(b) * kNPts + static_cast<size_t>(gi)) * 16;
    float dx = sXyz[r], dy = sXyz[128 + r], dz = sXyz[256 + r];

    #pragma unroll 1
    for (int ch = 0; ch < 2; ch++) {
        if (ch > 0) __syncthreads();
        for (int j = h * 4; j < h * 4 + 4; j++) {
            float4 v = prow[ch * 8 + j];
            int kg = ch * 32 + j * 4;
            int k  = j * 4;
            float z0 = v.x + dx * sWx[kg + 0] + dy * sWx[64 + kg + 0] + dz * sWx[128 + kg + 0] + sWx[192 + kg + 0];
            float z1v = v.y + dx * sWx[kg + 1] + dy * sWx[64 + kg + 1] + dz * sWx[128 + kg + 1] + sWx[192 + kg + 1];
            float z2v = v.z + dx * sWx[kg + 2] + dy * sWx[64 + kg + 2] + dz * sWx[128 + kg + 2] + sWx[192 + kg + 2];
            float z3v = v.w + dx * sWx[kg + 3] + dy * sWx[64 + kg + 3] + dz * sWx[128 + kg + 3] + sWx[192 + kg + 3];
            xT[(k + 0) * 128 + r] = fmaxf(z0  * sG[kg + 0] + sH[kg + 0], 0.0f);
            xT[(k + 1) * 128 + r] = fmaxf(z1v * sG[kg + 1] + sH[kg + 1], 0.0f);
            xT[(k + 2) * 128 + r] = fmaxf(z2v * sG[kg + 2] + sH[kg + 2], 0.0f);
            xT[(k + 3) * 128 + r] = fmaxf(z3v * sG[kg + 3] + sH[kg + 3], 0.0f);
        }
        __syncthreads();

        int kw = 3 + ch * 32;
        static_cast<void>(kw);
        int kwBase = ch * 32;
        for (int k = 0; k < 32; k++) {
            const float* xk = &xT[k * 128 + ty * 8];
            const float* wk = &sW[(kwBase + k) * 64 + tx * 4];
            float w0 = wk[0], w1v = wk[1], w2v = wk[2], w3v = wk[3];
            #pragma unroll
            for (int i = 0; i < 8; i++) {
                float xv = xk[i];
                acc[i][0] += xv * w0;
                acc[i][1] += xv * w1v;
                acc[i][2] += xv * w2v;
                acc[i][3] += xv * w3v;
            }
        }
    }

    float s[4] = {0.f, 0.f, 0.f, 0.f};
    float q[4] = {0.f, 0.f, 0.f, 0.f};
    #pragma unroll
    for (int i = 0; i < 8; i++) {
        int row = R0 + ty * 8 + i;
        z2[static_cast<size_t>(row) * 16 + tx] =
            make_float4(acc[i][0], acc[i][1], acc[i][2], acc[i][3]);
        #pragma unroll
        for (int j = 0; j < 4; j++) {
            s[j] += acc[i][j];
            q[j] += acc[i][j] * acc[i][j];
        }
    }
    int lane = tid & 63;
    #pragma unroll
    for (int j = 0; j < 4; j++) {
        s[j] += __shfl_xor(s[j], 16); q[j] += __shfl_xor(q[j], 16);
        s[j] += __shfl_xor(s[j], 32); q[j] += __shfl_xor(q[j], 32);
    }
    if (lane < 16) {
        #pragma unroll
        for (int j = 0; j < 4; j++) {
            atomicAdd(&sStat[tx * 4 + j],      s[j]);
            atomicAdd(&sStat[64 + tx * 4 + j], q[j]);
        }
    }
    __syncthreads();
    if (tid < 128) {
        atomicAdd(&statsOut[tid], sStat[tid]);
    }
}

// ---------------------------------------------------------------- layer 3
// sW staged per 32-k chunk (LDS ~35K -> 4 blocks/CU); split column tile
// (tx*4 and 64+tx*4) so ds_read_b128 of weights is 2-way (free) not 4-way.
__global__ __launch_bounds__(256) void ssaLayer3Kernel(
    const float4* z2, const float* wT3, const float* bias3,
    const float* gamma2, const float* beta2, const float* statsIn,
    float* poolMax, float* statsOut)
{
    __shared__ float xT[32 * 128];    // 16 KB
    __shared__ float sW[32 * 128];    // 16 KB (one 32-k chunk)
    __shared__ float sB[128];
    __shared__ float sG[64];
    __shared__ float sH[64];
    __shared__ float sStat[256];
    int tid = static_cast<int>(threadIdx.x);
    int R0  = static_cast<int>(blockIdx.x) * 128;
    int ty  = tid >> 4;
    int tx  = tid & 15;
    int r   = tid & 127;
    int h   = tid >> 7;

    if (tid < 64) {
        double mean = static_cast<double>(statsIn[tid]) / static_cast<double>(kNRows);
        double var  = static_cast<double>(statsIn[64 + tid]) / static_cast<double>(kNRows) - mean * mean;
        double rstd = 1.0 / sqrt(var + 1e-5);
        float g = static_cast<float>(rstd) * gamma2[tid];
        sG[tid] = g;
        sH[tid] = beta2[tid] - static_cast<float>(mean) * g;
    }
    if (tid < 128) sB[tid] = bias3[tid];
    sStat[tid] = 0.0f;
    __syncthreads();

    float acc[8][8];
    #pragma unroll
    for (int i = 0; i < 8; i++) {
        #pragma unroll
        for (int j = 0; j < 4; j++) {
            acc[i][j]     = sB[tx * 4 + j];
            acc[i][4 + j] = sB[64 + tx * 4 + j];
        }
    }

    const float4* zr = z2 + static_cast<size_t>(R0 + r) * 16;

    #pragma unroll 1
    for (int ch = 0; ch < 2; ch++) {
        if (ch > 0) __syncthreads();
        for (int j = h * 4; j < h * 4 + 4; j++) {
            float4 v = zr[ch * 8 + j];
            int kg = ch * 32 + j * 4;
            int k  = j * 4;
            xT[(k + 0) * 128 + r] = fmaxf(v.x * sG[kg + 0] + sH[kg + 0], 0.0f);
            xT[(k + 1) * 128 + r] = fmaxf(v.y * sG[kg + 1] + sH[kg + 1], 0.0f);
            xT[(k + 2) * 128 + r] = fmaxf(v.z * sG[kg + 2] + sH[kg + 2], 0.0f);
            xT[(k + 3) * 128 + r] = fmaxf(v.w * sG[kg + 3] + sH[kg + 3], 0.0f);
        }
        for (int i = tid; i < 32 * 128; i += 256) {
            sW[i] = wT3[ch * 32 * 128 + i];
        }
        __syncthreads();

        for (int k = 0; k < 32; k++) {
            const float* xk = &xT[k * 128 + ty * 8];
            const float* wk = &sW[k * 128];
            float wv[8];
            #pragma unroll
            for (int j = 0; j < 4; j++) wv[j] = wk[tx * 4 + j];
            #pragma unroll
            for (int j = 0; j < 4; j++) wv[4 + j] = wk[64 + tx * 4 + j];
            #pragma unroll
            for (int i = 0; i < 8; i++) {
                float xv = xk[i];
                #pragma unroll
                for (int j = 0; j < 8; j++) {
                    acc[i][j] += xv * wv[j];
                }
            }
        }
    }

    // pooling (max over the wave's 32 rows) + stats
    int lane = tid & 63;
    int grp  = static_cast<int>(blockIdx.x) * 4 + (ty >> 2);
    float mx[8];
    float s[8];
    float q[8];
    #pragma unroll
    for (int j = 0; j < 8; j++) {
        mx[j] = acc[0][j];
        s[j]  = 0.0f;
        q[j]  = 0.0f;
    }
    #pragma unroll
    for (int i = 0; i < 8; i++)
        #pragma unroll
        for (int j = 0; j < 8; j++) {
            float v = acc[i][j];
            mx[j] = fmaxf(mx[j], v);
            s[j] += v;
            q[j] += v * v;
        }
    #pragma unroll
    for (int j = 0; j < 8; j++) {
        mx[j] = fmaxf(mx[j], __shfl_xor(mx[j], 16));
        mx[j] = fmaxf(mx[j], __shfl_xor(mx[j], 32));
        s[j] += __shfl_xor(s[j], 16); q[j] += __shfl_xor(q[j], 16);
        s[j] += __shfl_xor(s[j], 32); q[j] += __shfl_xor(q[j], 32);
    }
    if (lane < 16) {
        #pragma unroll
        for (int j = 0; j < 8; j++) {
            int c = (j < 4) ? (tx * 4 + j) : (64 + tx * 4 + (j - 4));
            poolMax[static_cast<size_t>(grp) * kC3 + c] = mx[j];
            atomicAdd(&sStat[c],       s[j]);
            atomicAdd(&sStat[128 + c], q[j]);
        }
    }
    __syncthreads();
    atomicAdd(&statsOut[tid], sStat[tid]);
}

// ---------------------------------------------------------------- finalize
__global__ __launch_bounds__(256) void ssaFinalKernel(
    const float* poolMax, const float* sum3, const float* sq3,
    const float* gamma3, const float* beta3, float* outTail)
{
    __shared__ float sG[128];
    __shared__ float sH[128];
    int tid = static_cast<int>(threadIdx.x);
    if (tid < 128) {
        double mean = static_cast<double>(sum3[tid]) / static_cast<double>(kNRows);
        double var  = static_cast<double>(sq3[tid]) / static_cast<double>(kNRows) - mean * mean;
        double rstd = 1.0 / sqrt(var + 1e-5);
        float g = static_cast<float>(rstd) * gamma3[tid];
        sG[tid] = g;
        sH[tid] = beta3[tid] - static_cast<float>(mean) * g;
    }
    __syncthreads();
    int e  = static_cast<int>(blockIdx.x) * 256 + tid;
    int b  = e >> 18;
    int ch = (e >> 11) & 127;
    int s  = e & 2047;
    size_t gi = static_cast<size_t>(b * kNS + s) * kC3 + ch;
    outTail[e] = fmaxf(poolMax[gi] * sG[ch] + sH[ch], 0.0f);
}

// ---------------------------------------------------------------- launch
static inline void* ssaWsAt(void* base, size_t byteOff)
{
    return static_cast<void*>(static_cast<char*>(base) + byteOff);
}

extern "C" __attribute__((visibility("default"), used))
void kernel_launch(void* const* d_in, const int* in_sizes, int n_in,
                   void* d_out, int out_size, void* d_ws, size_t ws_size,
                   hipStream_t stream)
{
    static_cast<void>(in_sizes);
    static_cast<void>(n_in);
    static_cast<void>(out_size);
    static_cast<void>(ws_size);

    const float*  xyz    = static_cast<const float*>(d_in[0]);
    const float4* points = static_cast<const float4*>(d_in[1]);
    const float*  newXyz = static_cast<const float*>(d_in[2]);
    const float*  w1Ptr  = static_cast<const float*>(d_in[3]);
    const float*  b1Ptr  = static_cast<const float*>(d_in[4]);
    const float*  g1Ptr  = static_cast<const float*>(d_in[5]);
    const float*  e1Ptr  = static_cast<const float*>(d_in[6]);
    const float*  w2Ptr  = static_cast<const float*>(d_in[7]);
    const float*  b2Ptr  = static_cast<const float*>(d_in[8]);
    const float*  g2Ptr  = static_cast<const float*>(d_in[9]);
    const float*  e2Ptr  = static_cast<const float*>(d_in[10]);
    const float*  w3Ptr  = static_cast<const float*>(d_in[11]);
    const float*  b3Ptr  = static_cast<const float*>(d_in[12]);
    const float*  g3Ptr  = static_cast<const float*>(d_in[13]);
    const float*  e3Ptr  = static_cast<const float*>(d_in[14]);

    float4* soa   = static_cast<float4*>(ssaWsAt(d_ws, 0));           //  1,048,576 B
    int*    bIdx  = static_cast<int*>(ssaWsAt(d_ws, 1048576));        //  1,048,576 B
    float4* bDxy  = static_cast<float4*>(ssaWsAt(d_ws, 2097152));     //  4,194,304 B
    float4* p1    = static_cast<float4*>(ssaWsAt(d_ws, 6291456));     // 16,777,216 B
    float4* z2    = static_cast<float4*>(ssaWsAt(d_ws, 23068672));    // 67,108,864 B
    float*  pMax  = static_cast<float*>(ssaWsAt(d_ws, 90177536));     //  4,194,304 B
    float*  stats = static_cast<float*>(ssaWsAt(d_ws, 94371840));     //      2,048 B
    float*  wT3   = static_cast<float*>(ssaWsAt(d_ws, 94373888));     //     32,768 B
    float*  wT2   = static_cast<float*>(ssaWsAt(d_ws, 94406656));     //     16,384 B
    float*  outF  = static_cast<float*>(d_out);

    ssaPrepKernel<<<256, 256, 0, stream>>>(xyz, newXyz, w2Ptr, w3Ptr,
                                           outF, soa, stats, wT2, wT3);
    ssaP1Kernel<<<kNPtsTot / 128, 256, 0, stream>>>(points, w1Ptr, p1);
    ssaBallKernel<<<kNGrp / 4, 256, 0, stream>>>(newXyz, soa, w1Ptr, b1Ptr,
                                                 reinterpret_cast<const float*>(p1),
                                                 bIdx, bDxy, stats);
    ssaLayer2Kernel<<<kNRows / 128, 256, 0, stream>>>(p1, w1Ptr, b1Ptr, w2Ptr, b2Ptr,
                                                      g1Ptr, e1Ptr, stats, bIdx, bDxy,
                                                      z2, stats + 128);
    ssaLayer3Kernel<<<kNRows / 128, 256, 0, stream>>>(z2, wT3, b3Ptr, g2Ptr, e2Ptr,
                                                      stats + 128, pMax, stats + 256);
    ssaFinalKernel<<<kNB * kC3 * kNS / 256, 256, 0, stream>>>(pMax, stats + 256, stats + 384,
                                                              g3Ptr, e3Ptr,
                                                              outF + kNB * kNS * 3);
}

// Round 7
// 321.959 us; speedup vs baseline: 1.3614x; 1.0331x over previous
//
#include <hip/hip_runtime.h>

// SingleScaleSA: B=4, N=16384, S=2048, K=32, mlp 64 -> 64 -> 128, radius 0.2.
// Round 29: base = r28 (332.6 us). Occupancy push on the two GEMMs:
//  - L3: 4 phases x 16-k; xT/sW 8 KB each -> LDS ~18.4 KB -> 8 blocks/CU
//    (was 4). z2 read is a coalesced stream, so finer phasing is safe
//    (r25's failure was fragmenting L2's RANDOM gather -- not applicable).
//  - L2: sW staged per 32-k chunk from wT2 (coalesced) -> LDS 35->28 KB,
//    5 blocks/CU. Gather granularity untouched.
//  - NO register prefetch anywhere (r26/r27: hipcc balloons VGPR to 250+).
// Numerics: identical FMA accumulation order -> absmax unchanged.
constexpr int kNB      = 4;
constexpr int kNPts    = 16384;
constexpr int kNS      = 2048;
constexpr int kNK      = 32;
constexpr int kC3      = 128;
constexpr int kNRows   = kNB * kNS * kNK;   // 262144
constexpr int kNGrp    = kNB * kNS;         // 8192
constexpr int kNPtsTot = kNB * kNPts;       // 65536
constexpr double kR2   = 0.2 * 0.2;

// ---------------------------------------------------------------- prep
__global__ __launch_bounds__(256) void ssaPrepKernel(
    const float* xyz, const float* newXyz, const float* w2, const float* w3,
    float* outHead, float4* soa, float* stats, float* wT2, float* wT3)
{
    int t = static_cast<int>(blockIdx.x) * 256 + static_cast<int>(threadIdx.x);
    if (t < kNPtsTot) {
        soa[t] = make_float4(xyz[t * 3 + 0], xyz[t * 3 + 1], xyz[t * 3 + 2], 0.0f);
    }
    if (t < kNB * kNS * 3) {
        outHead[t] = newXyz[t];
    }
    if (t < 512) {
        stats[t] = 0.0f;
    }
    if (t < 64 * 128) {
        int k = t >> 7;
        int c = t & 127;
        wT3[t] = w3[c * 64 + k];
    }
    if (t < 64 * 64) {
        int k = t >> 6;
        int c = t & 63;
        wT2[t] = w2[c * 64 + k];
    }
}

// ---------------------------------------------------------------- P1 GEMM
// P1[b,n,:] = points[b,n,:] @ W1[:,3:67]^T  — 65536 rows, K=64, 64 cols.
__global__ __launch_bounds__(256) void ssaP1Kernel(
    const float4* points, const float* w1, float4* p1)
{
    __shared__ float xT[32 * 128];
    __shared__ float sW[64 * 64];
    int tid = static_cast<int>(threadIdx.x);
    int R0  = static_cast<int>(blockIdx.x) * 128;
    int ty  = tid >> 4;
    int tx  = tid & 15;
    int r   = tid & 127;
    int h   = tid >> 7;

    for (int i = tid; i < 64 * 64; i += 256) {
        int k = i >> 6;
        int c = i & 63;
        sW[i] = w1[c * 67 + 3 + k];
    }
    __syncthreads();

    float acc[8][4];
    #pragma unroll
    for (int i = 0; i < 8; i++)
        #pragma unroll
        for (int j = 0; j < 4; j++) acc[i][j] = 0.0f;

    const float4* prow = points + static_cast<size_t>(R0 + r) * 16;

    #pragma unroll 1
    for (int ch = 0; ch < 2; ch++) {
        if (ch > 0) __syncthreads();
        for (int j = h * 4; j < h * 4 + 4; j++) {
            float4 v = prow[ch * 8 + j];
            int k = j * 4;
            xT[(k + 0) * 128 + r] = v.x;
            xT[(k + 1) * 128 + r] = v.y;
            xT[(k + 2) * 128 + r] = v.z;
            xT[(k + 3) * 128 + r] = v.w;
        }
        __syncthreads();

        int kw = ch * 32;
        for (int k = 0; k < 32; k++) {
            const float* xk = &xT[k * 128 + ty * 8];
            const float* wk = &sW[(kw + k) * 64 + tx * 4];
            float w0 = wk[0], w1v = wk[1], w2v = wk[2], w3v = wk[3];
            #pragma unroll
            for (int i = 0; i < 8; i++) {
                float xv = xk[i];
                acc[i][0] += xv * w0;
                acc[i][1] += xv * w1v;
                acc[i][2] += xv * w2v;
                acc[i][3] += xv * w3v;
            }
        }
    }

    #pragma unroll
    for (int i = 0; i < 8; i++) {
        p1[static_cast<size_t>(R0 + ty * 8 + i) * 16 + tx] =
            make_float4(acc[i][0], acc[i][1], acc[i][2], acc[i][3]);
    }
}

// ---------------------------------------------------------------- ball query + BN1 stats
__global__ __launch_bounds__(256) void ssaBallKernel(
    const float* newXyz, const float4* soa, const float* w1, const float* bias1,
    const float* p1f, int* ballIdx, float4* ballDxyz, float* stats)
{
    __shared__ int   sIdx[4][32];
    __shared__ float sDx[4][32];
    __shared__ float sDy[4][32];
    __shared__ float sDz[4][32];
    __shared__ float sStat[128];
    int tid  = static_cast<int>(threadIdx.x);
    int wv   = tid >> 6;
    int lane = tid & 63;
    int w    = static_cast<int>(blockIdx.x) * 4 + wv;
    int b    = w >> 11;
    if (tid < 128) sStat[tid] = 0.0f;
    __syncthreads();

    float qx = newXyz[w * 3 + 0];
    float qy = newXyz[w * 3 + 1];
    float qz = newXyz[w * 3 + 2];
    double qxd = static_cast<double>(qx);
    double qyd = static_cast<double>(qy);
    double qzd = static_cast<double>(qz);
    double qq  = qxd * qxd + qyd * qyd + qzd * qzd;
    const float4* sp = soa + b * kNPts;
    int*    oi = ballIdx  + static_cast<size_t>(w) * kNK;
    float4* od = ballDxyz + static_cast<size_t>(w) * kNK;

    int cnt = 0;
    int firstN = -1;
    float fdx = 0.0f, fdy = 0.0f, fdz = 0.0f;
    for (int base = 0; base < kNPts && cnt < kNK; base += 64) {
        float4 p = sp[base + lane];
        double pxd = static_cast<double>(p.x);
        double pyd = static_cast<double>(p.y);
        double pzd = static_cast<double>(p.z);
        double d2  = qq + (pxd * pxd + pyd * pyd + pzd * pzd)
                   - 2.0 * (qxd * pxd + qyd * pyd + qzd * pzd);
        bool hit   = (d2 <= kR2);
        unsigned long long m = __ballot(hit);
        int pos = cnt + __popcll(m & ((1ull << lane) - 1ull));
        if (hit && pos < kNK) {
            float dx = p.x - qx;
            float dy = p.y - qy;
            float dz = p.z - qz;
            oi[pos] = base + lane;
            od[pos] = make_float4(dx, dy, dz, 0.0f);
            sIdx[wv][pos] = base + lane;
            sDx[wv][pos] = dx;
            sDy[wv][pos] = dy;
            sDz[wv][pos] = dz;
            if (pos == 0) { firstN = base + lane; fdx = dx; fdy = dy; fdz = dz; }
        }
        cnt += __popcll(m);
    }
    if (cnt < kNK) {
        unsigned long long hv = __ballot(firstN >= 0);
        int fi;
        float dx, dy, dz;
        if (hv != 0ull) {
            int src = __builtin_ctzll(hv);
            fi = __shfl(firstN, src);
            dx = __shfl(fdx, src);
            dy = __shfl(fdy, src);
            dz = __shfl(fdz, src);
        } else {
            float4 p = sp[kNPts - 1];
            fi = kNPts - 1;
            dx = p.x - qx;
            dy = p.y - qy;
            dz = p.z - qz;
        }
        for (int p2 = cnt + lane; p2 < kNK; p2 += 64) {
            oi[p2] = fi;
            od[p2] = make_float4(dx, dy, dz, 0.0f);
            sIdx[wv][p2] = fi;
            sDx[wv][p2] = dx;
            sDy[wv][p2] = dy;
            sDz[wv][p2] = dz;
        }
    }

    // BN1 stats: lane = channel; z1 = P1[gi,c] + dxyz.W1xyz[:,c] + b1[c].
    float wa  = w1[lane * 67 + 0];
    float wbv = w1[lane * 67 + 1];
    float wc  = w1[lane * 67 + 2];
    float bb  = bias1[lane];
    const float* pb = p1f + static_cast<size_t>(b) * kNPts * 64;
    float s = 0.0f, q = 0.0f;
    #pragma unroll 4
    for (int k2 = 0; k2 < kNK; k2++) {
        int g = sIdx[wv][k2];
        float val = pb[static_cast<size_t>(g) * 64 + lane]
                  + sDx[wv][k2] * wa + sDy[wv][k2] * wbv + sDz[wv][k2] * wc + bb;
        s += val;
        q += val * val;
    }
    atomicAdd(&sStat[lane], s);
    atomicAdd(&sStat[64 + lane], q);
    __syncthreads();
    if (tid < 128) {
        atomicAdd(&stats[tid], sStat[tid]);
    }
}

// ---------------------------------------------------------------- layer 2
// Input reconstructed on the fly: relu(bn1(P1[gi] + dxyz@W1xyz + b1)).
// sW staged per 32-k chunk from wT2 (coalesced) -> LDS ~28 KB, 5 blocks/CU.
__global__ __launch_bounds__(256) void ssaLayer2Kernel(
    const float4* p1, const float* w1, const float* bias1,
    const float* wT2, const float* bias2,
    const float* gamma1, const float* beta1, const float* statsIn,
    const int* ballIdx, const float4* ballDxyz,
    float4* z2, float* statsOut)
{
    __shared__ float xT[32 * 128];    // 16 KB
    __shared__ float sW[32 * 64];     //  8 KB (one 32-k chunk)
    __shared__ float sXyz[3 * 128];
    __shared__ float sWx[256];
    __shared__ float sB[64];
    __shared__ float sG[64];
    __shared__ float sH[64];
    __shared__ float sStat[128];
    int tid = static_cast<int>(threadIdx.x);
    int R0  = static_cast<int>(blockIdx.x) * 128;
    int ty  = tid >> 4;
    int tx  = tid & 15;
    int r   = tid & 127;
    int h   = tid >> 7;

    if (tid < 64) {
        sB[tid] = bias2[tid];
        double mean = static_cast<double>(statsIn[tid]) / static_cast<double>(kNRows);
        double var  = static_cast<double>(statsIn[64 + tid]) / static_cast<double>(kNRows) - mean * mean;
        double rstd = 1.0 / sqrt(var + 1e-5);
        float g = static_cast<float>(rstd) * gamma1[tid];
        sG[tid] = g;
        sH[tid] = beta1[tid] - static_cast<float>(mean) * g;
        sWx[tid]       = w1[tid * 67 + 0];
        sWx[64 + tid]  = w1[tid * 67 + 1];
        sWx[128 + tid] = w1[tid * 67 + 2];
        sWx[192 + tid] = bias1[tid];
    }
    if (tid < 128) sStat[tid] = 0.0f;
    if (h == 0) {
        float4 d = ballDxyz[R0 + r];
        sXyz[r]       = d.x;
        sXyz[128 + r] = d.y;
        sXyz[256 + r] = d.z;
    }
    __syncthreads();

    float acc[8][4];
    #pragma unroll
    for (int i = 0; i < 8; i++)
        #pragma unroll
        for (int j = 0; j < 4; j++) acc[i][j] = sB[tx * 4 + j];

    int gi = ballIdx[R0 + r];
    int b  = R0 >> 16;
    const float4* prow = p1 + (static_cast<size_t>(b) * kNPts + static_cast<size_t>(gi)) * 16;
    float dx = sXyz[r], dy = sXyz[128 + r], dz = sXyz[256 + r];

    #pragma unroll 1
    for (int ch = 0; ch < 2; ch++) {
        if (ch > 0) __syncthreads();
        for (int j = h * 4; j < h * 4 + 4; j++) {
            float4 v = prow[ch * 8 + j];
            int kg = ch * 32 + j * 4;
            int k  = j * 4;
            float z0 = v.x + dx * sWx[kg + 0] + dy * sWx[64 + kg + 0] + dz * sWx[128 + kg + 0] + sWx[192 + kg + 0];
            float z1v = v.y + dx * sWx[kg + 1] + dy * sWx[64 + kg + 1] + dz * sWx[128 + kg + 1] + sWx[192 + kg + 1];
            float z2v = v.z + dx * sWx[kg + 2] + dy * sWx[64 + kg + 2] + dz * sWx[128 + kg + 2] + sWx[192 + kg + 2];
            float z3v = v.w + dx * sWx[kg + 3] + dy * sWx[64 + kg + 3] + dz * sWx[128 + kg + 3] + sWx[192 + kg + 3];
            xT[(k + 0) * 128 + r] = fmaxf(z0  * sG[kg + 0] + sH[kg + 0], 0.0f);
            xT[(k + 1) * 128 + r] = fmaxf(z1v * sG[kg + 1] + sH[kg + 1], 0.0f);
            xT[(k + 2) * 128 + r] = fmaxf(z2v * sG[kg + 2] + sH[kg + 2], 0.0f);
            xT[(k + 3) * 128 + r] = fmaxf(z3v * sG[kg + 3] + sH[kg + 3], 0.0f);
        }
        for (int i = tid; i < 32 * 64; i += 256) {
            sW[i] = wT2[ch * 32 * 64 + i];
        }
        __syncthreads();

        for (int k = 0; k < 32; k++) {
            const float* xk = &xT[k * 128 + ty * 8];
            const float* wk = &sW[k * 64 + tx * 4];
            float w0 = wk[0], w1v = wk[1], w2v = wk[2], w3v = wk[3];
            #pragma unroll
            for (int i = 0; i < 8; i++) {
                float xv = xk[i];
                acc[i][0] += xv * w0;
                acc[i][1] += xv * w1v;
                acc[i][2] += xv * w2v;
                acc[i][3] += xv * w3v;
            }
        }
    }

    float s[4] = {0.f, 0.f, 0.f, 0.f};
    float q[4] = {0.f, 0.f, 0.f, 0.f};
    #pragma unroll
    for (int i = 0; i < 8; i++) {
        int row = R0 + ty * 8 + i;
        z2[static_cast<size_t>(row) * 16 + tx] =
            make_float4(acc[i][0], acc[i][1], acc[i][2], acc[i][3]);
        #pragma unroll
        for (int j = 0; j < 4; j++) {
            s[j] += acc[i][j];
            q[j] += acc[i][j] * acc[i][j];
        }
    }
    int lane = tid & 63;
    #pragma unroll
    for (int j = 0; j < 4; j++) {
        s[j] += __shfl_xor(s[j], 16); q[j] += __shfl_xor(q[j], 16);
        s[j] += __shfl_xor(s[j], 32); q[j] += __shfl_xor(q[j], 32);
    }
    if (lane < 16) {
        #pragma unroll
        for (int j = 0; j < 4; j++) {
            atomicAdd(&sStat[tx * 4 + j],      s[j]);
            atomicAdd(&sStat[64 + tx * 4 + j], q[j]);
        }
    }
    __syncthreads();
    if (tid < 128) {
        atomicAdd(&statsOut[tid], sStat[tid]);
    }
}

// ---------------------------------------------------------------- layer 3
// 4 phases x 16-k; xT/sW 8 KB each -> LDS ~18.4 KB -> 8 blocks/CU.
// Split column tile (tx*4 and 64+tx*4): weight ds_read_b128 2-way (free).
__global__ __launch_bounds__(256) void ssaLayer3Kernel(
    const float4* z2, const float* wT3, const float* bias3,
    const float* gamma2, const float* beta2, const float* statsIn,
    float* poolMax, float* statsOut)
{
    __shared__ float xT[16 * 128];    // 8 KB
    __shared__ float sW[16 * 128];    // 8 KB (one 16-k chunk)
    __shared__ float sB[128];
    __shared__ float sG[64];
    __shared__ float sH[64];
    __shared__ float sStat[256];
    int tid = static_cast<int>(threadIdx.x);
    int R0  = static_cast<int>(blockIdx.x) * 128;
    int ty  = tid >> 4;
    int tx  = tid & 15;
    int r   = tid & 127;
    int h   = tid >> 7;

    if (tid < 64) {
        double mean = static_cast<double>(statsIn[tid]) / static_cast<double>(kNRows);
        double var  = static_cast<double>(statsIn[64 + tid]) / static_cast<double>(kNRows) - mean * mean;
        double rstd = 1.0 / sqrt(var + 1e-5);
        float g = static_cast<float>(rstd) * gamma2[tid];
        sG[tid] = g;
        sH[tid] = beta2[tid] - static_cast<float>(mean) * g;
    }
    if (tid < 128) sB[tid] = bias3[tid];
    sStat[tid] = 0.0f;
    __syncthreads();

    float acc[8][8];
    #pragma unroll
    for (int i = 0; i < 8; i++) {
        #pragma unroll
        for (int j = 0; j < 4; j++) {
            acc[i][j]     = sB[tx * 4 + j];
            acc[i][4 + j] = sB[64 + tx * 4 + j];
        }
    }

    const float4* zr = z2 + static_cast<size_t>(R0 + r) * 16;

    #pragma unroll 1
    for (int p = 0; p < 4; p++) {
        if (p > 0) __syncthreads();
        // stage 2 float4 of this row's 16-k slice (coalesced stream)
        for (int m = 0; m < 2; m++) {
            float4 v = zr[p * 4 + h * 2 + m];
            int kg = p * 16 + (h * 2 + m) * 4;
            int k  = (h * 2 + m) * 4;
            xT[(k + 0) * 128 + r] = fmaxf(v.x * sG[kg + 0] + sH[kg + 0], 0.0f);
            xT[(k + 1) * 128 + r] = fmaxf(v.y * sG[kg + 1] + sH[kg + 1], 0.0f);
            xT[(k + 2) * 128 + r] = fmaxf(v.z * sG[kg + 2] + sH[kg + 2], 0.0f);
            xT[(k + 3) * 128 + r] = fmaxf(v.w * sG[kg + 3] + sH[kg + 3], 0.0f);
        }
        for (int i = tid; i < 16 * 128; i += 256) {
            sW[i] = wT3[p * 16 * 128 + i];
        }
        __syncthreads();

        for (int k = 0; k < 16; k++) {
            const float* xk = &xT[k * 128 + ty * 8];
            const float* wk = &sW[k * 128];
            float wv[8];
            #pragma unroll
            for (int j = 0; j < 4; j++) wv[j] = wk[tx * 4 + j];
            #pragma unroll
            for (int j = 0; j < 4; j++) wv[4 + j] = wk[64 + tx * 4 + j];
            #pragma unroll
            for (int i = 0; i < 8; i++) {
                float xv = xk[i];
                #pragma unroll
                for (int j = 0; j < 8; j++) {
                    acc[i][j] += xv * wv[j];
                }
            }
        }
    }

    // pooling (max over the wave's 32 rows) + stats
    int lane = tid & 63;
    int grp  = static_cast<int>(blockIdx.x) * 4 + (ty >> 2);
    float mx[8];
    float s[8];
    float q[8];
    #pragma unroll
    for (int j = 0; j < 8; j++) {
        mx[j] = acc[0][j];
        s[j]  = 0.0f;
        q[j]  = 0.0f;
    }
    #pragma unroll
    for (int i = 0; i < 8; i++)
        #pragma unroll
        for (int j = 0; j < 8; j++) {
            float v = acc[i][j];
            mx[j] = fmaxf(mx[j], v);
            s[j] += v;
            q[j] += v * v;
        }
    #pragma unroll
    for (int j = 0; j < 8; j++) {
        mx[j] = fmaxf(mx[j], __shfl_xor(mx[j], 16));
        mx[j] = fmaxf(mx[j], __shfl_xor(mx[j], 32));
        s[j] += __shfl_xor(s[j], 16); q[j] += __shfl_xor(q[j], 16);
        s[j] += __shfl_xor(s[j], 32); q[j] += __shfl_xor(q[j], 32);
    }
    if (lane < 16) {
        #pragma unroll
        for (int j = 0; j < 8; j++) {
            int c = (j < 4) ? (tx * 4 + j) : (64 + tx * 4 + (j - 4));
            poolMax[static_cast<size_t>(grp) * kC3 + c] = mx[j];
            atomicAdd(&sStat[c],       s[j]);
            atomicAdd(&sStat[128 + c], q[j]);
        }
    }
    __syncthreads();
    atomicAdd(&statsOut[tid], sStat[tid]);
}

// ---------------------------------------------------------------- finalize
__global__ __launch_bounds__(256) void ssaFinalKernel(
    const float* poolMax, const float* sum3, const float* sq3,
    const float* gamma3, const float* beta3, float* outTail)
{
    __shared__ float sG[128];
    __shared__ float sH[128];
    int tid = static_cast<int>(threadIdx.x);
    if (tid < 128) {
        double mean = static_cast<double>(sum3[tid]) / static_cast<double>(kNRows);
        double var  = static_cast<double>(sq3[tid]) / static_cast<double>(kNRows) - mean * mean;
        double rstd = 1.0 / sqrt(var + 1e-5);
        float g = static_cast<float>(rstd) * gamma3[tid];
        sG[tid] = g;
        sH[tid] = beta3[tid] - static_cast<float>(mean) * g;
    }
    __syncthreads();
    int e  = static_cast<int>(blockIdx.x) * 256 + tid;
    int b  = e >> 18;
    int ch = (e >> 11) & 127;
    int s  = e & 2047;
    size_t gi = static_cast<size_t>(b * kNS + s) * kC3 + ch;
    outTail[e] = fmaxf(poolMax[gi] * sG[ch] + sH[ch], 0.0f);
}

// ---------------------------------------------------------------- launch
static inline void* ssaWsAt(void* base, size_t byteOff)
{
    return static_cast<void*>(static_cast<char*>(base) + byteOff);
}

extern "C" __attribute__((visibility("default"), used))
void kernel_launch(void* const* d_in, const int* in_sizes, int n_in,
                   void* d_out, int out_size, void* d_ws, size_t ws_size,
                   hipStream_t stream)
{
    static_cast<void>(in_sizes);
    static_cast<void>(n_in);
    static_cast<void>(out_size);
    static_cast<void>(ws_size);

    const float*  xyz    = static_cast<const float*>(d_in[0]);
    const float4* points = static_cast<const float4*>(d_in[1]);
    const float*  newXyz = static_cast<const float*>(d_in[2]);
    const float*  w1Ptr  = static_cast<const float*>(d_in[3]);
    const float*  b1Ptr  = static_cast<const float*>(d_in[4]);
    const float*  g1Ptr  = static_cast<const float*>(d_in[5]);
    const float*  e1Ptr  = static_cast<const float*>(d_in[6]);
    const float*  w2Ptr  = static_cast<const float*>(d_in[7]);
    const float*  b2Ptr  = static_cast<const float*>(d_in[8]);
    const float*  g2Ptr  = static_cast<const float*>(d_in[9]);
    const float*  e2Ptr  = static_cast<const float*>(d_in[10]);
    const float*  w3Ptr  = static_cast<const float*>(d_in[11]);
    const float*  b3Ptr  = static_cast<const float*>(d_in[12]);
    const float*  g3Ptr  = static_cast<const float*>(d_in[13]);
    const float*  e3Ptr  = static_cast<const float*>(d_in[14]);

    float4* soa   = static_cast<float4*>(ssaWsAt(d_ws, 0));           //  1,048,576 B
    int*    bIdx  = static_cast<int*>(ssaWsAt(d_ws, 1048576));        //  1,048,576 B
    float4* bDxy  = static_cast<float4*>(ssaWsAt(d_ws, 2097152));     //  4,194,304 B
    float4* p1    = static_cast<float4*>(ssaWsAt(d_ws, 6291456));     // 16,777,216 B
    float4* z2    = static_cast<float4*>(ssaWsAt(d_ws, 23068672));    // 67,108,864 B
    float*  pMax  = static_cast<float*>(ssaWsAt(d_ws, 90177536));     //  4,194,304 B
    float*  stats = static_cast<float*>(ssaWsAt(d_ws, 94371840));     //      2,048 B
    float*  wT3   = static_cast<float*>(ssaWsAt(d_ws, 94373888));     //     32,768 B
    float*  wT2   = static_cast<float*>(ssaWsAt(d_ws, 94406656));     //     16,384 B
    float*  outF  = static_cast<float*>(d_out);

    ssaPrepKernel<<<256, 256, 0, stream>>>(xyz, newXyz, w2Ptr, w3Ptr,
                                           outF, soa, stats, wT2, wT3);
    ssaP1Kernel<<<kNPtsTot / 128, 256, 0, stream>>>(points, w1Ptr, p1);
    ssaBallKernel<<<kNGrp / 4, 256, 0, stream>>>(newXyz, soa, w1Ptr, b1Ptr,
                                                 reinterpret_cast<const float*>(p1),
                                                 bIdx, bDxy, stats);
    ssaLayer2Kernel<<<kNRows / 128, 256, 0, stream>>>(p1, w1Ptr, b1Ptr, wT2, b2Ptr,
                                                      g1Ptr, e1Ptr, stats, bIdx, bDxy,
                                                      z2, stats + 128);
    ssaLayer3Kernel<<<kNRows / 128, 256, 0, stream>>>(z2, wT3, b3Ptr, g2Ptr, e2Ptr,
                                                      stats + 128, pMax, stats + 256);
    ssaFinalKernel<<<kNB * kC3 * kNS / 256, 256, 0, stream>>>(pMax, stats + 256, stats + 384,
                                                              g3Ptr, e3Ptr,
                                                              outF + kNB * kNS * 3);
}

// Round 8
// 321.951 us; speedup vs baseline: 1.3614x; 1.0000x over previous
//
#include <hip/hip_runtime.h>

// SingleScaleSA: B=4, N=16384, S=2048, K=32, mlp 64 -> 64 -> 128, radius 0.2.
// Round 30: base = r29 (322 us). Safe additive changes:
//  - L2: sXyz LDS buffer deleted (per-thread ballDxyz read) -> 26.9 KB ->
//    6 blocks/CU (was 5).
//  - L2+L3: weight staging via float4 (2 dwordx4/thread instead of 8 dword).
//  - prep kernel merged into P1 (one fewer dispatch).
// Numerics: identical FMA order -> absmax unchanged.
constexpr int kNB      = 4;
constexpr int kNPts    = 16384;
constexpr int kNS      = 2048;
constexpr int kNK      = 32;
constexpr int kC3      = 128;
constexpr int kNRows   = kNB * kNS * kNK;   // 262144
constexpr int kNGrp    = kNB * kNS;         // 8192
constexpr int kNPtsTot = kNB * kNPts;       // 65536
constexpr double kR2   = 0.2 * 0.2;

// ---------------------------------------------------------------- P1 GEMM (+prep)
// P1[b,n,:] = points[b,n,:] @ W1[:,3:67]^T  — 65536 rows, K=64, 64 cols.
// First 256 blocks also do the old prep work (soa/outHead/stats/wT2/wT3).
__global__ __launch_bounds__(256) void ssaP1Kernel(
    const float4* points, const float* w1,
    const float* xyz, const float* newXyz, const float* w2, const float* w3,
    float* outHead, float4* soa, float* stats, float* wT2, float* wT3,
    float4* p1)
{
    __shared__ float xT[32 * 128];
    __shared__ float sW[64 * 64];
    int tid = static_cast<int>(threadIdx.x);
    int R0  = static_cast<int>(blockIdx.x) * 128;
    int ty  = tid >> 4;
    int tx  = tid & 15;
    int r   = tid & 127;
    int h   = tid >> 7;

    // ---- merged prep (blocks 0..255 cover all ranges)
    int t = static_cast<int>(blockIdx.x) * 256 + tid;
    if (t < kNPtsTot) {
        soa[t] = make_float4(xyz[t * 3 + 0], xyz[t * 3 + 1], xyz[t * 3 + 2], 0.0f);
    }
    if (t < kNB * kNS * 3) {
        outHead[t] = newXyz[t];
    }
    if (t < 512) {
        stats[t] = 0.0f;
    }
    if (t < 64 * 128) {
        int k = t >> 7;
        int c = t & 127;
        wT3[t] = w3[c * 64 + k];
    }
    if (t < 64 * 64) {
        int k = t >> 6;
        int c = t & 63;
        wT2[t] = w2[c * 64 + k];
    }

    for (int i = tid; i < 64 * 64; i += 256) {
        int k = i >> 6;
        int c = i & 63;
        sW[i] = w1[c * 67 + 3 + k];
    }
    __syncthreads();

    float acc[8][4];
    #pragma unroll
    for (int i = 0; i < 8; i++)
        #pragma unroll
        for (int j = 0; j < 4; j++) acc[i][j] = 0.0f;

    const float4* prow = points + static_cast<size_t>(R0 + r) * 16;

    #pragma unroll 1
    for (int ch = 0; ch < 2; ch++) {
        if (ch > 0) __syncthreads();
        for (int j = h * 4; j < h * 4 + 4; j++) {
            float4 v = prow[ch * 8 + j];
            int k = j * 4;
            xT[(k + 0) * 128 + r] = v.x;
            xT[(k + 1) * 128 + r] = v.y;
            xT[(k + 2) * 128 + r] = v.z;
            xT[(k + 3) * 128 + r] = v.w;
        }
        __syncthreads();

        int kw = ch * 32;
        for (int k = 0; k < 32; k++) {
            const float* xk = &xT[k * 128 + ty * 8];
            const float* wk = &sW[(kw + k) * 64 + tx * 4];
            float w0 = wk[0], w1v = wk[1], w2v = wk[2], w3v = wk[3];
            #pragma unroll
            for (int i = 0; i < 8; i++) {
                float xv = xk[i];
                acc[i][0] += xv * w0;
                acc[i][1] += xv * w1v;
                acc[i][2] += xv * w2v;
                acc[i][3] += xv * w3v;
            }
        }
    }

    #pragma unroll
    for (int i = 0; i < 8; i++) {
        p1[static_cast<size_t>(R0 + ty * 8 + i) * 16 + tx] =
            make_float4(acc[i][0], acc[i][1], acc[i][2], acc[i][3]);
    }
}

// ---------------------------------------------------------------- ball query + BN1 stats
__global__ __launch_bounds__(256) void ssaBallKernel(
    const float* newXyz, const float4* soa, const float* w1, const float* bias1,
    const float* p1f, int* ballIdx, float4* ballDxyz, float* stats)
{
    __shared__ int   sIdx[4][32];
    __shared__ float sDx[4][32];
    __shared__ float sDy[4][32];
    __shared__ float sDz[4][32];
    __shared__ float sStat[128];
    int tid  = static_cast<int>(threadIdx.x);
    int wv   = tid >> 6;
    int lane = tid & 63;
    int w    = static_cast<int>(blockIdx.x) * 4 + wv;
    int b    = w >> 11;
    if (tid < 128) sStat[tid] = 0.0f;
    __syncthreads();

    float qx = newXyz[w * 3 + 0];
    float qy = newXyz[w * 3 + 1];
    float qz = newXyz[w * 3 + 2];
    double qxd = static_cast<double>(qx);
    double qyd = static_cast<double>(qy);
    double qzd = static_cast<double>(qz);
    double qq  = qxd * qxd + qyd * qyd + qzd * qzd;
    const float4* sp = soa + b * kNPts;
    int*    oi = ballIdx  + static_cast<size_t>(w) * kNK;
    float4* od = ballDxyz + static_cast<size_t>(w) * kNK;

    int cnt = 0;
    int firstN = -1;
    float fdx = 0.0f, fdy = 0.0f, fdz = 0.0f;
    for (int base = 0; base < kNPts && cnt < kNK; base += 64) {
        float4 p = sp[base + lane];
        double pxd = static_cast<double>(p.x);
        double pyd = static_cast<double>(p.y);
        double pzd = static_cast<double>(p.z);
        double d2  = qq + (pxd * pxd + pyd * pyd + pzd * pzd)
                   - 2.0 * (qxd * pxd + qyd * pyd + qzd * pzd);
        bool hit   = (d2 <= kR2);
        unsigned long long m = __ballot(hit);
        int pos = cnt + __popcll(m & ((1ull << lane) - 1ull));
        if (hit && pos < kNK) {
            float dx = p.x - qx;
            float dy = p.y - qy;
            float dz = p.z - qz;
            oi[pos] = base + lane;
            od[pos] = make_float4(dx, dy, dz, 0.0f);
            sIdx[wv][pos] = base + lane;
            sDx[wv][pos] = dx;
            sDy[wv][pos] = dy;
            sDz[wv][pos] = dz;
            if (pos == 0) { firstN = base + lane; fdx = dx; fdy = dy; fdz = dz; }
        }
        cnt += __popcll(m);
    }
    if (cnt < kNK) {
        unsigned long long hv = __ballot(firstN >= 0);
        int fi;
        float dx, dy, dz;
        if (hv != 0ull) {
            int src = __builtin_ctzll(hv);
            fi = __shfl(firstN, src);
            dx = __shfl(fdx, src);
            dy = __shfl(fdy, src);
            dz = __shfl(fdz, src);
        } else {
            float4 p = sp[kNPts - 1];
            fi = kNPts - 1;
            dx = p.x - qx;
            dy = p.y - qy;
            dz = p.z - qz;
        }
        for (int p2 = cnt + lane; p2 < kNK; p2 += 64) {
            oi[p2] = fi;
            od[p2] = make_float4(dx, dy, dz, 0.0f);
            sIdx[wv][p2] = fi;
            sDx[wv][p2] = dx;
            sDy[wv][p2] = dy;
            sDz[wv][p2] = dz;
        }
    }

    // BN1 stats: lane = channel; z1 = P1[gi,c] + dxyz.W1xyz[:,c] + b1[c].
    float wa  = w1[lane * 67 + 0];
    float wbv = w1[lane * 67 + 1];
    float wc  = w1[lane * 67 + 2];
    float bb  = bias1[lane];
    const float* pb = p1f + static_cast<size_t>(b) * kNPts * 64;
    float s = 0.0f, q = 0.0f;
    #pragma unroll 4
    for (int k2 = 0; k2 < kNK; k2++) {
        int g = sIdx[wv][k2];
        float val = pb[static_cast<size_t>(g) * 64 + lane]
                  + sDx[wv][k2] * wa + sDy[wv][k2] * wbv + sDz[wv][k2] * wc + bb;
        s += val;
        q += val * val;
    }
    atomicAdd(&sStat[lane], s);
    atomicAdd(&sStat[64 + lane], q);
    __syncthreads();
    if (tid < 128) {
        atomicAdd(&stats[tid], sStat[tid]);
    }
}

// ---------------------------------------------------------------- layer 2
// Input reconstructed on the fly: relu(bn1(P1[gi] + dxyz@W1xyz + b1)).
// sW per 32-k chunk (float4 staging); sXyz removed -> LDS ~26.9 KB, 6 blocks/CU.
__global__ __launch_bounds__(256) void ssaLayer2Kernel(
    const float4* p1, const float* w1, const float* bias1,
    const float4* wT2f4, const float* bias2,
    const float* gamma1, const float* beta1, const float* statsIn,
    const int* ballIdx, const float4* ballDxyz,
    float4* z2, float* statsOut)
{
    __shared__ __align__(16) float xT[32 * 128];   // 16 KB
    __shared__ __align__(16) float sW[32 * 64];    //  8 KB (one 32-k chunk)
    __shared__ float sWx[256];
    __shared__ float sB[64];
    __shared__ float sG[64];
    __shared__ float sH[64];
    __shared__ float sStat[128];
    int tid = static_cast<int>(threadIdx.x);
    int R0  = static_cast<int>(blockIdx.x) * 128;
    int ty  = tid >> 4;
    int tx  = tid & 15;
    int r   = tid & 127;
    int h   = tid >> 7;

    if (tid < 64) {
        sB[tid] = bias2[tid];
        double mean = static_cast<double>(statsIn[tid]) / static_cast<double>(kNRows);
        double var  = static_cast<double>(statsIn[64 + tid]) / static_cast<double>(kNRows) - mean * mean;
        double rstd = 1.0 / sqrt(var + 1e-5);
        float g = static_cast<float>(rstd) * gamma1[tid];
        sG[tid] = g;
        sH[tid] = beta1[tid] - static_cast<float>(mean) * g;
        sWx[tid]       = w1[tid * 67 + 0];
        sWx[64 + tid]  = w1[tid * 67 + 1];
        sWx[128 + tid] = w1[tid * 67 + 2];
        sWx[192 + tid] = bias1[tid];
    }
    if (tid < 128) sStat[tid] = 0.0f;
    __syncthreads();

    float acc[8][4];
    #pragma unroll
    for (int i = 0; i < 8; i++)
        #pragma unroll
        for (int j = 0; j < 4; j++) acc[i][j] = sB[tx * 4 + j];

    int gi = ballIdx[R0 + r];
    float4 dd = ballDxyz[R0 + r];
    int b  = R0 >> 16;
    const float4* prow = p1 + (static_cast<size_t>(b) * kNPts + static_cast<size_t>(gi)) * 16;
    float dx = dd.x, dy = dd.y, dz = dd.z;

    float4* sWf4 = reinterpret_cast<float4*>(sW);

    #pragma unroll 1
    for (int ch = 0; ch < 2; ch++) {
        if (ch > 0) __syncthreads();
        for (int j = h * 4; j < h * 4 + 4; j++) {
            float4 v = prow[ch * 8 + j];
            int kg = ch * 32 + j * 4;
            int k  = j * 4;
            float z0 = v.x + dx * sWx[kg + 0] + dy * sWx[64 + kg + 0] + dz * sWx[128 + kg + 0] + sWx[192 + kg + 0];
            float z1v = v.y + dx * sWx[kg + 1] + dy * sWx[64 + kg + 1] + dz * sWx[128 + kg + 1] + sWx[192 + kg + 1];
            float z2v = v.z + dx * sWx[kg + 2] + dy * sWx[64 + kg + 2] + dz * sWx[128 + kg + 2] + sWx[192 + kg + 2];
            float z3v = v.w + dx * sWx[kg + 3] + dy * sWx[64 + kg + 3] + dz * sWx[128 + kg + 3] + sWx[192 + kg + 3];
            xT[(k + 0) * 128 + r] = fmaxf(z0  * sG[kg + 0] + sH[kg + 0], 0.0f);
            xT[(k + 1) * 128 + r] = fmaxf(z1v * sG[kg + 1] + sH[kg + 1], 0.0f);
            xT[(k + 2) * 128 + r] = fmaxf(z2v * sG[kg + 2] + sH[kg + 2], 0.0f);
            xT[(k + 3) * 128 + r] = fmaxf(z3v * sG[kg + 3] + sH[kg + 3], 0.0f);
        }
        sWf4[tid]       = wT2f4[ch * 512 + tid];
        sWf4[256 + tid] = wT2f4[ch * 512 + 256 + tid];
        __syncthreads();

        for (int k = 0; k < 32; k++) {
            const float* xk = &xT[k * 128 + ty * 8];
            const float* wk = &sW[k * 64 + tx * 4];
            float w0 = wk[0], w1v = wk[1], w2v = wk[2], w3v = wk[3];
            #pragma unroll
            for (int i = 0; i < 8; i++) {
                float xv = xk[i];
                acc[i][0] += xv * w0;
                acc[i][1] += xv * w1v;
                acc[i][2] += xv * w2v;
                acc[i][3] += xv * w3v;
            }
        }
    }

    float s[4] = {0.f, 0.f, 0.f, 0.f};
    float q[4] = {0.f, 0.f, 0.f, 0.f};
    #pragma unroll
    for (int i = 0; i < 8; i++) {
        int row = R0 + ty * 8 + i;
        z2[static_cast<size_t>(row) * 16 + tx] =
            make_float4(acc[i][0], acc[i][1], acc[i][2], acc[i][3]);
        #pragma unroll
        for (int j = 0; j < 4; j++) {
            s[j] += acc[i][j];
            q[j] += acc[i][j] * acc[i][j];
        }
    }
    int lane = tid & 63;
    #pragma unroll
    for (int j = 0; j < 4; j++) {
        s[j] += __shfl_xor(s[j], 16); q[j] += __shfl_xor(q[j], 16);
        s[j] += __shfl_xor(s[j], 32); q[j] += __shfl_xor(q[j], 32);
    }
    if (lane < 16) {
        #pragma unroll
        for (int j = 0; j < 4; j++) {
            atomicAdd(&sStat[tx * 4 + j],      s[j]);
            atomicAdd(&sStat[64 + tx * 4 + j], q[j]);
        }
    }
    __syncthreads();
    if (tid < 128) {
        atomicAdd(&statsOut[tid], sStat[tid]);
    }
}

// ---------------------------------------------------------------- layer 3
// 4 phases x 16-k; xT/sW 8 KB each -> LDS ~18.4 KB -> 8 blocks/CU.
// Split column tile; float4 weight staging.
__global__ __launch_bounds__(256) void ssaLayer3Kernel(
    const float4* z2, const float4* wT3f4, const float* bias3,
    const float* gamma2, const float* beta2, const float* statsIn,
    float* poolMax, float* statsOut)
{
    __shared__ __align__(16) float xT[16 * 128];   // 8 KB
    __shared__ __align__(16) float sW[16 * 128];   // 8 KB (one 16-k chunk)
    __shared__ float sB[128];
    __shared__ float sG[64];
    __shared__ float sH[64];
    __shared__ float sStat[256];
    int tid = static_cast<int>(threadIdx.x);
    int R0  = static_cast<int>(blockIdx.x) * 128;
    int ty  = tid >> 4;
    int tx  = tid & 15;
    int r   = tid & 127;
    int h   = tid >> 7;

    if (tid < 64) {
        double mean = static_cast<double>(statsIn[tid]) / static_cast<double>(kNRows);
        double var  = static_cast<double>(statsIn[64 + tid]) / static_cast<double>(kNRows) - mean * mean;
        double rstd = 1.0 / sqrt(var + 1e-5);
        float g = static_cast<float>(rstd) * gamma2[tid];
        sG[tid] = g;
        sH[tid] = beta2[tid] - static_cast<float>(mean) * g;
    }
    if (tid < 128) sB[tid] = bias3[tid];
    sStat[tid] = 0.0f;
    __syncthreads();

    float acc[8][8];
    #pragma unroll
    for (int i = 0; i < 8; i++) {
        #pragma unroll
        for (int j = 0; j < 4; j++) {
            acc[i][j]     = sB[tx * 4 + j];
            acc[i][4 + j] = sB[64 + tx * 4 + j];
        }
    }

    const float4* zr = z2 + static_cast<size_t>(R0 + r) * 16;
    float4* sWf4 = reinterpret_cast<float4*>(sW);

    #pragma unroll 1
    for (int p = 0; p < 4; p++) {
        if (p > 0) __syncthreads();
        // stage 2 float4 of this row's 16-k slice (coalesced stream)
        for (int m = 0; m < 2; m++) {
            float4 v = zr[p * 4 + h * 2 + m];
            int kg = p * 16 + (h * 2 + m) * 4;
            int k  = (h * 2 + m) * 4;
            xT[(k + 0) * 128 + r] = fmaxf(v.x * sG[kg + 0] + sH[kg + 0], 0.0f);
            xT[(k + 1) * 128 + r] = fmaxf(v.y * sG[kg + 1] + sH[kg + 1], 0.0f);
            xT[(k + 2) * 128 + r] = fmaxf(v.z * sG[kg + 2] + sH[kg + 2], 0.0f);
            xT[(k + 3) * 128 + r] = fmaxf(v.w * sG[kg + 3] + sH[kg + 3], 0.0f);
        }
        sWf4[tid]       = wT3f4[p * 512 + tid];
        sWf4[256 + tid] = wT3f4[p * 512 + 256 + tid];
        __syncthreads();

        for (int k = 0; k < 16; k++) {
            const float* xk = &xT[k * 128 + ty * 8];
            const float* wk = &sW[k * 128];
            float wv[8];
            #pragma unroll
            for (int j = 0; j < 4; j++) wv[j] = wk[tx * 4 + j];
            #pragma unroll
            for (int j = 0; j < 4; j++) wv[4 + j] = wk[64 + tx * 4 + j];
            #pragma unroll
            for (int i = 0; i < 8; i++) {
                float xv = xk[i];
                #pragma unroll
                for (int j = 0; j < 8; j++) {
                    acc[i][j] += xv * wv[j];
                }
            }
        }
    }

    // pooling (max over the wave's 32 rows) + stats
    int lane = tid & 63;
    int grp  = static_cast<int>(blockIdx.x) * 4 + (ty >> 2);
    float mx[8];
    float s[8];
    float q[8];
    #pragma unroll
    for (int j = 0; j < 8; j++) {
        mx[j] = acc[0][j];
        s[j]  = 0.0f;
        q[j]  = 0.0f;
    }
    #pragma unroll
    for (int i = 0; i < 8; i++)
        #pragma unroll
        for (int j = 0; j < 8; j++) {
            float v = acc[i][j];
            mx[j] = fmaxf(mx[j], v);
            s[j] += v;
            q[j] += v * v;
        }
    #pragma unroll
    for (int j = 0; j < 8; j++) {
        mx[j] = fmaxf(mx[j], __shfl_xor(mx[j], 16));
        mx[j] = fmaxf(mx[j], __shfl_xor(mx[j], 32));
        s[j] += __shfl_xor(s[j], 16); q[j] += __shfl_xor(q[j], 16);
        s[j] += __shfl_xor(s[j], 32); q[j] += __shfl_xor(q[j], 32);
    }
    if (lane < 16) {
        #pragma unroll
        for (int j = 0; j < 8; j++) {
            int c = (j < 4) ? (tx * 4 + j) : (64 + tx * 4 + (j - 4));
            poolMax[static_cast<size_t>(grp) * kC3 + c] = mx[j];
            atomicAdd(&sStat[c],       s[j]);
            atomicAdd(&sStat[128 + c], q[j]);
        }
    }
    __syncthreads();
    atomicAdd(&statsOut[tid], sStat[tid]);
}

// ---------------------------------------------------------------- finalize
__global__ __launch_bounds__(256) void ssaFinalKernel(
    const float* poolMax, const float* sum3, const float* sq3,
    const float* gamma3, const float* beta3, float* outTail)
{
    __shared__ float sG[128];
    __shared__ float sH[128];
    int tid = static_cast<int>(threadIdx.x);
    if (tid < 128) {
        double mean = static_cast<double>(sum3[tid]) / static_cast<double>(kNRows);
        double var  = static_cast<double>(sq3[tid]) / static_cast<double>(kNRows) - mean * mean;
        double rstd = 1.0 / sqrt(var + 1e-5);
        float g = static_cast<float>(rstd) * gamma3[tid];
        sG[tid] = g;
        sH[tid] = beta3[tid] - static_cast<float>(mean) * g;
    }
    __syncthreads();
    int e  = static_cast<int>(blockIdx.x) * 256 + tid;
    int b  = e >> 18;
    int ch = (e >> 11) & 127;
    int s  = e & 2047;
    size_t gi = static_cast<size_t>(b * kNS + s) * kC3 + ch;
    outTail[e] = fmaxf(poolMax[gi] * sG[ch] + sH[ch], 0.0f);
}

// ---------------------------------------------------------------- launch
static inline void* ssaWsAt(void* base, size_t byteOff)
{
    return static_cast<void*>(static_cast<char*>(base) + byteOff);
}

extern "C" __attribute__((visibility("default"), used))
void kernel_launch(void* const* d_in, const int* in_sizes, int n_in,
                   void* d_out, int out_size, void* d_ws, size_t ws_size,
                   hipStream_t stream)
{
    static_cast<void>(in_sizes);
    static_cast<void>(n_in);
    static_cast<void>(out_size);
    static_cast<void>(ws_size);

    const float*  xyz    = static_cast<const float*>(d_in[0]);
    const float4* points = static_cast<const float4*>(d_in[1]);
    const float*  newXyz = static_cast<const float*>(d_in[2]);
    const float*  w1Ptr  = static_cast<const float*>(d_in[3]);
    const float*  b1Ptr  = static_cast<const float*>(d_in[4]);
    const float*  g1Ptr  = static_cast<const float*>(d_in[5]);
    const float*  e1Ptr  = static_cast<const float*>(d_in[6]);
    const float*  w2Ptr  = static_cast<const float*>(d_in[7]);
    const float*  b2Ptr  = static_cast<const float*>(d_in[8]);
    const float*  g2Ptr  = static_cast<const float*>(d_in[9]);
    const float*  e2Ptr  = static_cast<const float*>(d_in[10]);
    const float*  w3Ptr  = static_cast<const float*>(d_in[11]);
    const float*  b3Ptr  = static_cast<const float*>(d_in[12]);
    const float*  g3Ptr  = static_cast<const float*>(d_in[13]);
    const float*  e3Ptr  = static_cast<const float*>(d_in[14]);

    float4* soa   = static_cast<float4*>(ssaWsAt(d_ws, 0));           //  1,048,576 B
    int*    bIdx  = static_cast<int*>(ssaWsAt(d_ws, 1048576));        //  1,048,576 B
    float4* bDxy  = static_cast<float4*>(ssaWsAt(d_ws, 2097152));     //  4,194,304 B
    float4* p1    = static_cast<float4*>(ssaWsAt(d_ws, 6291456));     // 16,777,216 B
    float4* z2    = static_cast<float4*>(ssaWsAt(d_ws, 23068672));    // 67,108,864 B
    float*  pMax  = static_cast<float*>(ssaWsAt(d_ws, 90177536));     //  4,194,304 B
    float*  stats = static_cast<float*>(ssaWsAt(d_ws, 94371840));     //      2,048 B
    float*  wT3   = static_cast<float*>(ssaWsAt(d_ws, 94373888));     //     32,768 B
    float*  wT2   = static_cast<float*>(ssaWsAt(d_ws, 94406656));     //     16,384 B
    float*  outF  = static_cast<float*>(d_out);

    ssaP1Kernel<<<kNPtsTot / 128, 256, 0, stream>>>(points, w1Ptr,
                                                    xyz, newXyz, w2Ptr, w3Ptr,
                                                    outF, soa, stats, wT2, wT3, p1);
    ssaBallKernel<<<kNGrp / 4, 256, 0, stream>>>(newXyz, soa, w1Ptr, b1Ptr,
                                                 reinterpret_cast<const float*>(p1),
                                                 bIdx, bDxy, stats);
    ssaLayer2Kernel<<<kNRows / 128, 256, 0, stream>>>(p1, w1Ptr, b1Ptr,
                                                      reinterpret_cast<const float4*>(wT2),
                                                      b2Ptr, g1Ptr, e1Ptr, stats, bIdx, bDxy,
                                                      z2, stats + 128);
    ssaLayer3Kernel<<<kNRows / 128, 256, 0, stream>>>(z2,
                                                      reinterpret_cast<const float4*>(wT3),
                                                      b3Ptr, g2Ptr, e2Ptr,
                                                      stats + 128, pMax, stats + 256);
    ssaFinalKernel<<<kNB * kC3 * kNS / 256, 256, 0, stream>>>(pMax, stats + 256, stats + 384,
                                                              g3Ptr, e3Ptr,
                                                              outF + kNB * kNS * 3);
}

// Round 9
// 315.384 us; speedup vs baseline: 1.3897x; 1.0208x over previous
//
#include <hip/hip_runtime.h>

// SingleScaleSA: B=4, N=16384, S=2048, K=32, mlp 64 -> 64 -> 128, radius 0.2.
// Round 31: base = r30 (322 us). Wave-autonomous GEMM staging in L2/L3:
//  - each wave owns a PRIVATE xT slice (its 32 rows) in LDS; stage->compute
//    is self-paced with NO block barrier in the main loop (wave-local LDS
//    RAW ordered by lgkmcnt; cross-lane visibility within wave64 needs no
//    barrier). Block barriers remain only around shared weight-chunk staging
//    (3/kernel instead of 8).
//  - L3: sW per 32-k half; 4 self-paced 16-k phases; LDS 26.6 KB, 6 blk/CU.
//  - L2: sW per 32-k chunk; 2 self-paced 32-k phases (gather granularity per
//    row unchanged vs r30 -> no r25-style thrash); LDS 26.9 KB, 6 blk/CU.
//  - FMA order identical -> absmax unchanged. No register prefetch (r26/r27).
constexpr int kNB      = 4;
constexpr int kNPts    = 16384;
constexpr int kNS      = 2048;
constexpr int kNK      = 32;
constexpr int kC3      = 128;
constexpr int kNRows   = kNB * kNS * kNK;   // 262144
constexpr int kNGrp    = kNB * kNS;         // 8192
constexpr int kNPtsTot = kNB * kNPts;       // 65536
constexpr double kR2   = 0.2 * 0.2;

// ---------------------------------------------------------------- P1 GEMM (+prep)
__global__ __launch_bounds__(256) void ssaP1Kernel(
    const float4* points, const float* w1,
    const float* xyz, const float* newXyz, const float* w2, const float* w3,
    float* outHead, float4* soa, float* stats, float* wT2, float* wT3,
    float4* p1)
{
    __shared__ float xT[32 * 128];
    __shared__ float sW[64 * 64];
    int tid = static_cast<int>(threadIdx.x);
    int R0  = static_cast<int>(blockIdx.x) * 128;
    int ty  = tid >> 4;
    int tx  = tid & 15;
    int r   = tid & 127;
    int h   = tid >> 7;

    // ---- merged prep (blocks 0..255 cover all ranges)
    int t = static_cast<int>(blockIdx.x) * 256 + tid;
    if (t < kNPtsTot) {
        soa[t] = make_float4(xyz[t * 3 + 0], xyz[t * 3 + 1], xyz[t * 3 + 2], 0.0f);
    }
    if (t < kNB * kNS * 3) {
        outHead[t] = newXyz[t];
    }
    if (t < 512) {
        stats[t] = 0.0f;
    }
    if (t < 64 * 128) {
        int k = t >> 7;
        int c = t & 127;
        wT3[t] = w3[c * 64 + k];
    }
    if (t < 64 * 64) {
        int k = t >> 6;
        int c = t & 63;
        wT2[t] = w2[c * 64 + k];
    }

    for (int i = tid; i < 64 * 64; i += 256) {
        int k = i >> 6;
        int c = i & 63;
        sW[i] = w1[c * 67 + 3 + k];
    }
    __syncthreads();

    float acc[8][4];
    #pragma unroll
    for (int i = 0; i < 8; i++)
        #pragma unroll
        for (int j = 0; j < 4; j++) acc[i][j] = 0.0f;

    const float4* prow = points + static_cast<size_t>(R0 + r) * 16;

    #pragma unroll 1
    for (int ch = 0; ch < 2; ch++) {
        if (ch > 0) __syncthreads();
        for (int j = h * 4; j < h * 4 + 4; j++) {
            float4 v = prow[ch * 8 + j];
            int k = j * 4;
            xT[(k + 0) * 128 + r] = v.x;
            xT[(k + 1) * 128 + r] = v.y;
            xT[(k + 2) * 128 + r] = v.z;
            xT[(k + 3) * 128 + r] = v.w;
        }
        __syncthreads();

        int kw = ch * 32;
        for (int k = 0; k < 32; k++) {
            const float* xk = &xT[k * 128 + ty * 8];
            const float* wk = &sW[(kw + k) * 64 + tx * 4];
            float w0 = wk[0], w1v = wk[1], w2v = wk[2], w3v = wk[3];
            #pragma unroll
            for (int i = 0; i < 8; i++) {
                float xv = xk[i];
                acc[i][0] += xv * w0;
                acc[i][1] += xv * w1v;
                acc[i][2] += xv * w2v;
                acc[i][3] += xv * w3v;
            }
        }
    }

    #pragma unroll
    for (int i = 0; i < 8; i++) {
        p1[static_cast<size_t>(R0 + ty * 8 + i) * 16 + tx] =
            make_float4(acc[i][0], acc[i][1], acc[i][2], acc[i][3]);
    }
}

// ---------------------------------------------------------------- ball query + BN1 stats
__global__ __launch_bounds__(256) void ssaBallKernel(
    const float* newXyz, const float4* soa, const float* w1, const float* bias1,
    const float* p1f, int* ballIdx, float4* ballDxyz, float* stats)
{
    __shared__ int   sIdx[4][32];
    __shared__ float sDx[4][32];
    __shared__ float sDy[4][32];
    __shared__ float sDz[4][32];
    __shared__ float sStat[128];
    int tid  = static_cast<int>(threadIdx.x);
    int wv   = tid >> 6;
    int lane = tid & 63;
    int w    = static_cast<int>(blockIdx.x) * 4 + wv;
    int b    = w >> 11;
    if (tid < 128) sStat[tid] = 0.0f;
    __syncthreads();

    float qx = newXyz[w * 3 + 0];
    float qy = newXyz[w * 3 + 1];
    float qz = newXyz[w * 3 + 2];
    double qxd = static_cast<double>(qx);
    double qyd = static_cast<double>(qy);
    double qzd = static_cast<double>(qz);
    double qq  = qxd * qxd + qyd * qyd + qzd * qzd;
    const float4* sp = soa + b * kNPts;
    int*    oi = ballIdx  + static_cast<size_t>(w) * kNK;
    float4* od = ballDxyz + static_cast<size_t>(w) * kNK;

    int cnt = 0;
    int firstN = -1;
    float fdx = 0.0f, fdy = 0.0f, fdz = 0.0f;
    for (int base = 0; base < kNPts && cnt < kNK; base += 64) {
        float4 p = sp[base + lane];
        double pxd = static_cast<double>(p.x);
        double pyd = static_cast<double>(p.y);
        double pzd = static_cast<double>(p.z);
        double d2  = qq + (pxd * pxd + pyd * pyd + pzd * pzd)
                   - 2.0 * (qxd * pxd + qyd * pyd + qzd * pzd);
        bool hit   = (d2 <= kR2);
        unsigned long long m = __ballot(hit);
        int pos = cnt + __popcll(m & ((1ull << lane) - 1ull));
        if (hit && pos < kNK) {
            float dx = p.x - qx;
            float dy = p.y - qy;
            float dz = p.z - qz;
            oi[pos] = base + lane;
            od[pos] = make_float4(dx, dy, dz, 0.0f);
            sIdx[wv][pos] = base + lane;
            sDx[wv][pos] = dx;
            sDy[wv][pos] = dy;
            sDz[wv][pos] = dz;
            if (pos == 0) { firstN = base + lane; fdx = dx; fdy = dy; fdz = dz; }
        }
        cnt += __popcll(m);
    }
    if (cnt < kNK) {
        unsigned long long hv = __ballot(firstN >= 0);
        int fi;
        float dx, dy, dz;
        if (hv != 0ull) {
            int src = __builtin_ctzll(hv);
            fi = __shfl(firstN, src);
            dx = __shfl(fdx, src);
            dy = __shfl(fdy, src);
            dz = __shfl(fdz, src);
        } else {
            float4 p = sp[kNPts - 1];
            fi = kNPts - 1;
            dx = p.x - qx;
            dy = p.y - qy;
            dz = p.z - qz;
        }
        for (int p2 = cnt + lane; p2 < kNK; p2 += 64) {
            oi[p2] = fi;
            od[p2] = make_float4(dx, dy, dz, 0.0f);
            sIdx[wv][p2] = fi;
            sDx[wv][p2] = dx;
            sDy[wv][p2] = dy;
            sDz[wv][p2] = dz;
        }
    }

    // BN1 stats: lane = channel; z1 = P1[gi,c] + dxyz.W1xyz[:,c] + b1[c].
    float wa  = w1[lane * 67 + 0];
    float wbv = w1[lane * 67 + 1];
    float wc  = w1[lane * 67 + 2];
    float bb  = bias1[lane];
    const float* pb = p1f + static_cast<size_t>(b) * kNPts * 64;
    float s = 0.0f, q = 0.0f;
    #pragma unroll 4
    for (int k2 = 0; k2 < kNK; k2++) {
        int g = sIdx[wv][k2];
        float val = pb[static_cast<size_t>(g) * 64 + lane]
                  + sDx[wv][k2] * wa + sDy[wv][k2] * wbv + sDz[wv][k2] * wc + bb;
        s += val;
        q += val * val;
    }
    atomicAdd(&sStat[lane], s);
    atomicAdd(&sStat[64 + lane], q);
    __syncthreads();
    if (tid < 128) {
        atomicAdd(&stats[tid], sStat[tid]);
    }
}

// ---------------------------------------------------------------- layer 2
// Wave-autonomous: per-wave xT [32k][32rows]; block barriers only around the
// per-32k sW staging (3 total). relu(bn1(P1[gi] + dxyz@W1xyz + b1)) @ W2.
__global__ __launch_bounds__(256) void ssaLayer2Kernel(
    const float4* p1, const float* w1, const float* bias1,
    const float4* wT2f4, const float* bias2,
    const float* gamma1, const float* beta1, const float* statsIn,
    const int* ballIdx, const float4* ballDxyz,
    float4* z2, float* statsOut)
{
    __shared__ __align__(16) float sW[32 * 64];     //  8 KB (one 32-k chunk)
    __shared__ __align__(16) float xT[4][32 * 32];  // 16 KB, wave-private
    __shared__ float sWx[256];
    __shared__ float sB[64];
    __shared__ float sG[64];
    __shared__ float sH[64];
    __shared__ float sStat[128];
    int tid  = static_cast<int>(threadIdx.x);
    int R0   = static_cast<int>(blockIdx.x) * 128;
    int ty   = tid >> 4;
    int tx   = tid & 15;
    int wv   = tid >> 6;
    int lane = tid & 63;
    int lty  = ty & 3;
    int lr   = lane & 31;
    int hh   = lane >> 5;

    if (tid < 64) {
        sB[tid] = bias2[tid];
        double mean = static_cast<double>(statsIn[tid]) / static_cast<double>(kNRows);
        double var  = static_cast<double>(statsIn[64 + tid]) / static_cast<double>(kNRows) - mean * mean;
        double rstd = 1.0 / sqrt(var + 1e-5);
        float g = static_cast<float>(rstd) * gamma1[tid];
        sG[tid] = g;
        sH[tid] = beta1[tid] - static_cast<float>(mean) * g;
        sWx[tid]       = w1[tid * 67 + 0];
        sWx[64 + tid]  = w1[tid * 67 + 1];
        sWx[128 + tid] = w1[tid * 67 + 2];
        sWx[192 + tid] = bias1[tid];
    }
    if (tid < 128) sStat[tid] = 0.0f;

    int grow = R0 + wv * 32 + lr;
    int gi = ballIdx[grow];
    float4 dd = ballDxyz[grow];
    int b = R0 >> 16;
    const float4* prow = p1 + (static_cast<size_t>(b) * kNPts + static_cast<size_t>(gi)) * 16;
    float dx = dd.x, dy = dd.y, dz = dd.z;
    float* xw = xT[wv];
    float4* sWf4 = reinterpret_cast<float4*>(sW);

    float acc[8][4];

    #pragma unroll 1
    for (int pg = 0; pg < 2; pg++) {
        if (pg > 0) __syncthreads();
        sWf4[tid]       = wT2f4[pg * 512 + tid];
        sWf4[256 + tid] = wT2f4[pg * 512 + 256 + tid];
        __syncthreads();
        if (pg == 0) {
            #pragma unroll
            for (int i = 0; i < 8; i++)
                #pragma unroll
                for (int j = 0; j < 4; j++) acc[i][j] = sB[tx * 4 + j];
        }

        // wave-local staging: 4 f4 per lane (2 lanes per row), no barrier
        #pragma unroll
        for (int m = 0; m < 4; m++) {
            float4 v = prow[pg * 8 + hh * 4 + m];
            int kk = hh * 16 + m * 4;
            int kg = pg * 32 + kk;
            float z0  = v.x + dx * sWx[kg + 0] + dy * sWx[64 + kg + 0] + dz * sWx[128 + kg + 0] + sWx[192 + kg + 0];
            float z1v = v.y + dx * sWx[kg + 1] + dy * sWx[64 + kg + 1] + dz * sWx[128 + kg + 1] + sWx[192 + kg + 1];
            float z2v = v.z + dx * sWx[kg + 2] + dy * sWx[64 + kg + 2] + dz * sWx[128 + kg + 2] + sWx[192 + kg + 2];
            float z3v = v.w + dx * sWx[kg + 3] + dy * sWx[64 + kg + 3] + dz * sWx[128 + kg + 3] + sWx[192 + kg + 3];
            xw[(kk + 0) * 32 + lr] = fmaxf(z0  * sG[kg + 0] + sH[kg + 0], 0.0f);
            xw[(kk + 1) * 32 + lr] = fmaxf(z1v * sG[kg + 1] + sH[kg + 1], 0.0f);
            xw[(kk + 2) * 32 + lr] = fmaxf(z2v * sG[kg + 2] + sH[kg + 2], 0.0f);
            xw[(kk + 3) * 32 + lr] = fmaxf(z3v * sG[kg + 3] + sH[kg + 3], 0.0f);
        }

        for (int k = 0; k < 32; k++) {
            const float* xk = &xw[k * 32 + lty * 8];
            const float* wk = &sW[k * 64 + tx * 4];
            float w0 = wk[0], w1v = wk[1], w2v = wk[2], w3v = wk[3];
            #pragma unroll
            for (int i = 0; i < 8; i++) {
                float xv = xk[i];
                acc[i][0] += xv * w0;
                acc[i][1] += xv * w1v;
                acc[i][2] += xv * w2v;
                acc[i][3] += xv * w3v;
            }
        }
    }

    float s[4] = {0.f, 0.f, 0.f, 0.f};
    float q[4] = {0.f, 0.f, 0.f, 0.f};
    #pragma unroll
    for (int i = 0; i < 8; i++) {
        int row = R0 + ty * 8 + i;
        z2[static_cast<size_t>(row) * 16 + tx] =
            make_float4(acc[i][0], acc[i][1], acc[i][2], acc[i][3]);
        #pragma unroll
        for (int j = 0; j < 4; j++) {
            s[j] += acc[i][j];
            q[j] += acc[i][j] * acc[i][j];
        }
    }
    #pragma unroll
    for (int j = 0; j < 4; j++) {
        s[j] += __shfl_xor(s[j], 16); q[j] += __shfl_xor(q[j], 16);
        s[j] += __shfl_xor(s[j], 32); q[j] += __shfl_xor(q[j], 32);
    }
    if (lane < 16) {
        #pragma unroll
        for (int j = 0; j < 4; j++) {
            atomicAdd(&sStat[tx * 4 + j],      s[j]);
            atomicAdd(&sStat[64 + tx * 4 + j], q[j]);
        }
    }
    __syncthreads();
    if (tid < 128) {
        atomicAdd(&statsOut[tid], sStat[tid]);
    }
}

// ---------------------------------------------------------------- layer 3
// Wave-autonomous: per-wave xT [16k][32rows]; sW per 32-k half (barriers only
// there, 3 total); 4 self-paced 16-k phases; split column tile.
__global__ __launch_bounds__(256) void ssaLayer3Kernel(
    const float4* z2, const float4* wT3f4, const float* bias3,
    const float* gamma2, const float* beta2, const float* statsIn,
    float* poolMax, float* statsOut)
{
    __shared__ __align__(16) float sW[32 * 128];    // 16 KB (one 32-k half)
    __shared__ __align__(16) float xT[4][16 * 32];  //  8 KB, wave-private
    __shared__ float sB[128];
    __shared__ float sG[64];
    __shared__ float sH[64];
    __shared__ float sStat[256];
    int tid  = static_cast<int>(threadIdx.x);
    int R0   = static_cast<int>(blockIdx.x) * 128;
    int ty   = tid >> 4;
    int tx   = tid & 15;
    int wv   = tid >> 6;
    int lane = tid & 63;
    int lty  = ty & 3;
    int lr   = lane & 31;
    int hh   = lane >> 5;

    if (tid < 64) {
        double mean = static_cast<double>(statsIn[tid]) / static_cast<double>(kNRows);
        double var  = static_cast<double>(statsIn[64 + tid]) / static_cast<double>(kNRows) - mean * mean;
        double rstd = 1.0 / sqrt(var + 1e-5);
        float g = static_cast<float>(rstd) * gamma2[tid];
        sG[tid] = g;
        sH[tid] = beta2[tid] - static_cast<float>(mean) * g;
    }
    if (tid < 128) sB[tid] = bias3[tid];
    sStat[tid] = 0.0f;

    const float4* zrow = z2 + static_cast<size_t>(R0 + wv * 32 + lr) * 16;
    float* xw = xT[wv];
    float4* sWf4 = reinterpret_cast<float4*>(sW);

    float acc[8][8];

    #pragma unroll 1
    for (int half = 0; half < 2; half++) {
        if (half > 0) __syncthreads();
        #pragma unroll
        for (int q2 = 0; q2 < 4; q2++) {
            sWf4[q2 * 256 + tid] = wT3f4[half * 1024 + q2 * 256 + tid];
        }
        __syncthreads();
        if (half == 0) {
            #pragma unroll
            for (int i = 0; i < 8; i++) {
                #pragma unroll
                for (int j = 0; j < 4; j++) {
                    acc[i][j]     = sB[tx * 4 + j];
                    acc[i][4 + j] = sB[64 + tx * 4 + j];
                }
            }
        }

        #pragma unroll 1
        for (int sub = 0; sub < 2; sub++) {
            int pg = half * 2 + sub;
            // wave-local staging: 2 f4 per lane (2 lanes per row), no barrier
            #pragma unroll
            for (int m = 0; m < 2; m++) {
                float4 v = zrow[pg * 4 + hh * 2 + m];
                int kk = hh * 8 + m * 4;
                int kg = pg * 16 + kk;
                xw[(kk + 0) * 32 + lr] = fmaxf(v.x * sG[kg + 0] + sH[kg + 0], 0.0f);
                xw[(kk + 1) * 32 + lr] = fmaxf(v.y * sG[kg + 1] + sH[kg + 1], 0.0f);
                xw[(kk + 2) * 32 + lr] = fmaxf(v.z * sG[kg + 2] + sH[kg + 2], 0.0f);
                xw[(kk + 3) * 32 + lr] = fmaxf(v.w * sG[kg + 3] + sH[kg + 3], 0.0f);
            }

            for (int k = 0; k < 16; k++) {
                const float* xk = &xw[k * 32 + lty * 8];
                const float* wk = &sW[(sub * 16 + k) * 128];
                float wt[8];
                #pragma unroll
                for (int j = 0; j < 4; j++) wt[j] = wk[tx * 4 + j];
                #pragma unroll
                for (int j = 0; j < 4; j++) wt[4 + j] = wk[64 + tx * 4 + j];
                #pragma unroll
                for (int i = 0; i < 8; i++) {
                    float xv = xk[i];
                    #pragma unroll
                    for (int j = 0; j < 8; j++) {
                        acc[i][j] += xv * wt[j];
                    }
                }
            }
        }
    }

    // pooling (max over the wave's 32 rows) + stats
    int grp = static_cast<int>(blockIdx.x) * 4 + wv;
    float mx[8];
    float s[8];
    float q[8];
    #pragma unroll
    for (int j = 0; j < 8; j++) {
        mx[j] = acc[0][j];
        s[j]  = 0.0f;
        q[j]  = 0.0f;
    }
    #pragma unroll
    for (int i = 0; i < 8; i++)
        #pragma unroll
        for (int j = 0; j < 8; j++) {
            float v = acc[i][j];
            mx[j] = fmaxf(mx[j], v);
            s[j] += v;
            q[j] += v * v;
        }
    #pragma unroll
    for (int j = 0; j < 8; j++) {
        mx[j] = fmaxf(mx[j], __shfl_xor(mx[j], 16));
        mx[j] = fmaxf(mx[j], __shfl_xor(mx[j], 32));
        s[j] += __shfl_xor(s[j], 16); q[j] += __shfl_xor(q[j], 16);
        s[j] += __shfl_xor(s[j], 32); q[j] += __shfl_xor(q[j], 32);
    }
    if (lane < 16) {
        #pragma unroll
        for (int j = 0; j < 8; j++) {
            int c = (j < 4) ? (tx * 4 + j) : (64 + tx * 4 + (j - 4));
            poolMax[static_cast<size_t>(grp) * kC3 + c] = mx[j];
            atomicAdd(&sStat[c],       s[j]);
            atomicAdd(&sStat[128 + c], q[j]);
        }
    }
    __syncthreads();
    atomicAdd(&statsOut[tid], sStat[tid]);
}

// ---------------------------------------------------------------- finalize
__global__ __launch_bounds__(256) void ssaFinalKernel(
    const float* poolMax, const float* sum3, const float* sq3,
    const float* gamma3, const float* beta3, float* outTail)
{
    __shared__ float sG[128];
    __shared__ float sH[128];
    int tid = static_cast<int>(threadIdx.x);
    if (tid < 128) {
        double mean = static_cast<double>(sum3[tid]) / static_cast<double>(kNRows);
        double var  = static_cast<double>(sq3[tid]) / static_cast<double>(kNRows) - mean * mean;
        double rstd = 1.0 / sqrt(var + 1e-5);
        float g = static_cast<float>(rstd) * gamma3[tid];
        sG[tid] = g;
        sH[tid] = beta3[tid] - static_cast<float>(mean) * g;
    }
    __syncthreads();
    int e  = static_cast<int>(blockIdx.x) * 256 + tid;
    int b  = e >> 18;
    int ch = (e >> 11) & 127;
    int s  = e & 2047;
    size_t gi = static_cast<size_t>(b * kNS + s) * kC3 + ch;
    outTail[e] = fmaxf(poolMax[gi] * sG[ch] + sH[ch], 0.0f);
}

// ---------------------------------------------------------------- launch
static inline void* ssaWsAt(void* base, size_t byteOff)
{
    return static_cast<void*>(static_cast<char*>(base) + byteOff);
}

extern "C" __attribute__((visibility("default"), used))
void kernel_launch(void* const* d_in, const int* in_sizes, int n_in,
                   void* d_out, int out_size, void* d_ws, size_t ws_size,
                   hipStream_t stream)
{
    static_cast<void>(in_sizes);
    static_cast<void>(n_in);
    static_cast<void>(out_size);
    static_cast<void>(ws_size);

    const float*  xyz    = static_cast<const float*>(d_in[0]);
    const float4* points = static_cast<const float4*>(d_in[1]);
    const float*  newXyz = static_cast<const float*>(d_in[2]);
    const float*  w1Ptr  = static_cast<const float*>(d_in[3]);
    const float*  b1Ptr  = static_cast<const float*>(d_in[4]);
    const float*  g1Ptr  = static_cast<const float*>(d_in[5]);
    const float*  e1Ptr  = static_cast<const float*>(d_in[6]);
    const float*  w2Ptr  = static_cast<const float*>(d_in[7]);
    const float*  b2Ptr  = static_cast<const float*>(d_in[8]);
    const float*  g2Ptr  = static_cast<const float*>(d_in[9]);
    const float*  e2Ptr  = static_cast<const float*>(d_in[10]);
    const float*  w3Ptr  = static_cast<const float*>(d_in[11]);
    const float*  b3Ptr  = static_cast<const float*>(d_in[12]);
    const float*  g3Ptr  = static_cast<const float*>(d_in[13]);
    const float*  e3Ptr  = static_cast<const float*>(d_in[14]);

    float4* soa   = static_cast<float4*>(ssaWsAt(d_ws, 0));           //  1,048,576 B
    int*    bIdx  = static_cast<int*>(ssaWsAt(d_ws, 1048576));        //  1,048,576 B
    float4* bDxy  = static_cast<float4*>(ssaWsAt(d_ws, 2097152));     //  4,194,304 B
    float4* p1    = static_cast<float4*>(ssaWsAt(d_ws, 6291456));     // 16,777,216 B
    float4* z2    = static_cast<float4*>(ssaWsAt(d_ws, 23068672));    // 67,108,864 B
    float*  pMax  = static_cast<float*>(ssaWsAt(d_ws, 90177536));     //  4,194,304 B
    float*  stats = static_cast<float*>(ssaWsAt(d_ws, 94371840));     //      2,048 B
    float*  wT3   = static_cast<float*>(ssaWsAt(d_ws, 94373888));     //     32,768 B
    float*  wT2   = static_cast<float*>(ssaWsAt(d_ws, 94406656));     //     16,384 B
    float*  outF  = static_cast<float*>(d_out);

    ssaP1Kernel<<<kNPtsTot / 128, 256, 0, stream>>>(points, w1Ptr,
                                                    xyz, newXyz, w2Ptr, w3Ptr,
                                                    outF, soa, stats, wT2, wT3, p1);
    ssaBallKernel<<<kNGrp / 4, 256, 0, stream>>>(newXyz, soa, w1Ptr, b1Ptr,
                                                 reinterpret_cast<const float*>(p1),
                                                 bIdx, bDxy, stats);
    ssaLayer2Kernel<<<kNRows / 128, 256, 0, stream>>>(p1, w1Ptr, b1Ptr,
                                                      reinterpret_cast<const float4*>(wT2),
                                                      b2Ptr, g1Ptr, e1Ptr, stats, bIdx, bDxy,
                                                      z2, stats + 128);
    ssaLayer3Kernel<<<kNRows / 128, 256, 0, stream>>>(z2,
                                                      reinterpret_cast<const float4*>(wT3),
                                                      b3Ptr, g2Ptr, e2Ptr,
                                                      stats + 128, pMax, stats + 256);
    ssaFinalKernel<<<kNB * kC3 * kNS / 256, 256, 0, stream>>>(pMax, stats + 256, stats + 384,
                                                              g3Ptr, e3Ptr,
                                                              outF + kNB * kNS * 3);
}

// Round 10
// 307.388 us; speedup vs baseline: 1.4259x; 1.0260x over previous
//
#include <hip/hip_runtime.h>

// SingleScaleSA: B=4, N=16384, S=2048, K=32, mlp 64 -> 64 -> 128, radius 0.2.
// Round 32: base = r31 (315 us; L2/L3 wave-autonomous). ONE change: ball-query
// scan batched 4 chunks (256 points) per iteration -- 4 independent loads
// issued upfront into named regs, then 4 ballot/compact steps. Serial latency
// exposures /4; selection set bit-identical (same order, same cnt guards).
// Stats gather unroll 4 -> 8. Everything else identical to r31.
constexpr int kNB      = 4;
constexpr int kNPts    = 16384;
constexpr int kNS      = 2048;
constexpr int kNK      = 32;
constexpr int kC3      = 128;
constexpr int kNRows   = kNB * kNS * kNK;   // 262144
constexpr int kNGrp    = kNB * kNS;         // 8192
constexpr int kNPtsTot = kNB * kNPts;       // 65536
constexpr double kR2   = 0.2 * 0.2;

// ---------------------------------------------------------------- P1 GEMM (+prep)
__global__ __launch_bounds__(256) void ssaP1Kernel(
    const float4* points, const float* w1,
    const float* xyz, const float* newXyz, const float* w2, const float* w3,
    float* outHead, float4* soa, float* stats, float* wT2, float* wT3,
    float4* p1)
{
    __shared__ float xT[32 * 128];
    __shared__ float sW[64 * 64];
    int tid = static_cast<int>(threadIdx.x);
    int R0  = static_cast<int>(blockIdx.x) * 128;
    int ty  = tid >> 4;
    int tx  = tid & 15;
    int r   = tid & 127;
    int h   = tid >> 7;

    // ---- merged prep (blocks 0..255 cover all ranges)
    int t = static_cast<int>(blockIdx.x) * 256 + tid;
    if (t < kNPtsTot) {
        soa[t] = make_float4(xyz[t * 3 + 0], xyz[t * 3 + 1], xyz[t * 3 + 2], 0.0f);
    }
    if (t < kNB * kNS * 3) {
        outHead[t] = newXyz[t];
    }
    if (t < 512) {
        stats[t] = 0.0f;
    }
    if (t < 64 * 128) {
        int k = t >> 7;
        int c = t & 127;
        wT3[t] = w3[c * 64 + k];
    }
    if (t < 64 * 64) {
        int k = t >> 6;
        int c = t & 63;
        wT2[t] = w2[c * 64 + k];
    }

    for (int i = tid; i < 64 * 64; i += 256) {
        int k = i >> 6;
        int c = i & 63;
        sW[i] = w1[c * 67 + 3 + k];
    }
    __syncthreads();

    float acc[8][4];
    #pragma unroll
    for (int i = 0; i < 8; i++)
        #pragma unroll
        for (int j = 0; j < 4; j++) acc[i][j] = 0.0f;

    const float4* prow = points + static_cast<size_t>(R0 + r) * 16;

    #pragma unroll 1
    for (int ch = 0; ch < 2; ch++) {
        if (ch > 0) __syncthreads();
        for (int j = h * 4; j < h * 4 + 4; j++) {
            float4 v = prow[ch * 8 + j];
            int k = j * 4;
            xT[(k + 0) * 128 + r] = v.x;
            xT[(k + 1) * 128 + r] = v.y;
            xT[(k + 2) * 128 + r] = v.z;
            xT[(k + 3) * 128 + r] = v.w;
        }
        __syncthreads();

        int kw = ch * 32;
        for (int k = 0; k < 32; k++) {
            const float* xk = &xT[k * 128 + ty * 8];
            const float* wk = &sW[(kw + k) * 64 + tx * 4];
            float w0 = wk[0], w1v = wk[1], w2v = wk[2], w3v = wk[3];
            #pragma unroll
            for (int i = 0; i < 8; i++) {
                float xv = xk[i];
                acc[i][0] += xv * w0;
                acc[i][1] += xv * w1v;
                acc[i][2] += xv * w2v;
                acc[i][3] += xv * w3v;
            }
        }
    }

    #pragma unroll
    for (int i = 0; i < 8; i++) {
        p1[static_cast<size_t>(R0 + ty * 8 + i) * 16 + tx] =
            make_float4(acc[i][0], acc[i][1], acc[i][2], acc[i][3]);
    }
}

// ---------------------------------------------------------------- ball query + BN1 stats
__global__ __launch_bounds__(256) void ssaBallKernel(
    const float* newXyz, const float4* soa, const float* w1, const float* bias1,
    const float* p1f, int* ballIdx, float4* ballDxyz, float* stats)
{
    __shared__ int   sIdx[4][32];
    __shared__ float sDx[4][32];
    __shared__ float sDy[4][32];
    __shared__ float sDz[4][32];
    __shared__ float sStat[128];
    int tid  = static_cast<int>(threadIdx.x);
    int wv   = tid >> 6;
    int lane = tid & 63;
    int w    = static_cast<int>(blockIdx.x) * 4 + wv;
    int b    = w >> 11;
    if (tid < 128) sStat[tid] = 0.0f;
    __syncthreads();

    float qx = newXyz[w * 3 + 0];
    float qy = newXyz[w * 3 + 1];
    float qz = newXyz[w * 3 + 2];
    double qxd = static_cast<double>(qx);
    double qyd = static_cast<double>(qy);
    double qzd = static_cast<double>(qz);
    double qq  = qxd * qxd + qyd * qyd + qzd * qzd;
    const float4* sp = soa + b * kNPts;
    int*    oi = ballIdx  + static_cast<size_t>(w) * kNK;
    float4* od = ballDxyz + static_cast<size_t>(w) * kNK;

    int cnt = 0;
    int firstN = -1;
    float fdx = 0.0f, fdy = 0.0f, fdz = 0.0f;

    // batched scan: 4 chunks (256 points) per iteration; loads issued upfront.
    for (int base = 0; base < kNPts && cnt < kNK; base += 256) {
        float4 pA = sp[base +   0 + lane];
        float4 pB = sp[base +  64 + lane];
        float4 pC = sp[base + 128 + lane];
        float4 pD = sp[base + 192 + lane];
        #pragma unroll
        for (int c = 0; c < 4; c++) {
            if (cnt >= kNK) break;
            float4 p = (c == 0) ? pA : (c == 1) ? pB : (c == 2) ? pC : pD;
            int cbase = base + c * 64;
            double pxd = static_cast<double>(p.x);
            double pyd = static_cast<double>(p.y);
            double pzd = static_cast<double>(p.z);
            double d2  = qq + (pxd * pxd + pyd * pyd + pzd * pzd)
                       - 2.0 * (qxd * pxd + qyd * pyd + qzd * pzd);
            bool hit   = (d2 <= kR2);
            unsigned long long m = __ballot(hit);
            int pos = cnt + __popcll(m & ((1ull << lane) - 1ull));
            if (hit && pos < kNK) {
                float dx = p.x - qx;
                float dy = p.y - qy;
                float dz = p.z - qz;
                oi[pos] = cbase + lane;
                od[pos] = make_float4(dx, dy, dz, 0.0f);
                sIdx[wv][pos] = cbase + lane;
                sDx[wv][pos] = dx;
                sDy[wv][pos] = dy;
                sDz[wv][pos] = dz;
                if (pos == 0) { firstN = cbase + lane; fdx = dx; fdy = dy; fdz = dz; }
            }
            cnt += __popcll(m);
        }
    }
    if (cnt < kNK) {
        unsigned long long hv = __ballot(firstN >= 0);
        int fi;
        float dx, dy, dz;
        if (hv != 0ull) {
            int src = __builtin_ctzll(hv);
            fi = __shfl(firstN, src);
            dx = __shfl(fdx, src);
            dy = __shfl(fdy, src);
            dz = __shfl(fdz, src);
        } else {
            float4 p = sp[kNPts - 1];
            fi = kNPts - 1;
            dx = p.x - qx;
            dy = p.y - qy;
            dz = p.z - qz;
        }
        for (int p2 = cnt + lane; p2 < kNK; p2 += 64) {
            oi[p2] = fi;
            od[p2] = make_float4(dx, dy, dz, 0.0f);
            sIdx[wv][p2] = fi;
            sDx[wv][p2] = dx;
            sDy[wv][p2] = dy;
            sDz[wv][p2] = dz;
        }
    }

    // BN1 stats: lane = channel; z1 = P1[gi,c] + dxyz.W1xyz[:,c] + b1[c].
    float wa  = w1[lane * 67 + 0];
    float wbv = w1[lane * 67 + 1];
    float wc  = w1[lane * 67 + 2];
    float bb  = bias1[lane];
    const float* pb = p1f + static_cast<size_t>(b) * kNPts * 64;
    float s = 0.0f, q = 0.0f;
    #pragma unroll 8
    for (int k2 = 0; k2 < kNK; k2++) {
        int g = sIdx[wv][k2];
        float val = pb[static_cast<size_t>(g) * 64 + lane]
                  + sDx[wv][k2] * wa + sDy[wv][k2] * wbv + sDz[wv][k2] * wc + bb;
        s += val;
        q += val * val;
    }
    atomicAdd(&sStat[lane], s);
    atomicAdd(&sStat[64 + lane], q);
    __syncthreads();
    if (tid < 128) {
        atomicAdd(&stats[tid], sStat[tid]);
    }
}

// ---------------------------------------------------------------- layer 2
// Wave-autonomous: per-wave xT [32k][32rows]; block barriers only around the
// per-32k sW staging (3 total). relu(bn1(P1[gi] + dxyz@W1xyz + b1)) @ W2.
__global__ __launch_bounds__(256) void ssaLayer2Kernel(
    const float4* p1, const float* w1, const float* bias1,
    const float4* wT2f4, const float* bias2,
    const float* gamma1, const float* beta1, const float* statsIn,
    const int* ballIdx, const float4* ballDxyz,
    float4* z2, float* statsOut)
{
    __shared__ __align__(16) float sW[32 * 64];     //  8 KB (one 32-k chunk)
    __shared__ __align__(16) float xT[4][32 * 32];  // 16 KB, wave-private
    __shared__ float sWx[256];
    __shared__ float sB[64];
    __shared__ float sG[64];
    __shared__ float sH[64];
    __shared__ float sStat[128];
    int tid  = static_cast<int>(threadIdx.x);
    int R0   = static_cast<int>(blockIdx.x) * 128;
    int ty   = tid >> 4;
    int tx   = tid & 15;
    int wv   = tid >> 6;
    int lane = tid & 63;
    int lty  = ty & 3;
    int lr   = lane & 31;
    int hh   = lane >> 5;

    if (tid < 64) {
        sB[tid] = bias2[tid];
        double mean = static_cast<double>(statsIn[tid]) / static_cast<double>(kNRows);
        double var  = static_cast<double>(statsIn[64 + tid]) / static_cast<double>(kNRows) - mean * mean;
        double rstd = 1.0 / sqrt(var + 1e-5);
        float g = static_cast<float>(rstd) * gamma1[tid];
        sG[tid] = g;
        sH[tid] = beta1[tid] - static_cast<float>(mean) * g;
        sWx[tid]       = w1[tid * 67 + 0];
        sWx[64 + tid]  = w1[tid * 67 + 1];
        sWx[128 + tid] = w1[tid * 67 + 2];
        sWx[192 + tid] = bias1[tid];
    }
    if (tid < 128) sStat[tid] = 0.0f;

    int grow = R0 + wv * 32 + lr;
    int gi = ballIdx[grow];
    float4 dd = ballDxyz[grow];
    int b = R0 >> 16;
    const float4* prow = p1 + (static_cast<size_t>(b) * kNPts + static_cast<size_t>(gi)) * 16;
    float dx = dd.x, dy = dd.y, dz = dd.z;
    float* xw = xT[wv];
    float4* sWf4 = reinterpret_cast<float4*>(sW);

    float acc[8][4];

    #pragma unroll 1
    for (int pg = 0; pg < 2; pg++) {
        if (pg > 0) __syncthreads();
        sWf4[tid]       = wT2f4[pg * 512 + tid];
        sWf4[256 + tid] = wT2f4[pg * 512 + 256 + tid];
        __syncthreads();
        if (pg == 0) {
            #pragma unroll
            for (int i = 0; i < 8; i++)
                #pragma unroll
                for (int j = 0; j < 4; j++) acc[i][j] = sB[tx * 4 + j];
        }

        // wave-local staging: 4 f4 per lane (2 lanes per row), no barrier
        #pragma unroll
        for (int m = 0; m < 4; m++) {
            float4 v = prow[pg * 8 + hh * 4 + m];
            int kk = hh * 16 + m * 4;
            int kg = pg * 32 + kk;
            float z0  = v.x + dx * sWx[kg + 0] + dy * sWx[64 + kg + 0] + dz * sWx[128 + kg + 0] + sWx[192 + kg + 0];
            float z1v = v.y + dx * sWx[kg + 1] + dy * sWx[64 + kg + 1] + dz * sWx[128 + kg + 1] + sWx[192 + kg + 1];
            float z2v = v.z + dx * sWx[kg + 2] + dy * sWx[64 + kg + 2] + dz * sWx[128 + kg + 2] + sWx[192 + kg + 2];
            float z3v = v.w + dx * sWx[kg + 3] + dy * sWx[64 + kg + 3] + dz * sWx[128 + kg + 3] + sWx[192 + kg + 3];
            xw[(kk + 0) * 32 + lr] = fmaxf(z0  * sG[kg + 0] + sH[kg + 0], 0.0f);
            xw[(kk + 1) * 32 + lr] = fmaxf(z1v * sG[kg + 1] + sH[kg + 1], 0.0f);
            xw[(kk + 2) * 32 + lr] = fmaxf(z2v * sG[kg + 2] + sH[kg + 2], 0.0f);
            xw[(kk + 3) * 32 + lr] = fmaxf(z3v * sG[kg + 3] + sH[kg + 3], 0.0f);
        }

        for (int k = 0; k < 32; k++) {
            const float* xk = &xw[k * 32 + lty * 8];
            const float* wk = &sW[k * 64 + tx * 4];
            float w0 = wk[0], w1v = wk[1], w2v = wk[2], w3v = wk[3];
            #pragma unroll
            for (int i = 0; i < 8; i++) {
                float xv = xk[i];
                acc[i][0] += xv * w0;
                acc[i][1] += xv * w1v;
                acc[i][2] += xv * w2v;
                acc[i][3] += xv * w3v;
            }
        }
    }

    float s[4] = {0.f, 0.f, 0.f, 0.f};
    float q[4] = {0.f, 0.f, 0.f, 0.f};
    #pragma unroll
    for (int i = 0; i < 8; i++) {
        int row = R0 + ty * 8 + i;
        z2[static_cast<size_t>(row) * 16 + tx] =
            make_float4(acc[i][0], acc[i][1], acc[i][2], acc[i][3]);
        #pragma unroll
        for (int j = 0; j < 4; j++) {
            s[j] += acc[i][j];
            q[j] += acc[i][j] * acc[i][j];
        }
    }
    #pragma unroll
    for (int j = 0; j < 4; j++) {
        s[j] += __shfl_xor(s[j], 16); q[j] += __shfl_xor(q[j], 16);
        s[j] += __shfl_xor(s[j], 32); q[j] += __shfl_xor(q[j], 32);
    }
    if (lane < 16) {
        #pragma unroll
        for (int j = 0; j < 4; j++) {
            atomicAdd(&sStat[tx * 4 + j],      s[j]);
            atomicAdd(&sStat[64 + tx * 4 + j], q[j]);
        }
    }
    __syncthreads();
    if (tid < 128) {
        atomicAdd(&statsOut[tid], sStat[tid]);
    }
}

// ---------------------------------------------------------------- layer 3
// Wave-autonomous: per-wave xT [16k][32rows]; sW per 32-k half (barriers only
// there, 3 total); 4 self-paced 16-k phases; split column tile.
__global__ __launch_bounds__(256) void ssaLayer3Kernel(
    const float4* z2, const float4* wT3f4, const float* bias3,
    const float* gamma2, const float* beta2, const float* statsIn,
    float* poolMax, float* statsOut)
{
    __shared__ __align__(16) float sW[32 * 128];    // 16 KB (one 32-k half)
    __shared__ __align__(16) float xT[4][16 * 32];  //  8 KB, wave-private
    __shared__ float sB[128];
    __shared__ float sG[64];
    __shared__ float sH[64];
    __shared__ float sStat[256];
    int tid  = static_cast<int>(threadIdx.x);
    int R0   = static_cast<int>(blockIdx.x) * 128;
    int ty   = tid >> 4;
    int tx   = tid & 15;
    int wv   = tid >> 6;
    int lane = tid & 63;
    int lty  = ty & 3;
    int lr   = lane & 31;
    int hh   = lane >> 5;

    if (tid < 64) {
        double mean = static_cast<double>(statsIn[tid]) / static_cast<double>(kNRows);
        double var  = static_cast<double>(statsIn[64 + tid]) / static_cast<double>(kNRows) - mean * mean;
        double rstd = 1.0 / sqrt(var + 1e-5);
        float g = static_cast<float>(rstd) * gamma2[tid];
        sG[tid] = g;
        sH[tid] = beta2[tid] - static_cast<float>(mean) * g;
    }
    if (tid < 128) sB[tid] = bias3[tid];
    sStat[tid] = 0.0f;

    const float4* zrow = z2 + static_cast<size_t>(R0 + wv * 32 + lr) * 16;
    float* xw = xT[wv];
    float4* sWf4 = reinterpret_cast<float4*>(sW);

    float acc[8][8];

    #pragma unroll 1
    for (int half = 0; half < 2; half++) {
        if (half > 0) __syncthreads();
        #pragma unroll
        for (int q2 = 0; q2 < 4; q2++) {
            sWf4[q2 * 256 + tid] = wT3f4[half * 1024 + q2 * 256 + tid];
        }
        __syncthreads();
        if (half == 0) {
            #pragma unroll
            for (int i = 0; i < 8; i++) {
                #pragma unroll
                for (int j = 0; j < 4; j++) {
                    acc[i][j]     = sB[tx * 4 + j];
                    acc[i][4 + j] = sB[64 + tx * 4 + j];
                }
            }
        }

        #pragma unroll 1
        for (int sub = 0; sub < 2; sub++) {
            int pg = half * 2 + sub;
            // wave-local staging: 2 f4 per lane (2 lanes per row), no barrier
            #pragma unroll
            for (int m = 0; m < 2; m++) {
                float4 v = zrow[pg * 4 + hh * 2 + m];
                int kk = hh * 8 + m * 4;
                int kg = pg * 16 + kk;
                xw[(kk + 0) * 32 + lr] = fmaxf(v.x * sG[kg + 0] + sH[kg + 0], 0.0f);
                xw[(kk + 1) * 32 + lr] = fmaxf(v.y * sG[kg + 1] + sH[kg + 1], 0.0f);
                xw[(kk + 2) * 32 + lr] = fmaxf(v.z * sG[kg + 2] + sH[kg + 2], 0.0f);
                xw[(kk + 3) * 32 + lr] = fmaxf(v.w * sG[kg + 3] + sH[kg + 3], 0.0f);
            }

            for (int k = 0; k < 16; k++) {
                const float* xk = &xw[k * 32 + lty * 8];
                const float* wk = &sW[(sub * 16 + k) * 128];
                float wt[8];
                #pragma unroll
                for (int j = 0; j < 4; j++) wt[j] = wk[tx * 4 + j];
                #pragma unroll
                for (int j = 0; j < 4; j++) wt[4 + j] = wk[64 + tx * 4 + j];
                #pragma unroll
                for (int i = 0; i < 8; i++) {
                    float xv = xk[i];
                    #pragma unroll
                    for (int j = 0; j < 8; j++) {
                        acc[i][j] += xv * wt[j];
                    }
                }
            }
        }
    }

    // pooling (max over the wave's 32 rows) + stats
    int grp = static_cast<int>(blockIdx.x) * 4 + wv;
    float mx[8];
    float s[8];
    float q[8];
    #pragma unroll
    for (int j = 0; j < 8; j++) {
        mx[j] = acc[0][j];
        s[j]  = 0.0f;
        q[j]  = 0.0f;
    }
    #pragma unroll
    for (int i = 0; i < 8; i++)
        #pragma unroll
        for (int j = 0; j < 8; j++) {
            float v = acc[i][j];
            mx[j] = fmaxf(mx[j], v);
            s[j] += v;
            q[j] += v * v;
        }
    #pragma unroll
    for (int j = 0; j < 8; j++) {
        mx[j] = fmaxf(mx[j], __shfl_xor(mx[j], 16));
        mx[j] = fmaxf(mx[j], __shfl_xor(mx[j], 32));
        s[j] += __shfl_xor(s[j], 16); q[j] += __shfl_xor(q[j], 16);
        s[j] += __shfl_xor(s[j], 32); q[j] += __shfl_xor(q[j], 32);
    }
    if (lane < 16) {
        #pragma unroll
        for (int j = 0; j < 8; j++) {
            int c = (j < 4) ? (tx * 4 + j) : (64 + tx * 4 + (j - 4));
            poolMax[static_cast<size_t>(grp) * kC3 + c] = mx[j];
            atomicAdd(&sStat[c],       s[j]);
            atomicAdd(&sStat[128 + c], q[j]);
        }
    }
    __syncthreads();
    atomicAdd(&statsOut[tid], sStat[tid]);
}

// ---------------------------------------------------------------- finalize
__global__ __launch_bounds__(256) void ssaFinalKernel(
    const float* poolMax, const float* sum3, const float* sq3,
    const float* gamma3, const float* beta3, float* outTail)
{
    __shared__ float sG[128];
    __shared__ float sH[128];
    int tid = static_cast<int>(threadIdx.x);
    if (tid < 128) {
        double mean = static_cast<double>(sum3[tid]) / static_cast<double>(kNRows);
        double var  = static_cast<double>(sq3[tid]) / static_cast<double>(kNRows) - mean * mean;
        double rstd = 1.0 / sqrt(var + 1e-5);
        float g = static_cast<float>(rstd) * gamma3[tid];
        sG[tid] = g;
        sH[tid] = beta3[tid] - static_cast<float>(mean) * g;
    }
    __syncthreads();
    int e  = static_cast<int>(blockIdx.x) * 256 + tid;
    int b  = e >> 18;
    int ch = (e >> 11) & 127;
    int s  = e & 2047;
    size_t gi = static_cast<size_t>(b * kNS + s) * kC3 + ch;
    outTail[e] = fmaxf(poolMax[gi] * sG[ch] + sH[ch], 0.0f);
}

// ---------------------------------------------------------------- launch
static inline void* ssaWsAt(void* base, size_t byteOff)
{
    return static_cast<void*>(static_cast<char*>(base) + byteOff);
}

extern "C" __attribute__((visibility("default"), used))
void kernel_launch(void* const* d_in, const int* in_sizes, int n_in,
                   void* d_out, int out_size, void* d_ws, size_t ws_size,
                   hipStream_t stream)
{
    static_cast<void>(in_sizes);
    static_cast<void>(n_in);
    static_cast<void>(out_size);
    static_cast<void>(ws_size);

    const float*  xyz    = static_cast<const float*>(d_in[0]);
    const float4* points = static_cast<const float4*>(d_in[1]);
    const float*  newXyz = static_cast<const float*>(d_in[2]);
    const float*  w1Ptr  = static_cast<const float*>(d_in[3]);
    const float*  b1Ptr  = static_cast<const float*>(d_in[4]);
    const float*  g1Ptr  = static_cast<const float*>(d_in[5]);
    const float*  e1Ptr  = static_cast<const float*>(d_in[6]);
    const float*  w2Ptr  = static_cast<const float*>(d_in[7]);
    const float*  b2Ptr  = static_cast<const float*>(d_in[8]);
    const float*  g2Ptr  = static_cast<const float*>(d_in[9]);
    const float*  e2Ptr  = static_cast<const float*>(d_in[10]);
    const float*  w3Ptr  = static_cast<const float*>(d_in[11]);
    const float*  b3Ptr  = static_cast<const float*>(d_in[12]);
    const float*  g3Ptr  = static_cast<const float*>(d_in[13]);
    const float*  e3Ptr  = static_cast<const float*>(d_in[14]);

    float4* soa   = static_cast<float4*>(ssaWsAt(d_ws, 0));           //  1,048,576 B
    int*    bIdx  = static_cast<int*>(ssaWsAt(d_ws, 1048576));        //  1,048,576 B
    float4* bDxy  = static_cast<float4*>(ssaWsAt(d_ws, 2097152));     //  4,194,304 B
    float4* p1    = static_cast<float4*>(ssaWsAt(d_ws, 6291456));     // 16,777,216 B
    float4* z2    = static_cast<float4*>(ssaWsAt(d_ws, 23068672));    // 67,108,864 B
    float*  pMax  = static_cast<float*>(ssaWsAt(d_ws, 90177536));     //  4,194,304 B
    float*  stats = static_cast<float*>(ssaWsAt(d_ws, 94371840));     //      2,048 B
    float*  wT3   = static_cast<float*>(ssaWsAt(d_ws, 94373888));     //     32,768 B
    float*  wT2   = static_cast<float*>(ssaWsAt(d_ws, 94406656));     //     16,384 B
    float*  outF  = static_cast<float*>(d_out);

    ssaP1Kernel<<<kNPtsTot / 128, 256, 0, stream>>>(points, w1Ptr,
                                                    xyz, newXyz, w2Ptr, w3Ptr,
                                                    outF, soa, stats, wT2, wT3, p1);
    ssaBallKernel<<<kNGrp / 4, 256, 0, stream>>>(newXyz, soa, w1Ptr, b1Ptr,
                                                 reinterpret_cast<const float*>(p1),
                                                 bIdx, bDxy, stats);
    ssaLayer2Kernel<<<kNRows / 128, 256, 0, stream>>>(p1, w1Ptr, b1Ptr,
                                                      reinterpret_cast<const float4*>(wT2),
                                                      b2Ptr, g1Ptr, e1Ptr, stats, bIdx, bDxy,
                                                      z2, stats + 128);
    ssaLayer3Kernel<<<kNRows / 128, 256, 0, stream>>>(z2,
                                                      reinterpret_cast<const float4*>(wT3),
                                                      b3Ptr, g2Ptr, e2Ptr,
                                                      stats + 128, pMax, stats + 256);
    ssaFinalKernel<<<kNB * kC3 * kNS / 256, 256, 0, stream>>>(pMax, stats + 256, stats + 384,
                                                              g3Ptr, e3Ptr,
                                                              outF + kNB * kNS * 3);
}